// Round 1
// baseline (887.873 us; speedup 1.0000x reference)
//
#include <hip/hip_runtime.h>
#include <math.h>

#define SEQ 1024
#define BATCH 2
#define T 2048
#define DM 1024
#define NH 16
#define NOPE 32
#define RP 32
#define HD 64
#define QL 20
#define KVL 20
#define KVA 52   // KV_LORA + ROPE
#define HID 1024
#define NEXP 4

typedef float f32x4 __attribute__((ext_vector_type(4)));

static __device__ __forceinline__ float sigmoidf_(float x) {
    return 1.0f / (1.0f + __expf(-x));
}

// ---------------------------------------------------------------------------
// K1: per-token LoRA projections + RMS norms + RoPE. One block per token.
// Produces q_buf (roped, [t][h*64]), k_buf (k_nope + roped k_pe), v_buf.
// ---------------------------------------------------------------------------
__global__ __launch_bounds__(256) void k_proj(
    const float* __restrict__ dec, const float* __restrict__ wq_a,
    const float* __restrict__ q_norm_w, const float* __restrict__ wq_b,
    const float* __restrict__ wkv_a, const float* __restrict__ kv_norm_w,
    const float* __restrict__ wkv_b,
    float* __restrict__ qb, float* __restrict__ kb, float* __restrict__ vb)
{
    __shared__ float xrow[DM];
    __shared__ float sval[72];   // 0..19 = x@wq_a ; 20..39 = ckv ; 40..71 = k_pe raw
    __shared__ float nrm[40];    // 0..19 q_normed ; 20..39 ckv_normed
    __shared__ float fac[2];
    __shared__ float qrow[DM];

    int t = blockIdx.x;
    int b = t / SEQ, s = t % SEQ;
    int tid = threadIdx.x;

    for (int j = tid; j < DM; j += 256)
        xrow[j] = dec[(size_t)s * (BATCH * DM) + b * DM + j];
    __syncthreads();

    if (tid < 72) {
        float acc = 0.f;
        if (tid < 20) {
            #pragma unroll 4
            for (int k = 0; k < DM; ++k) acc += xrow[k] * wq_a[k * QL + tid];
        } else {
            int c = tid - 20;
            #pragma unroll 4
            for (int k = 0; k < DM; ++k) acc += xrow[k] * wkv_a[k * KVA + c];
        }
        sval[tid] = acc;
    }
    __syncthreads();

    if (tid < 2) {
        int base = (tid == 0) ? 0 : 20;
        float ss = 0.f;
        for (int i = 0; i < 20; ++i) { float v0 = sval[base + i]; ss += v0 * v0; }
        fac[tid] = rsqrtf(ss / 20.0f + 1e-6f);
    }
    __syncthreads();

    if (tid < 40) {
        if (tid < 20) nrm[tid] = sval[tid] * fac[0] * q_norm_w[tid];
        else          nrm[tid] = sval[tid] * fac[1] * kv_norm_w[tid - 20];
    }
    __syncthreads();

    // q row (1024) into LDS
    for (int o = tid; o < DM; o += 256) {
        float acc = 0.f;
        #pragma unroll
        for (int k = 0; k < QL; ++k) acc += nrm[k] * wq_b[k * DM + o];
        qrow[o] = acc;
    }
    // kvb row (1536): k_nope + v straight to global
    for (int o = tid; o < NH * 96; o += 256) {
        float acc = 0.f;
        #pragma unroll
        for (int k = 0; k < KVL; ++k) acc += nrm[20 + k] * wkv_b[k * (NH * 96) + o];
        int h = o / 96, w = o % 96;
        if (w < NOPE) kb[(size_t)t * DM + h * HD + w] = acc;
        else          vb[(size_t)t * DM + h * HD + (w - 32)] = acc;
    }
    __syncthreads();

    // RoPE: 256 (head, pair) combos
    {
        int h = tid >> 4, r = tid & 15;
        float freq = powf(10000.0f, -(float)(h * 16 + r) / 256.0f);
        float ang = (float)s * freq;
        float c = cosf(ang), sn = sinf(ang);
        int i0 = h * HD + NOPE + 2 * r;
        float x0 = qrow[i0], x1 = qrow[i0 + 1];
        qrow[i0]     = x0 * c - x1 * sn;
        qrow[i0 + 1] = x0 * sn + x1 * c;
        float y0 = sval[40 + 2 * r], y1 = sval[41 + 2 * r];
        kb[(size_t)t * DM + i0]     = y0 * c - y1 * sn;
        kb[(size_t)t * DM + i0 + 1] = y0 * sn + y1 * c;
    }
    __syncthreads();

    for (int j = tid; j < DM; j += 256) qb[(size_t)t * DM + j] = qrow[j];
}

// ---------------------------------------------------------------------------
// K2: flash attention. Block = (q-tile of 64, head, batch). 256 threads.
// ---------------------------------------------------------------------------
__global__ __launch_bounds__(256) void k_attn(
    const float* __restrict__ qb, const float* __restrict__ kb,
    const float* __restrict__ vb, float* __restrict__ ab)
{
    __shared__ __align__(16) float qs[64][68];
    __shared__ __align__(16) float ks[64][68];
    __shared__ __align__(16) float vst[64][68];  // [dim][key]
    __shared__ __align__(16) float ps[64][68];
    __shared__ float m_l[64], l_l[64], corr_l[64];

    int qt = blockIdx.x, h = blockIdx.y, b = blockIdx.z;
    int tid = threadIdx.x;
    int ri = tid >> 4, ci = tid & 15;   // 4x4 register tiles
    int row = tid >> 2, sub = tid & 3;  // softmax phase mapping

    for (int j = tid; j < 64 * 64; j += 256) {
        int i = j >> 6, d = j & 63;
        qs[i][d] = qb[(size_t)(b * SEQ + qt * 64 + i) * DM + h * HD + d];
    }
    if (tid < 64) { m_l[tid] = -1e30f; l_l[tid] = 0.f; }
    float acc[4][4] = {};
    __syncthreads();

    for (int kt = 0; kt < SEQ / 64; ++kt) {
        for (int j = tid; j < 64 * 64; j += 256) {
            int i = j >> 6, d = j & 63;
            size_t base = (size_t)(b * SEQ + kt * 64 + i) * DM + h * HD + d;
            ks[i][d] = kb[base];
            vst[d][i] = vb[base];
        }
        __syncthreads();

        // scores 4x4 per thread
        float sc[4][4] = {};
        #pragma unroll
        for (int d4 = 0; d4 < 16; ++d4) {
            f32x4 a[4], bb[4];
            #pragma unroll
            for (int i = 0; i < 4; ++i) a[i] = *(const f32x4*)&qs[ri * 4 + i][d4 * 4];
            #pragma unroll
            for (int j = 0; j < 4; ++j) bb[j] = *(const f32x4*)&ks[ci * 4 + j][d4 * 4];
            #pragma unroll
            for (int i = 0; i < 4; ++i)
                #pragma unroll
                for (int j = 0; j < 4; ++j)
                    sc[i][j] += a[i][0]*bb[j][0] + a[i][1]*bb[j][1]
                              + a[i][2]*bb[j][2] + a[i][3]*bb[j][3];
        }
        #pragma unroll
        for (int i = 0; i < 4; ++i)
            #pragma unroll
            for (int j = 0; j < 4; ++j)
                ps[ri * 4 + i][ci * 4 + j] = sc[i][j] * 0.125f;
        __syncthreads();

        // online softmax, 4 lanes per row
        {
            float sv[16]; float mt = -1e30f;
            #pragma unroll
            for (int jj = 0; jj < 16; ++jj) { sv[jj] = ps[row][sub * 16 + jj]; mt = fmaxf(mt, sv[jj]); }
            mt = fmaxf(mt, __shfl_xor(mt, 1));
            mt = fmaxf(mt, __shfl_xor(mt, 2));
            float m_old = m_l[row];
            float m_new = fmaxf(m_old, mt);
            float lsum = 0.f;
            #pragma unroll
            for (int jj = 0; jj < 16; ++jj) {
                float p = __expf(sv[jj] - m_new);
                ps[row][sub * 16 + jj] = p;
                lsum += p;
            }
            lsum += __shfl_xor(lsum, 1);
            lsum += __shfl_xor(lsum, 2);
            if (sub == 0) {
                corr_l[row] = __expf(m_old - m_new);
                m_l[row] = m_new;
                l_l[row] = l_l[row] * corr_l[row] + lsum;
            }
        }
        __syncthreads();

        // PV with rescale
        #pragma unroll
        for (int i = 0; i < 4; ++i) {
            float c = corr_l[ri * 4 + i];
            #pragma unroll
            for (int j = 0; j < 4; ++j) acc[i][j] *= c;
        }
        #pragma unroll
        for (int k4 = 0; k4 < 16; ++k4) {
            f32x4 p[4], v4[4];
            #pragma unroll
            for (int i = 0; i < 4; ++i) p[i] = *(const f32x4*)&ps[ri * 4 + i][k4 * 4];
            #pragma unroll
            for (int j = 0; j < 4; ++j) v4[j] = *(const f32x4*)&vst[ci * 4 + j][k4 * 4];
            #pragma unroll
            for (int i = 0; i < 4; ++i)
                #pragma unroll
                for (int j = 0; j < 4; ++j)
                    acc[i][j] += p[i][0]*v4[j][0] + p[i][1]*v4[j][1]
                               + p[i][2]*v4[j][2] + p[i][3]*v4[j][3];
        }
        __syncthreads();
    }

    #pragma unroll
    for (int i = 0; i < 4; ++i) {
        float inv = 1.0f / l_l[ri * 4 + i];
        #pragma unroll
        for (int j = 0; j < 4; ++j)
            ab[(size_t)(b * SEQ + qt * 64 + ri * 4 + i) * DM + h * HD + ci * 4 + j] = acc[i][j] * inv;
    }
}

// ---------------------------------------------------------------------------
// K3: plain GEMM C[M=2048,1024] = A @ B[1024,1024]. 64x64 tile, 4x4/thread.
// ---------------------------------------------------------------------------
__global__ __launch_bounds__(256) void k_gemm_wo(
    const float* __restrict__ A, const float* __restrict__ Bm, float* __restrict__ C)
{
    __shared__ __align__(16) float As[16][68];
    __shared__ __align__(16) float Bs[16][68];
    int n0 = blockIdx.x * 64, m0 = blockIdx.y * 64;
    int tid = threadIdx.x;
    int trow = tid >> 4, tcol = tid & 15;
    int lar = tid >> 2, lak = (tid & 3) * 4;
    int lbk = tid >> 4, lbc = (tid & 15) * 4;
    float acc[4][4] = {};
    for (int k0 = 0; k0 < DM; k0 += 16) {
        f32x4 av = *(const f32x4*)&A[(size_t)(m0 + lar) * DM + k0 + lak];
        f32x4 bv = *(const f32x4*)&Bm[(size_t)(k0 + lbk) * DM + n0 + lbc];
        __syncthreads();
        #pragma unroll
        for (int q2 = 0; q2 < 4; ++q2) As[lak + q2][lar] = av[q2];
        *(f32x4*)&Bs[lbk][lbc] = bv;
        __syncthreads();
        #pragma unroll
        for (int kk = 0; kk < 16; ++kk) {
            f32x4 a = *(const f32x4*)&As[kk][trow * 4];
            f32x4 bq = *(const f32x4*)&Bs[kk][tcol * 4];
            #pragma unroll
            for (int i = 0; i < 4; ++i)
                #pragma unroll
                for (int j = 0; j < 4; ++j) acc[i][j] += a[i] * bq[j];
        }
    }
    #pragma unroll
    for (int i = 0; i < 4; ++i)
        #pragma unroll
        for (int j = 0; j < 4; ++j)
            C[(size_t)(m0 + trow * 4 + i) * DM + n0 + tcol * 4 + j] = acc[i][j];
}

// ---------------------------------------------------------------------------
// K4: gating = softmax over 4 experts, argmax (group logic is a no-op here:
// TOPK_GROUP==N_GROUP). Builds per-expert token lists.
// ---------------------------------------------------------------------------
__global__ __launch_bounds__(256) void k_gate(
    const float* __restrict__ y, const float* __restrict__ gw,
    int* __restrict__ cnt, int* __restrict__ lists, float* __restrict__ wtok)
{
    int warp = threadIdx.x >> 6, lane = threadIdx.x & 63;
    int t = blockIdx.x * 4 + warp;
    float acc[NEXP] = {};
    for (int d = lane; d < DM; d += 64) {
        float xv = y[(size_t)t * DM + d];
        #pragma unroll
        for (int e = 0; e < NEXP; ++e) acc[e] += xv * gw[e * DM + d];
    }
    #pragma unroll
    for (int off = 32; off; off >>= 1)
        #pragma unroll
        for (int e = 0; e < NEXP; ++e) acc[e] += __shfl_xor(acc[e], off);
    if (lane == 0) {
        float mx = fmaxf(fmaxf(acc[0], acc[1]), fmaxf(acc[2], acc[3]));
        float ex[NEXP], ssum = 0.f;
        #pragma unroll
        for (int e = 0; e < NEXP; ++e) { ex[e] = __expf(acc[e] - mx); ssum += ex[e]; }
        int best = 0; float bv = ex[0];
        #pragma unroll
        for (int e = 1; e < NEXP; ++e) if (ex[e] > bv) { bv = ex[e]; best = e; }
        wtok[t] = bv / ssum;  // * ROUTED_SCALE(=1)
        int pos = atomicAdd(&cnt[best], 1);
        lists[best * T + pos] = t;
    }
}

// ---------------------------------------------------------------------------
// K5: routed gate+up (gathered rows), fused SiLU*up -> act
// ---------------------------------------------------------------------------
__global__ __launch_bounds__(256) void k_moe_gu(
    const float* __restrict__ X, const float* __restrict__ Wg0,
    const float* __restrict__ Wu0, const int* __restrict__ cnt,
    const int* __restrict__ lists, float* __restrict__ act)
{
    int e = blockIdx.z;
    int n = cnt[e];
    int m0 = blockIdx.y * 64;
    if (m0 >= n) return;
    int n0 = blockIdx.x * 64;
    const float* Wg = Wg0 + (size_t)e * DM * HID;
    const float* Wu = Wu0 + (size_t)e * DM * HID;
    __shared__ __align__(16) float As[16][68];
    __shared__ __align__(16) float Bg[16][68];
    __shared__ __align__(16) float Bu[16][68];
    __shared__ int rowid[64];
    int tid = threadIdx.x;
    if (tid < 64) rowid[tid] = lists[(size_t)e * T + ((m0 + tid < n) ? (m0 + tid) : 0)];
    __syncthreads();
    int lar = tid >> 2, lak = (tid & 3) * 4;
    int lbk = tid >> 4, lbc = (tid & 15) * 4;
    int trow = tid >> 4, tcol = tid & 15;
    int rowA = rowid[lar];
    float ag[4][4] = {}, au[4][4] = {};
    for (int k0 = 0; k0 < DM; k0 += 16) {
        f32x4 av = *(const f32x4*)&X[(size_t)rowA * DM + k0 + lak];
        f32x4 bg = *(const f32x4*)&Wg[(size_t)(k0 + lbk) * HID + n0 + lbc];
        f32x4 bu = *(const f32x4*)&Wu[(size_t)(k0 + lbk) * HID + n0 + lbc];
        __syncthreads();
        #pragma unroll
        for (int q2 = 0; q2 < 4; ++q2) As[lak + q2][lar] = av[q2];
        *(f32x4*)&Bg[lbk][lbc] = bg;
        *(f32x4*)&Bu[lbk][lbc] = bu;
        __syncthreads();
        #pragma unroll
        for (int kk = 0; kk < 16; ++kk) {
            f32x4 a = *(const f32x4*)&As[kk][trow * 4];
            f32x4 g = *(const f32x4*)&Bg[kk][tcol * 4];
            f32x4 u = *(const f32x4*)&Bu[kk][tcol * 4];
            #pragma unroll
            for (int i = 0; i < 4; ++i)
                #pragma unroll
                for (int j = 0; j < 4; ++j) { ag[i][j] += a[i] * g[j]; au[i][j] += a[i] * u[j]; }
        }
    }
    #pragma unroll
    for (int i = 0; i < 4; ++i) {
        if (m0 + trow * 4 + i >= n) continue;
        int token = rowid[trow * 4 + i];
        #pragma unroll
        for (int j = 0; j < 4; ++j) {
            float g = ag[i][j], u = au[i][j];
            act[(size_t)token * HID + n0 + tcol * 4 + j] = g * sigmoidf_(g) * u;
        }
    }
}

// ---------------------------------------------------------------------------
// K6: routed down (gathered) -> writes d_out (=, covers every token once)
// ---------------------------------------------------------------------------
__global__ __launch_bounds__(256) void k_moe_down(
    const float* __restrict__ act, const float* __restrict__ Wd0,
    const int* __restrict__ cnt, const int* __restrict__ lists,
    const float* __restrict__ wtok, float* __restrict__ out)
{
    int e = blockIdx.z;
    int n = cnt[e];
    int m0 = blockIdx.y * 64;
    if (m0 >= n) return;
    int n0 = blockIdx.x * 64;
    const float* Wd = Wd0 + (size_t)e * HID * DM;
    __shared__ __align__(16) float As[16][68];
    __shared__ __align__(16) float Bs[16][68];
    __shared__ int rowid[64];
    int tid = threadIdx.x;
    if (tid < 64) rowid[tid] = lists[(size_t)e * T + ((m0 + tid < n) ? (m0 + tid) : 0)];
    __syncthreads();
    int lar = tid >> 2, lak = (tid & 3) * 4;
    int lbk = tid >> 4, lbc = (tid & 15) * 4;
    int trow = tid >> 4, tcol = tid & 15;
    int rowA = rowid[lar];
    float acc[4][4] = {};
    for (int k0 = 0; k0 < HID; k0 += 16) {
        f32x4 av = *(const f32x4*)&act[(size_t)rowA * HID + k0 + lak];
        f32x4 bv = *(const f32x4*)&Wd[(size_t)(k0 + lbk) * DM + n0 + lbc];
        __syncthreads();
        #pragma unroll
        for (int q2 = 0; q2 < 4; ++q2) As[lak + q2][lar] = av[q2];
        *(f32x4*)&Bs[lbk][lbc] = bv;
        __syncthreads();
        #pragma unroll
        for (int kk = 0; kk < 16; ++kk) {
            f32x4 a = *(const f32x4*)&As[kk][trow * 4];
            f32x4 bq = *(const f32x4*)&Bs[kk][tcol * 4];
            #pragma unroll
            for (int i = 0; i < 4; ++i)
                #pragma unroll
                for (int j = 0; j < 4; ++j) acc[i][j] += a[i] * bq[j];
        }
    }
    #pragma unroll
    for (int i = 0; i < 4; ++i) {
        if (m0 + trow * 4 + i >= n) continue;
        int token = rowid[trow * 4 + i];
        float w = wtok[token];
        int bt = token / SEQ, st = token % SEQ;
        #pragma unroll
        for (int j = 0; j < 4; ++j)
            out[(size_t)st * (BATCH * DM) + bt * DM + n0 + tcol * 4 + j] = acc[i][j] * w;
    }
}

// ---------------------------------------------------------------------------
// K7: shared gate+up (dense) -> act_s
// ---------------------------------------------------------------------------
__global__ __launch_bounds__(256) void k_sh_gu(
    const float* __restrict__ X, const float* __restrict__ Wg,
    const float* __restrict__ Wu, float* __restrict__ act)
{
    __shared__ __align__(16) float As[16][68];
    __shared__ __align__(16) float Bg[16][68];
    __shared__ __align__(16) float Bu[16][68];
    int n0 = blockIdx.x * 64, m0 = blockIdx.y * 64;
    int tid = threadIdx.x;
    int lar = tid >> 2, lak = (tid & 3) * 4;
    int lbk = tid >> 4, lbc = (tid & 15) * 4;
    int trow = tid >> 4, tcol = tid & 15;
    float ag[4][4] = {}, au[4][4] = {};
    for (int k0 = 0; k0 < DM; k0 += 16) {
        f32x4 av = *(const f32x4*)&X[(size_t)(m0 + lar) * DM + k0 + lak];
        f32x4 bg = *(const f32x4*)&Wg[(size_t)(k0 + lbk) * HID + n0 + lbc];
        f32x4 bu = *(const f32x4*)&Wu[(size_t)(k0 + lbk) * HID + n0 + lbc];
        __syncthreads();
        #pragma unroll
        for (int q2 = 0; q2 < 4; ++q2) As[lak + q2][lar] = av[q2];
        *(f32x4*)&Bg[lbk][lbc] = bg;
        *(f32x4*)&Bu[lbk][lbc] = bu;
        __syncthreads();
        #pragma unroll
        for (int kk = 0; kk < 16; ++kk) {
            f32x4 a = *(const f32x4*)&As[kk][trow * 4];
            f32x4 g = *(const f32x4*)&Bg[kk][tcol * 4];
            f32x4 u = *(const f32x4*)&Bu[kk][tcol * 4];
            #pragma unroll
            for (int i = 0; i < 4; ++i)
                #pragma unroll
                for (int j = 0; j < 4; ++j) { ag[i][j] += a[i] * g[j]; au[i][j] += a[i] * u[j]; }
        }
    }
    #pragma unroll
    for (int i = 0; i < 4; ++i)
        #pragma unroll
        for (int j = 0; j < 4; ++j) {
            float g = ag[i][j], u = au[i][j];
            act[(size_t)(m0 + trow * 4 + i) * HID + n0 + tcol * 4 + j] = g * sigmoidf_(g) * u;
        }
}

// ---------------------------------------------------------------------------
// K8: shared down (dense) -> out +=
// ---------------------------------------------------------------------------
__global__ __launch_bounds__(256) void k_sh_down(
    const float* __restrict__ act, const float* __restrict__ Wd, float* __restrict__ out)
{
    __shared__ __align__(16) float As[16][68];
    __shared__ __align__(16) float Bs[16][68];
    int n0 = blockIdx.x * 64, m0 = blockIdx.y * 64;
    int tid = threadIdx.x;
    int lar = tid >> 2, lak = (tid & 3) * 4;
    int lbk = tid >> 4, lbc = (tid & 15) * 4;
    int trow = tid >> 4, tcol = tid & 15;
    float acc[4][4] = {};
    for (int k0 = 0; k0 < HID; k0 += 16) {
        f32x4 av = *(const f32x4*)&act[(size_t)(m0 + lar) * HID + k0 + lak];
        f32x4 bv = *(const f32x4*)&Wd[(size_t)(k0 + lbk) * DM + n0 + lbc];
        __syncthreads();
        #pragma unroll
        for (int q2 = 0; q2 < 4; ++q2) As[lak + q2][lar] = av[q2];
        *(f32x4*)&Bs[lbk][lbc] = bv;
        __syncthreads();
        #pragma unroll
        for (int kk = 0; kk < 16; ++kk) {
            f32x4 a = *(const f32x4*)&As[kk][trow * 4];
            f32x4 bq = *(const f32x4*)&Bs[kk][tcol * 4];
            #pragma unroll
            for (int i = 0; i < 4; ++i)
                #pragma unroll
                for (int j = 0; j < 4; ++j) acc[i][j] += a[i] * bq[j];
        }
    }
    #pragma unroll
    for (int i = 0; i < 4; ++i) {
        int t = m0 + trow * 4 + i;
        int bt = t / SEQ, st = t % SEQ;
        #pragma unroll
        for (int j = 0; j < 4; ++j)
            out[(size_t)st * (BATCH * DM) + bt * DM + n0 + tcol * 4 + j] += acc[i][j];
    }
}

// ---------------------------------------------------------------------------
extern "C" void kernel_launch(void* const* d_in, const int* in_sizes, int n_in,
                              void* d_out, int out_size, void* d_ws, size_t ws_size,
                              hipStream_t stream) {
    (void)in_sizes; (void)n_in; (void)out_size; (void)ws_size;
    const float* dec      = (const float*)d_in[0];
    const float* wq_a     = (const float*)d_in[1];
    const float* q_norm_w = (const float*)d_in[2];
    const float* wq_b     = (const float*)d_in[3];
    const float* wkv_a    = (const float*)d_in[4];
    const float* kv_norm_w= (const float*)d_in[5];
    const float* wkv_b    = (const float*)d_in[6];
    const float* wo       = (const float*)d_in[7];
    const float* gate_w   = (const float*)d_in[8];
    const float* exp_gate = (const float*)d_in[9];
    const float* exp_up   = (const float*)d_in[10];
    const float* exp_down = (const float*)d_in[11];
    const float* sh_gate  = (const float*)d_in[12];
    const float* sh_up    = (const float*)d_in[13];
    const float* sh_down  = (const float*)d_in[14];
    float* out = (float*)d_out;

    float* ws = (float*)d_ws;
    const size_t BUF = (size_t)T * DM;   // 2M floats
    float* qb = ws;            // q (roped)          | later reused as act_r
    float* kb = ws + BUF;      // k_nope + roped pe  | later reused as act_s
    float* vb = ws + 2 * BUF;  // v                  | later reused as y
    float* ab = ws + 3 * BUF;  // attn out
    float* yb = vb;            // y = attn @ wo  (vb dead after attention)
    float* act_r = qb;
    float* act_s = kb;
    int*   cnt   = (int*)(ws + 4 * BUF);
    int*   lists = cnt + 8;
    float* wtok  = (float*)(lists + NEXP * T);

    hipMemsetAsync(cnt, 0, NEXP * sizeof(int), stream);

    k_proj<<<T, 256, 0, stream>>>(dec, wq_a, q_norm_w, wq_b, wkv_a, kv_norm_w, wkv_b,
                                  qb, kb, vb);
    k_attn<<<dim3(SEQ / 64, NH, BATCH), 256, 0, stream>>>(qb, kb, vb, ab);
    k_gemm_wo<<<dim3(DM / 64, T / 64), 256, 0, stream>>>(ab, wo, yb);
    k_gate<<<T / 4, 256, 0, stream>>>(yb, gate_w, cnt, lists, wtok);
    k_moe_gu<<<dim3(HID / 64, T / 64, NEXP), 256, 0, stream>>>(yb, exp_gate, exp_up,
                                                               cnt, lists, act_r);
    k_moe_down<<<dim3(DM / 64, T / 64, NEXP), 256, 0, stream>>>(act_r, exp_down,
                                                                cnt, lists, wtok, out);
    k_sh_gu<<<dim3(HID / 64, T / 64), 256, 0, stream>>>(yb, sh_gate, sh_up, act_s);
    k_sh_down<<<dim3(DM / 64, T / 64), 256, 0, stream>>>(act_s, sh_down, out);
}

// Round 2
// 288.349 us; speedup vs baseline: 3.0792x; 3.0792x over previous
//
#include <hip/hip_runtime.h>
#include <hip/hip_bf16.h>
#include <math.h>

#define SEQ 1024
#define BATCH 2
#define T 2048
#define DM 1024
#define NH 16
#define NOPE 32
#define HD 64
#define QL 20
#define KVL 20
#define KVA 52
#define HID 1024
#define NEXP 4

typedef short bf16x8 __attribute__((ext_vector_type(8)));
typedef float f32x4 __attribute__((ext_vector_type(4)));
typedef __hip_bfloat16 bf16;

static __device__ __forceinline__ float sigmoidf_(float x) {
    return 1.0f / (1.0f + __expf(-x));
}

// ---------------------------------------------------------------------------
// Transpose + fp32->bf16 convert: in [R][C] -> outT [C][R]  (per z slice)
// ---------------------------------------------------------------------------
__global__ __launch_bounds__(256) void k_cvt_t(
    const float* __restrict__ in, bf16* __restrict__ outT, int R, int C)
{
    __shared__ float tile[32][33];
    long z = blockIdx.z;
    in   += z * (long)R * C;
    outT += z * (long)R * C;
    int c0 = blockIdx.x * 32, r0 = blockIdx.y * 32;
    int tx = threadIdx.x, ty = threadIdx.y;
    for (int i = ty; i < 32; i += 8)
        tile[i][tx] = in[(size_t)(r0 + i) * C + c0 + tx];
    __syncthreads();
    for (int i = ty; i < 32; i += 8)
        outT[(size_t)(c0 + i) * R + r0 + tx] = __float2bfloat16(tile[tx][i]);
}

// ---------------------------------------------------------------------------
// K1: per-token LoRA projections + RMS + RoPE -> bf16 q/k/v
// ---------------------------------------------------------------------------
__global__ __launch_bounds__(256) void k_proj(
    const float* __restrict__ dec, const float* __restrict__ wq_a,
    const float* __restrict__ q_norm_w, const float* __restrict__ wq_b,
    const float* __restrict__ wkv_a, const float* __restrict__ kv_norm_w,
    const float* __restrict__ wkv_b,
    bf16* __restrict__ qb, bf16* __restrict__ kb, bf16* __restrict__ vb)
{
    __shared__ float xrow[DM];
    __shared__ float sval[72];   // 0..19 q_lora ; 20..39 ckv ; 40..71 k_pe raw
    __shared__ float nrm[40];
    __shared__ float fac[2];
    __shared__ float qrow[DM];

    int t = blockIdx.x;
    int b = t / SEQ, s = t % SEQ;
    int tid = threadIdx.x;

    for (int j = tid; j < DM; j += 256)
        xrow[j] = dec[(size_t)s * (BATCH * DM) + b * DM + j];
    __syncthreads();

    if (tid < 72) {
        const float* w; int stride, col;
        if (tid < 20) { w = wq_a; stride = QL; col = tid; }
        else          { w = wkv_a; stride = KVA; col = tid - 20; }
        float a0 = 0.f, a1 = 0.f, a2 = 0.f, a3 = 0.f;
        for (int k = 0; k < DM; k += 4) {
            a0 += xrow[k]     * w[(size_t)(k)     * stride + col];
            a1 += xrow[k + 1] * w[(size_t)(k + 1) * stride + col];
            a2 += xrow[k + 2] * w[(size_t)(k + 2) * stride + col];
            a3 += xrow[k + 3] * w[(size_t)(k + 3) * stride + col];
        }
        sval[tid] = (a0 + a1) + (a2 + a3);
    }
    __syncthreads();

    if (tid < 2) {
        int base = (tid == 0) ? 0 : 20;
        float ss = 0.f;
        for (int i = 0; i < 20; ++i) { float v0 = sval[base + i]; ss += v0 * v0; }
        fac[tid] = rsqrtf(ss / 20.0f + 1e-6f);
    }
    __syncthreads();

    if (tid < 40) {
        if (tid < 20) nrm[tid] = sval[tid] * fac[0] * q_norm_w[tid];
        else          nrm[tid] = sval[tid] * fac[1] * kv_norm_w[tid - 20];
    }
    __syncthreads();

    for (int o = tid; o < DM; o += 256) {
        float acc = 0.f;
        #pragma unroll
        for (int k = 0; k < QL; ++k) acc += nrm[k] * wq_b[k * DM + o];
        qrow[o] = acc;
    }
    for (int o = tid; o < NH * 96; o += 256) {
        float acc = 0.f;
        #pragma unroll
        for (int k = 0; k < KVL; ++k) acc += nrm[20 + k] * wkv_b[k * (NH * 96) + o];
        int h = o / 96, w = o % 96;
        if (w < NOPE) kb[(size_t)t * DM + h * HD + w] = __float2bfloat16(acc);
        else          vb[(size_t)t * DM + h * HD + (w - 32)] = __float2bfloat16(acc);
    }
    __syncthreads();

    {   // RoPE for q (in LDS) and k_pe (straight to kb)
        int h = tid >> 4, r = tid & 15;
        float freq = powf(10000.0f, -(float)(h * 16 + r) / 256.0f);
        float ang = (float)s * freq;
        float cc = cosf(ang), sn = sinf(ang);
        int i0 = h * HD + NOPE + 2 * r;
        float x0 = qrow[i0], x1 = qrow[i0 + 1];
        qrow[i0]     = x0 * cc - x1 * sn;
        qrow[i0 + 1] = x0 * sn + x1 * cc;
        float y0 = sval[40 + 2 * r], y1 = sval[41 + 2 * r];
        kb[(size_t)t * DM + i0]     = __float2bfloat16(y0 * cc - y1 * sn);
        kb[(size_t)t * DM + i0 + 1] = __float2bfloat16(y0 * sn + y1 * cc);
    }
    __syncthreads();

    for (int j = tid; j < DM; j += 256) qb[(size_t)t * DM + j] = __float2bfloat16(qrow[j]);
}

// ---------------------------------------------------------------------------
// K2: bf16 MFMA flash attention. Block = (64 q rows, head, batch), 4 waves.
// LDS rows are 128B; XOR-swizzle byte^=((row&7)<<4) keeps ds_read_b128
// conflict-free.
// ---------------------------------------------------------------------------
__global__ __launch_bounds__(256) void k_attn(
    const bf16* __restrict__ qb, const bf16* __restrict__ kb,
    const bf16* __restrict__ vb, bf16* __restrict__ ab)
{
    __shared__ __align__(16) char qs[64 * 128];
    __shared__ __align__(16) char ks[64 * 128];
    __shared__ __align__(16) char vt[64 * 128];   // transposed: row=d, col=key
    __shared__ __align__(16) char ps[64 * 128];   // wave-private P rows

    const int qt = blockIdx.x, h = blockIdx.y, b = blockIdx.z;
    const int tid = threadIdx.x;
    const int lane = tid & 63, wave = tid >> 6;
    const int g = lane >> 4, c = lane & 15;
    const int wq0 = wave * 16;

    // stage Q (swizzled)
    #pragma unroll
    for (int pass = 0; pass < 2; ++pass) {
        int row = (tid >> 3) + pass * 32;
        int col8 = (tid & 7) * 8;
        int4 v = *(const int4*)&qb[(size_t)(b * SEQ + qt * 64 + row) * DM + h * HD + col8];
        *(int4*)&qs[row * 128 + ((col8 * 2) ^ ((row & 7) << 4))] = v;
    }

    f32x4 o[4] = {};
    float m_r[4], l_r[4];
    #pragma unroll
    for (int r = 0; r < 4; ++r) { m_r[r] = -1e30f; l_r[r] = 0.f; }
    __syncthreads();

    for (int kt = 0; kt < SEQ / 64; ++kt) {
        const size_t gbase = (size_t)(b * SEQ + kt * 64) * DM + h * HD;
        // K rows (b128, swizzled)
        #pragma unroll
        for (int pass = 0; pass < 2; ++pass) {
            int row = (tid >> 3) + pass * 32;
            int col8 = (tid & 7) * 8;
            int4 kv4 = *(const int4*)&kb[gbase + (size_t)row * DM + col8];
            *(int4*)&ks[row * 128 + ((col8 * 2) ^ ((row & 7) << 4))] = kv4;
        }
        // V transposed: scalar loads so swizzle index (d&7) is uniform/thread
        {
            int vd0 = tid & 7;
            #pragma unroll
            for (int pass = 0; pass < 2; ++pass) {
                int key = (tid >> 3) + pass * 32;
                const bf16* vrow = &vb[gbase + (size_t)key * DM];
                #pragma unroll
                for (int j = 0; j < 8; ++j) {
                    int d = vd0 + 8 * j;
                    *(unsigned short*)&vt[d * 128 + ((key * 2) ^ (vd0 << 4))] =
                        *(const unsigned short*)&vrow[d];
                }
            }
        }
        __syncthreads();

        // QK^T -> sc[nt] (C-layout: row q = 4g+r, col key = c+16nt)
        f32x4 sc[4] = {};
        #pragma unroll
        for (int s = 0; s < 2; ++s) {
            int arow = wq0 + c;
            bf16x8 aq = *(const bf16x8*)&qs[arow * 128 + ((64 * s + 16 * g) ^ ((arow & 7) << 4))];
            #pragma unroll
            for (int nt = 0; nt < 4; ++nt) {
                int brow = nt * 16 + c;
                bf16x8 bk = *(const bf16x8*)&ks[brow * 128 + ((64 * s + 16 * g) ^ ((brow & 7) << 4))];
                sc[nt] = __builtin_amdgcn_mfma_f32_16x16x32_bf16(aq, bk, sc[nt], 0, 0, 0);
            }
        }
        #pragma unroll
        for (int nt = 0; nt < 4; ++nt)
            #pragma unroll
            for (int r = 0; r < 4; ++r) sc[nt][r] *= 0.125f;

        // online softmax (rows 4g+r; reduce across the 16-lane col group)
        float corr[4];
        #pragma unroll
        for (int r = 0; r < 4; ++r) {
            float mt = fmaxf(fmaxf(sc[0][r], sc[1][r]), fmaxf(sc[2][r], sc[3][r]));
            mt = fmaxf(mt, __shfl_xor(mt, 1));
            mt = fmaxf(mt, __shfl_xor(mt, 2));
            mt = fmaxf(mt, __shfl_xor(mt, 4));
            mt = fmaxf(mt, __shfl_xor(mt, 8));
            float mn = fmaxf(m_r[r], mt);
            float cr = __expf(m_r[r] - mn);
            m_r[r] = mn;
            float ls = 0.f;
            #pragma unroll
            for (int nt = 0; nt < 4; ++nt) {
                float p = __expf(sc[nt][r] - mn);
                sc[nt][r] = p;
                ls += p;
            }
            ls += __shfl_xor(ls, 1); ls += __shfl_xor(ls, 2);
            ls += __shfl_xor(ls, 4); ls += __shfl_xor(ls, 8);
            l_r[r] = l_r[r] * cr + ls;
            corr[r] = cr;
        }
        #pragma unroll
        for (int nt = 0; nt < 4; ++nt)
            #pragma unroll
            for (int r = 0; r < 4; ++r) o[nt][r] *= corr[r];

        // P -> LDS (bf16, swizzled; nt rotated by g to spread banks)
        #pragma unroll
        for (int nti = 0; nti < 4; ++nti) {
            int nt = (nti + g) & 3;
            #pragma unroll
            for (int r = 0; r < 4; ++r) {
                int prow = wq0 + 4 * g + r;
                int pcol = nt * 16 + c;
                bf16 hp = __float2bfloat16(sc[nt][r]);
                *(unsigned short*)&ps[prow * 128 + ((pcol * 2) ^ ((prow & 7) << 4))] =
                    *(unsigned short*)&hp;
            }
        }

        // PV (ps is wave-private; per-wave DS ordering suffices)
        #pragma unroll
        for (int s = 0; s < 2; ++s) {
            int arow = wq0 + c;
            bf16x8 pa = *(const bf16x8*)&ps[arow * 128 + ((64 * s + 16 * g) ^ ((arow & 7) << 4))];
            #pragma unroll
            for (int ntd = 0; ntd < 4; ++ntd) {
                int brow = ntd * 16 + c;
                bf16x8 bv = *(const bf16x8*)&vt[brow * 128 + ((64 * s + 16 * g) ^ ((brow & 7) << 4))];
                o[ntd] = __builtin_amdgcn_mfma_f32_16x16x32_bf16(pa, bv, o[ntd], 0, 0, 0);
            }
        }
        __syncthreads();
    }

    #pragma unroll
    for (int r = 0; r < 4; ++r) l_r[r] = 1.0f / l_r[r];
    int qrow = b * SEQ + qt * 64 + wq0 + 4 * g;
    #pragma unroll
    for (int nt = 0; nt < 4; ++nt)
        #pragma unroll
        for (int r = 0; r < 4; ++r)
            ab[(size_t)(qrow + r) * DM + h * HD + nt * 16 + c] =
                __float2bfloat16(o[nt][r] * l_r[r]);
}

// ---------------------------------------------------------------------------
// GEMM geometry shared by all matmuls: BM=128, BN=64, BK=32, 4 waves (2x2),
// per wave 64x32 out = 4x2 frags of 16x16x32 MFMA. LDS rows 64B -> no bank
// conflicts without swizzle. Register prefetch pipelines global loads.
// ---------------------------------------------------------------------------
__global__ __launch_bounds__(256) void k_mm_plain(
    const bf16* __restrict__ A, const bf16* __restrict__ Bt, bf16* __restrict__ C)
{
    __shared__ __align__(16) char As[128 * 64];
    __shared__ __align__(16) char Bs[64 * 64];
    const int tid = threadIdx.x;
    const int lane = tid & 63, wave = tid >> 6;
    const int g = lane >> 4, c = lane & 15;
    const int wm = wave >> 1, wn = wave & 1;
    const int m0 = blockIdx.y * 128, n0 = blockIdx.x * 64;
    const int sr = tid >> 2, scol = (tid & 3) * 8;

    size_t aoff0 = (size_t)(m0 + sr) * DM + scol;
    size_t aoff1 = aoff0 + (size_t)64 * DM;
    size_t boff  = (size_t)(n0 + sr) * DM + scol;
    int4 a0 = *(const int4*)&A[aoff0];
    int4 a1 = *(const int4*)&A[aoff1];
    int4 b0 = *(const int4*)&Bt[boff];

    f32x4 acc[4][2] = {};
    for (int k0 = 0; k0 < DM; k0 += 32) {
        __syncthreads();
        *(int4*)&As[sr * 64 + (tid & 3) * 16] = a0;
        *(int4*)&As[4096 + sr * 64 + (tid & 3) * 16] = a1;
        *(int4*)&Bs[sr * 64 + (tid & 3) * 16] = b0;
        __syncthreads();
        if (k0 + 32 < DM) {
            a0 = *(const int4*)&A[aoff0 + k0 + 32];
            a1 = *(const int4*)&A[aoff1 + k0 + 32];
            b0 = *(const int4*)&Bt[boff + k0 + 32];
        }
        bf16x8 af[4], bfx[2];
        #pragma unroll
        for (int mi = 0; mi < 4; ++mi)
            af[mi] = *(const bf16x8*)&As[(wm * 64 + mi * 16 + c) * 64 + 16 * g];
        #pragma unroll
        for (int ni = 0; ni < 2; ++ni)
            bfx[ni] = *(const bf16x8*)&Bs[(wn * 32 + ni * 16 + c) * 64 + 16 * g];
        #pragma unroll
        for (int mi = 0; mi < 4; ++mi)
            #pragma unroll
            for (int ni = 0; ni < 2; ++ni)
                acc[mi][ni] = __builtin_amdgcn_mfma_f32_16x16x32_bf16(af[mi], bfx[ni], acc[mi][ni], 0, 0, 0);
    }
    #pragma unroll
    for (int mi = 0; mi < 4; ++mi)
        #pragma unroll
        for (int ni = 0; ni < 2; ++ni)
            #pragma unroll
            for (int r = 0; r < 4; ++r)
                C[(size_t)(m0 + wm * 64 + mi * 16 + 4 * g + r) * DM + n0 + wn * 32 + ni * 16 + c]
                    = __float2bfloat16(acc[mi][ni][r]);
}

template<bool ROUTED>
__global__ __launch_bounds__(256) void k_mm_gu(
    const bf16* __restrict__ X, const bf16* __restrict__ BgT,
    const bf16* __restrict__ BuT, const int* __restrict__ cnt,
    const int* __restrict__ lists, bf16* __restrict__ act)
{
    const int e = blockIdx.z;
    const int ntok = ROUTED ? cnt[e] : T;
    const int m0 = blockIdx.y * 128;
    if (m0 >= ntok) return;
    const int n0 = blockIdx.x * 64;
    __shared__ __align__(16) char As[128 * 64];
    __shared__ __align__(16) char Bg[64 * 64];
    __shared__ __align__(16) char Bu[64 * 64];
    __shared__ int rowid[128];
    const int tid = threadIdx.x;
    if (tid < 128) {
        int idx = m0 + tid;
        rowid[tid] = ROUTED ? lists[e * T + (idx < ntok ? idx : ntok - 1)] : idx;
    }
    __syncthreads();
    const int lane = tid & 63, wave = tid >> 6;
    const int g = lane >> 4, c = lane & 15;
    const int wm = wave >> 1, wn = wave & 1;
    const int sr = tid >> 2, scol = (tid & 3) * 8;
    const int ra = rowid[sr], rb = rowid[64 + sr];
    const bf16* Bge = BgT + (ROUTED ? (size_t)e * HID * DM : 0);
    const bf16* Bue = BuT + (ROUTED ? (size_t)e * HID * DM : 0);
    size_t aoff0 = (size_t)ra * DM + scol;
    size_t aoff1 = (size_t)rb * DM + scol;
    size_t boff  = (size_t)(n0 + sr) * DM + scol;
    int4 a0 = *(const int4*)&X[aoff0];
    int4 a1 = *(const int4*)&X[aoff1];
    int4 g0 = *(const int4*)&Bge[boff];
    int4 u0 = *(const int4*)&Bue[boff];

    f32x4 accg[4][2] = {}, accu[4][2] = {};
    for (int k0 = 0; k0 < DM; k0 += 32) {
        __syncthreads();
        *(int4*)&As[sr * 64 + (tid & 3) * 16] = a0;
        *(int4*)&As[4096 + sr * 64 + (tid & 3) * 16] = a1;
        *(int4*)&Bg[sr * 64 + (tid & 3) * 16] = g0;
        *(int4*)&Bu[sr * 64 + (tid & 3) * 16] = u0;
        __syncthreads();
        if (k0 + 32 < DM) {
            a0 = *(const int4*)&X[aoff0 + k0 + 32];
            a1 = *(const int4*)&X[aoff1 + k0 + 32];
            g0 = *(const int4*)&Bge[boff + k0 + 32];
            u0 = *(const int4*)&Bue[boff + k0 + 32];
        }
        bf16x8 af[4], gf[2], uf[2];
        #pragma unroll
        for (int mi = 0; mi < 4; ++mi)
            af[mi] = *(const bf16x8*)&As[(wm * 64 + mi * 16 + c) * 64 + 16 * g];
        #pragma unroll
        for (int ni = 0; ni < 2; ++ni) {
            gf[ni] = *(const bf16x8*)&Bg[(wn * 32 + ni * 16 + c) * 64 + 16 * g];
            uf[ni] = *(const bf16x8*)&Bu[(wn * 32 + ni * 16 + c) * 64 + 16 * g];
        }
        #pragma unroll
        for (int mi = 0; mi < 4; ++mi)
            #pragma unroll
            for (int ni = 0; ni < 2; ++ni) {
                accg[mi][ni] = __builtin_amdgcn_mfma_f32_16x16x32_bf16(af[mi], gf[ni], accg[mi][ni], 0, 0, 0);
                accu[mi][ni] = __builtin_amdgcn_mfma_f32_16x16x32_bf16(af[mi], uf[ni], accu[mi][ni], 0, 0, 0);
            }
    }
    #pragma unroll
    for (int mi = 0; mi < 4; ++mi)
        #pragma unroll
        for (int ni = 0; ni < 2; ++ni)
            #pragma unroll
            for (int r = 0; r < 4; ++r) {
                int lr = wm * 64 + mi * 16 + 4 * g + r;
                if (ROUTED && m0 + lr >= ntok) continue;
                int token = rowid[lr];
                float gv = accg[mi][ni][r], uv = accu[mi][ni][r];
                act[(size_t)token * HID + n0 + wn * 32 + ni * 16 + c] =
                    __float2bfloat16(gv * sigmoidf_(gv) * uv);
            }
}

template<bool ROUTED>
__global__ __launch_bounds__(256) void k_mm_down(
    const bf16* __restrict__ Xact, const bf16* __restrict__ BdT,
    const int* __restrict__ cnt, const int* __restrict__ lists,
    const float* __restrict__ wtok, float* __restrict__ out)
{
    const int e = blockIdx.z;
    const int ntok = ROUTED ? cnt[e] : T;
    const int m0 = blockIdx.y * 128;
    if (m0 >= ntok) return;
    const int n0 = blockIdx.x * 64;
    __shared__ __align__(16) char As[128 * 64];
    __shared__ __align__(16) char Bs[64 * 64];
    __shared__ int rowid[128];
    const int tid = threadIdx.x;
    if (tid < 128) {
        int idx = m0 + tid;
        rowid[tid] = ROUTED ? lists[e * T + (idx < ntok ? idx : ntok - 1)] : idx;
    }
    __syncthreads();
    const int lane = tid & 63, wave = tid >> 6;
    const int g = lane >> 4, c = lane & 15;
    const int wm = wave >> 1, wn = wave & 1;
    const int sr = tid >> 2, scol = (tid & 3) * 8;
    const int ra = rowid[sr], rb = rowid[64 + sr];
    const bf16* Bde = BdT + (ROUTED ? (size_t)e * HID * DM : 0);
    size_t aoff0 = (size_t)ra * HID + scol;
    size_t aoff1 = (size_t)rb * HID + scol;
    size_t boff  = (size_t)(n0 + sr) * HID + scol;
    int4 a0 = *(const int4*)&Xact[aoff0];
    int4 a1 = *(const int4*)&Xact[aoff1];
    int4 b0 = *(const int4*)&Bde[boff];

    f32x4 acc[4][2] = {};
    for (int k0 = 0; k0 < HID; k0 += 32) {
        __syncthreads();
        *(int4*)&As[sr * 64 + (tid & 3) * 16] = a0;
        *(int4*)&As[4096 + sr * 64 + (tid & 3) * 16] = a1;
        *(int4*)&Bs[sr * 64 + (tid & 3) * 16] = b0;
        __syncthreads();
        if (k0 + 32 < HID) {
            a0 = *(const int4*)&Xact[aoff0 + k0 + 32];
            a1 = *(const int4*)&Xact[aoff1 + k0 + 32];
            b0 = *(const int4*)&Bde[boff + k0 + 32];
        }
        bf16x8 af[4], bfx[2];
        #pragma unroll
        for (int mi = 0; mi < 4; ++mi)
            af[mi] = *(const bf16x8*)&As[(wm * 64 + mi * 16 + c) * 64 + 16 * g];
        #pragma unroll
        for (int ni = 0; ni < 2; ++ni)
            bfx[ni] = *(const bf16x8*)&Bs[(wn * 32 + ni * 16 + c) * 64 + 16 * g];
        #pragma unroll
        for (int mi = 0; mi < 4; ++mi)
            #pragma unroll
            for (int ni = 0; ni < 2; ++ni)
                acc[mi][ni] = __builtin_amdgcn_mfma_f32_16x16x32_bf16(af[mi], bfx[ni], acc[mi][ni], 0, 0, 0);
    }
    #pragma unroll
    for (int mi = 0; mi < 4; ++mi)
        #pragma unroll
        for (int ni = 0; ni < 2; ++ni)
            #pragma unroll
            for (int r = 0; r < 4; ++r) {
                int lr = wm * 64 + mi * 16 + 4 * g + r;
                if (ROUTED && m0 + lr >= ntok) continue;
                int token = rowid[lr];
                int bt = token >> 10, st = token & (SEQ - 1);
                size_t oo = (size_t)st * (BATCH * DM) + bt * DM + n0 + wn * 32 + ni * 16 + c;
                if (ROUTED) out[oo] = acc[mi][ni][r] * wtok[token];
                else        out[oo] += acc[mi][ni][r];
            }
}

// ---------------------------------------------------------------------------
// Gating: softmax over 4 experts; group logic degenerates to plain top-1.
// ---------------------------------------------------------------------------
__global__ __launch_bounds__(256) void k_gate(
    const bf16* __restrict__ y, const float* __restrict__ gw,
    int* __restrict__ cnt, int* __restrict__ lists, float* __restrict__ wtok)
{
    int warp = threadIdx.x >> 6, lane = threadIdx.x & 63;
    int t = blockIdx.x * 4 + warp;
    float acc[NEXP] = {};
    for (int d = lane; d < DM; d += 64) {
        float xv = __bfloat162float(y[(size_t)t * DM + d]);
        #pragma unroll
        for (int e = 0; e < NEXP; ++e) acc[e] += xv * gw[e * DM + d];
    }
    #pragma unroll
    for (int off = 32; off; off >>= 1)
        #pragma unroll
        for (int e = 0; e < NEXP; ++e) acc[e] += __shfl_xor(acc[e], off);
    if (lane == 0) {
        float mx = fmaxf(fmaxf(acc[0], acc[1]), fmaxf(acc[2], acc[3]));
        float ex[NEXP], ssum = 0.f;
        #pragma unroll
        for (int e = 0; e < NEXP; ++e) { ex[e] = __expf(acc[e] - mx); ssum += ex[e]; }
        int best = 0; float bv = ex[0];
        #pragma unroll
        for (int e = 1; e < NEXP; ++e) if (ex[e] > bv) { bv = ex[e]; best = e; }
        wtok[t] = bv / ssum;
        int pos = atomicAdd(&cnt[best], 1);
        lists[best * T + pos] = t;
    }
}

// ---------------------------------------------------------------------------
extern "C" void kernel_launch(void* const* d_in, const int* in_sizes, int n_in,
                              void* d_out, int out_size, void* d_ws, size_t ws_size,
                              hipStream_t stream) {
    (void)in_sizes; (void)n_in; (void)out_size; (void)ws_size;
    const float* dec      = (const float*)d_in[0];
    const float* wq_a     = (const float*)d_in[1];
    const float* q_norm_w = (const float*)d_in[2];
    const float* wq_b     = (const float*)d_in[3];
    const float* wkv_a    = (const float*)d_in[4];
    const float* kv_norm_w= (const float*)d_in[5];
    const float* wkv_b    = (const float*)d_in[6];
    const float* wo       = (const float*)d_in[7];
    const float* gate_w   = (const float*)d_in[8];
    const float* exp_gate = (const float*)d_in[9];
    const float* exp_up   = (const float*)d_in[10];
    const float* exp_down = (const float*)d_in[11];
    const float* sh_gate  = (const float*)d_in[12];
    const float* sh_up    = (const float*)d_in[13];
    const float* sh_down  = (const float*)d_in[14];
    float* out = (float*)d_out;

    char* W = (char*)d_ws;
    bf16* qb  = (bf16*)(W);                    // 4MB; reused as y
    bf16* kb  = (bf16*)(W + (4ull  << 20));    // 4MB; reused as act_r
    bf16* vb  = (bf16*)(W + (8ull  << 20));    // 4MB; reused as act_s
    bf16* ab  = (bf16*)(W + (12ull << 20));    // 4MB
    bf16* woT = (bf16*)(W + (16ull << 20));    // 2MB
    bf16* sgT = (bf16*)(W + (18ull << 20));    // 2MB
    bf16* suT = (bf16*)(W + (20ull << 20));    // 2MB
    bf16* sdT = (bf16*)(W + (22ull << 20));    // 2MB
    bf16* egT = (bf16*)(W + (24ull << 20));    // 8MB
    bf16* euT = (bf16*)(W + (32ull << 20));    // 8MB
    bf16* edT = (bf16*)(W + (40ull << 20));    // 8MB
    int*   cnt   = (int*)(W + (48ull << 20));
    int*   lists = cnt + 16;
    float* wtok  = (float*)(lists + NEXP * T);
    bf16* yb    = qb;
    bf16* act_r = kb;
    bf16* act_s = vb;

    hipMemsetAsync(cnt, 0, 16 * sizeof(int), stream);

    dim3 tb(32, 8);
    k_cvt_t<<<dim3(32, 32, 1), tb, 0, stream>>>(wo,       woT, 1024, 1024);
    k_cvt_t<<<dim3(32, 32, 1), tb, 0, stream>>>(sh_gate,  sgT, 1024, 1024);
    k_cvt_t<<<dim3(32, 32, 1), tb, 0, stream>>>(sh_up,    suT, 1024, 1024);
    k_cvt_t<<<dim3(32, 32, 1), tb, 0, stream>>>(sh_down,  sdT, 1024, 1024);
    k_cvt_t<<<dim3(32, 32, 4), tb, 0, stream>>>(exp_gate, egT, 1024, 1024);
    k_cvt_t<<<dim3(32, 32, 4), tb, 0, stream>>>(exp_up,   euT, 1024, 1024);
    k_cvt_t<<<dim3(32, 32, 4), tb, 0, stream>>>(exp_down, edT, 1024, 1024);

    k_proj<<<T, 256, 0, stream>>>(dec, wq_a, q_norm_w, wq_b, wkv_a, kv_norm_w, wkv_b,
                                  qb, kb, vb);
    k_attn<<<dim3(SEQ / 64, NH, BATCH), 256, 0, stream>>>(qb, kb, vb, ab);
    k_mm_plain<<<dim3(DM / 64, T / 128), 256, 0, stream>>>(ab, woT, yb);
    k_gate<<<T / 4, 256, 0, stream>>>(yb, gate_w, cnt, lists, wtok);
    k_mm_gu<true><<<dim3(HID / 64, T / 128, NEXP), 256, 0, stream>>>(yb, egT, euT, cnt, lists, act_r);
    k_mm_down<true><<<dim3(DM / 64, T / 128, NEXP), 256, 0, stream>>>(act_r, edT, cnt, lists, wtok, out);
    k_mm_gu<false><<<dim3(HID / 64, T / 128, 1), 256, 0, stream>>>(yb, sgT, suT, cnt, lists, act_s);
    k_mm_down<false><<<dim3(DM / 64, T / 128, 1), 256, 0, stream>>>(act_s, sdT, cnt, lists, wtok, out);
}

// Round 3
// 256.343 us; speedup vs baseline: 3.4636x; 1.1249x over previous
//
#include <hip/hip_runtime.h>
#include <hip/hip_bf16.h>
#include <math.h>

#define SEQ 1024
#define BATCH 2
#define T 2048
#define DM 1024
#define NH 16
#define NOPE 32
#define HD 64
#define QL 20
#define KVL 20
#define KVA 52
#define HID 1024
#define NEXP 4

typedef short bf16x8 __attribute__((ext_vector_type(8)));
typedef float f32x4 __attribute__((ext_vector_type(4)));
typedef __hip_bfloat16 bf16;

static __device__ __forceinline__ float sigmoidf_(float x) {
    return 1.0f / (1.0f + __expf(-x));
}
static __device__ __forceinline__ unsigned short bfbits(float x) {
    bf16 h = __float2bfloat16(x);
    return *reinterpret_cast<unsigned short*>(&h);
}

// ---------------------------------------------------------------------------
// Transpose + fp32->bf16: in [R][C] -> outT [C][R] (per z). ushort4 stores.
// ---------------------------------------------------------------------------
__global__ __launch_bounds__(256) void k_cvt_t(
    const float* __restrict__ in, bf16* __restrict__ outT, int R, int C)
{
    __shared__ float tile[32][33];
    long z = blockIdx.z;
    in   += z * (long)R * C;
    outT += z * (long)R * C;
    int c0 = blockIdx.x * 32, r0 = blockIdx.y * 32;
    int tid = threadIdx.x;
    int tx = tid & 31, ty = tid >> 5;
    #pragma unroll
    for (int ii = 0; ii < 4; ++ii)
        tile[ty + ii * 8][tx] = in[(size_t)(r0 + ty + ii * 8) * C + c0 + tx];
    __syncthreads();
    int c = tid >> 3, rg = (tid & 7) * 4;
    ushort4 o;
    o.x = bfbits(tile[rg + 0][c]);
    o.y = bfbits(tile[rg + 1][c]);
    o.z = bfbits(tile[rg + 2][c]);
    o.w = bfbits(tile[rg + 3][c]);
    *(ushort4*)&outT[(size_t)(c0 + c) * R + r0 + rg] = o;
}

// ---------------------------------------------------------------------------
// k_prep: tiny transposed bf16 weights.
// z=0: loraT[80][1024]  (cols 0..19 wq_a, 20..71 wkv_a, 72..79 zero)
// z=1: wqbT[1024][32]   (k 0..19 = wq_b[k][n], else 0)
// z=2: wkvbT[1536][32]
// ---------------------------------------------------------------------------
__global__ __launch_bounds__(256) void k_prep(
    const float* __restrict__ wq_a, const float* __restrict__ wkv_a,
    const float* __restrict__ wq_b, const float* __restrict__ wkv_b,
    bf16* __restrict__ loraT, bf16* __restrict__ wqbT, bf16* __restrict__ wkvbT)
{
    int z = blockIdx.z;
    int idx = blockIdx.x * 256 + threadIdx.x;
    if (z == 0) {
        if (idx >= 80 * 1024) return;
        int n = idx >> 10, k = idx & 1023;
        float v = (n < 20) ? wq_a[k * QL + n] : (n < 72 ? wkv_a[k * KVA + (n - 20)] : 0.f);
        loraT[idx] = __float2bfloat16(v);
    } else if (z == 1) {
        if (idx >= 1024 * 32) return;
        int n = idx >> 5, k = idx & 31;
        float v = (k < 20) ? wq_b[k * DM + n] : 0.f;
        wqbT[idx] = __float2bfloat16(v);
    } else {
        if (idx >= 1536 * 32) return;
        int n = idx >> 5, k = idx & 31;
        float v = (k < 20) ? wkv_b[k * (NH * 96) + n] : 0.f;
        wkvbT[idx] = __float2bfloat16(v);
    }
}

// ---------------------------------------------------------------------------
// k_freqs: cos/sin tables [SEQ][256], pair index p = h*16 + r
// ---------------------------------------------------------------------------
__global__ __launch_bounds__(256) void k_freqs(
    float* __restrict__ ctab, float* __restrict__ stab)
{
    int s = blockIdx.x, p = threadIdx.x;
    float freq = exp2f(-(float)p * (13.287712379549449f / 256.0f));
    float ang = (float)s * freq;
    float sn, cs;
    __sincosf(ang, &sn, &cs);
    ctab[s * 256 + p] = cs;
    stab[s * 256 + p] = sn;
}

// ---------------------------------------------------------------------------
// k_p1: lora[T][72] = dec @ [wq_a|wkv_a] via MFMA, K-split 4 + atomicAdd.
// A (dec fp32, [s][b][d]) converted to bf16 during staging.
// ---------------------------------------------------------------------------
__global__ __launch_bounds__(256) void k_p1(
    const float* __restrict__ dec, const bf16* __restrict__ loraT,
    float* __restrict__ lora)
{
    __shared__ __align__(16) char As[128 * 64];  // [128][32] bf16
    __shared__ __align__(16) char Bs[80 * 64];   // [80][32] bf16
    const int tid = threadIdx.x;
    const int kz = blockIdx.x;
    const int m0 = blockIdx.y * 128;
    const int lane = tid & 63, wave = tid >> 6;
    const int g = lane >> 4, c = lane & 15;
    f32x4 acc[2][5] = {};
    for (int ks = 0; ks < 8; ++ks) {
        int k0 = kz * 256 + ks * 32;
        __syncthreads();
        #pragma unroll
        for (int pass = 0; pass < 4; ++pass) {
            int row = (tid >> 3) + pass * 32;
            int t = m0 + row;
            int b = t >> 10, s = t & 1023;
            f32x4 v = *(const f32x4*)&dec[(size_t)(s * 2 + b) * DM + k0 + (tid & 7) * 4];
            ushort4 h4;
            h4.x = bfbits(v[0]); h4.y = bfbits(v[1]);
            h4.z = bfbits(v[2]); h4.w = bfbits(v[3]);
            *(ushort4*)&As[row * 64 + (tid & 7) * 8] = h4;
        }
        if (tid < 160) {
            int row = tid >> 1, hf = tid & 1;
            const bf16* src = &loraT[row * 1024 + k0 + hf * 16];
            *(int4*)&Bs[row * 64 + hf * 32]      = *(const int4*)&src[0];
            *(int4*)&Bs[row * 64 + hf * 32 + 16] = *(const int4*)&src[8];
        }
        __syncthreads();
        bf16x8 af[2], bff[5];
        #pragma unroll
        for (int mi = 0; mi < 2; ++mi)
            af[mi] = *(const bf16x8*)&As[(wave * 32 + mi * 16 + c) * 64 + 16 * g];
        #pragma unroll
        for (int nf = 0; nf < 5; ++nf)
            bff[nf] = *(const bf16x8*)&Bs[(nf * 16 + c) * 64 + 16 * g];
        #pragma unroll
        for (int mi = 0; mi < 2; ++mi)
            #pragma unroll
            for (int nf = 0; nf < 5; ++nf)
                acc[mi][nf] = __builtin_amdgcn_mfma_f32_16x16x32_bf16(af[mi], bff[nf], acc[mi][nf], 0, 0, 0);
    }
    #pragma unroll
    for (int mi = 0; mi < 2; ++mi)
        #pragma unroll
        for (int nf = 0; nf < 5; ++nf)
            #pragma unroll
            for (int r = 0; r < 4; ++r) {
                int col = nf * 16 + c;
                if (col < 72) {
                    int row = m0 + wave * 32 + mi * 16 + 4 * g + r;
                    atomicAdd(&lora[row * 72 + col], acc[mi][nf][r]);
                }
            }
}

// ---------------------------------------------------------------------------
// k_p2: RMS of lora[:,:20] and [:,20:40] -> padded bf16 nrmq/nrmkv [T][32]
// ---------------------------------------------------------------------------
__global__ __launch_bounds__(256) void k_p2(
    const float* __restrict__ lora, const float* __restrict__ qnw,
    const float* __restrict__ kvnw, bf16* __restrict__ nrmq, bf16* __restrict__ nrmkv)
{
    int t = blockIdx.x * 256 + threadIdx.x;
    float lq[20], lk[20];
    float ssq = 0.f, ssk = 0.f;
    #pragma unroll
    for (int i = 0; i < 20; ++i) { lq[i] = lora[t * 72 + i];      ssq += lq[i] * lq[i]; }
    #pragma unroll
    for (int i = 0; i < 20; ++i) { lk[i] = lora[t * 72 + 20 + i]; ssk += lk[i] * lk[i]; }
    float fq = rsqrtf(ssq / 20.f + 1e-6f);
    float fk = rsqrtf(ssk / 20.f + 1e-6f);
    #pragma unroll
    for (int i = 0; i < 32; ++i) {
        nrmq[t * 32 + i]  = __float2bfloat16(i < 20 ? lq[i] * fq * qnw[i]  : 0.f);
        nrmkv[t * 32 + i] = __float2bfloat16(i < 20 ? lk[i] * fk * kvnw[i] : 0.f);
    }
}

// ---------------------------------------------------------------------------
// k_p2b: k_pe RoPE broadcast to all heads -> kb PE region
// ---------------------------------------------------------------------------
__global__ __launch_bounds__(256) void k_p2b(
    const float* __restrict__ lora, const float* __restrict__ ctab,
    const float* __restrict__ stab, bf16* __restrict__ kb)
{
    int t = blockIdx.x, p = threadIdx.x;
    int r = p & 15, h = p >> 4, s = t & (SEQ - 1);
    float y0 = lora[t * 72 + 40 + 2 * r];
    float y1 = lora[t * 72 + 41 + 2 * r];
    float cs = ctab[s * 256 + p], sn = stab[s * 256 + p];
    ushort2 pk;
    pk.x = bfbits(y0 * cs - y1 * sn);
    pk.y = bfbits(y0 * sn + y1 * cs);
    *(ushort2*)&kb[(size_t)t * DM + h * HD + NOPE + 2 * r] = pk;
}

// ---------------------------------------------------------------------------
// k_p3q: q = nrmq @ wqbT (K=32 single step) with fused RoPE epilogue -> qb
// ---------------------------------------------------------------------------
__global__ __launch_bounds__(256) void k_p3q(
    const bf16* __restrict__ nrmq, const bf16* __restrict__ wqbT,
    const float* __restrict__ ctab, const float* __restrict__ stab,
    bf16* __restrict__ qb)
{
    __shared__ __align__(16) char As[128 * 64];
    __shared__ __align__(16) char Bs[64 * 64];
    const int tid = threadIdx.x;
    const int m0 = blockIdx.y * 128, n0 = blockIdx.x * 64;
    const int lane = tid & 63, wave = tid >> 6;
    const int g = lane >> 4, c = lane & 15;
    const int wm = wave >> 1, wn = wave & 1;
    {
        int row = tid >> 1, hf = tid & 1;
        const bf16* sa = &nrmq[(size_t)(m0 + row) * 32 + hf * 16];
        *(int4*)&As[row * 64 + hf * 32]      = *(const int4*)&sa[0];
        *(int4*)&As[row * 64 + hf * 32 + 16] = *(const int4*)&sa[8];
        int brow = tid >> 2, koff = (tid & 3) * 8;
        *(int4*)&Bs[brow * 64 + koff * 2] = *(const int4*)&wqbT[(size_t)(n0 + brow) * 32 + koff];
    }
    __syncthreads();
    f32x4 acc[4][2] = {};
    bf16x8 af[4], bfr[2];
    #pragma unroll
    for (int mi = 0; mi < 4; ++mi)
        af[mi] = *(const bf16x8*)&As[(wm * 64 + mi * 16 + c) * 64 + 16 * g];
    #pragma unroll
    for (int ni = 0; ni < 2; ++ni)
        bfr[ni] = *(const bf16x8*)&Bs[(wn * 32 + ni * 16 + c) * 64 + 16 * g];
    #pragma unroll
    for (int mi = 0; mi < 4; ++mi)
        #pragma unroll
        for (int ni = 0; ni < 2; ++ni)
            acc[mi][ni] = __builtin_amdgcn_mfma_f32_16x16x32_bf16(af[mi], bfr[ni], acc[mi][ni], 0, 0, 0);

    #pragma unroll
    for (int mi = 0; mi < 4; ++mi)
        #pragma unroll
        for (int ni = 0; ni < 2; ++ni) {
            int n = n0 + wn * 32 + ni * 16 + c;
            int w = n & 63;
            if (w < 32) {
                #pragma unroll
                for (int r = 0; r < 4; ++r) {
                    int row = m0 + wm * 64 + mi * 16 + 4 * g + r;
                    qb[(size_t)row * DM + n] = __float2bfloat16(acc[mi][ni][r]);
                }
            } else {
                int h = n >> 6;
                int pidx = h * 16 + ((w - 32) >> 1);
                int odd = w & 1;
                #pragma unroll
                for (int r = 0; r < 4; ++r) {
                    int row = m0 + wm * 64 + mi * 16 + 4 * g + r;
                    int s = row & (SEQ - 1);
                    float own = acc[mi][ni][r];
                    float oth = __shfl_xor(own, 1);
                    float cs = ctab[s * 256 + pidx], sn = stab[s * 256 + pidx];
                    float o = odd ? (oth * sn + own * cs) : (own * cs - oth * sn);
                    qb[(size_t)row * DM + n] = __float2bfloat16(o);
                }
            }
        }
}

// ---------------------------------------------------------------------------
// k_p3kv: kvb = nrmkv @ wkvbT (K=32), route cols to kb (k_nope) / vb
// ---------------------------------------------------------------------------
__global__ __launch_bounds__(256) void k_p3kv(
    const bf16* __restrict__ nrmkv, const bf16* __restrict__ wkvbT,
    bf16* __restrict__ kb, bf16* __restrict__ vb)
{
    __shared__ __align__(16) char As[128 * 64];
    __shared__ __align__(16) char Bs[64 * 64];
    const int tid = threadIdx.x;
    const int m0 = blockIdx.y * 128, n0 = blockIdx.x * 64;
    const int lane = tid & 63, wave = tid >> 6;
    const int g = lane >> 4, c = lane & 15;
    const int wm = wave >> 1, wn = wave & 1;
    {
        int row = tid >> 1, hf = tid & 1;
        const bf16* sa = &nrmkv[(size_t)(m0 + row) * 32 + hf * 16];
        *(int4*)&As[row * 64 + hf * 32]      = *(const int4*)&sa[0];
        *(int4*)&As[row * 64 + hf * 32 + 16] = *(const int4*)&sa[8];
        int brow = tid >> 2, koff = (tid & 3) * 8;
        *(int4*)&Bs[brow * 64 + koff * 2] = *(const int4*)&wkvbT[(size_t)(n0 + brow) * 32 + koff];
    }
    __syncthreads();
    f32x4 acc[4][2] = {};
    bf16x8 af[4], bfr[2];
    #pragma unroll
    for (int mi = 0; mi < 4; ++mi)
        af[mi] = *(const bf16x8*)&As[(wm * 64 + mi * 16 + c) * 64 + 16 * g];
    #pragma unroll
    for (int ni = 0; ni < 2; ++ni)
        bfr[ni] = *(const bf16x8*)&Bs[(wn * 32 + ni * 16 + c) * 64 + 16 * g];
    #pragma unroll
    for (int mi = 0; mi < 4; ++mi)
        #pragma unroll
        for (int ni = 0; ni < 2; ++ni)
            acc[mi][ni] = __builtin_amdgcn_mfma_f32_16x16x32_bf16(af[mi], bfr[ni], acc[mi][ni], 0, 0, 0);

    #pragma unroll
    for (int mi = 0; mi < 4; ++mi)
        #pragma unroll
        for (int ni = 0; ni < 2; ++ni) {
            int n = n0 + wn * 32 + ni * 16 + c;
            int h = n / 96, w = n - h * 96;
            #pragma unroll
            for (int r = 0; r < 4; ++r) {
                int row = m0 + wm * 64 + mi * 16 + 4 * g + r;
                bf16 val = __float2bfloat16(acc[mi][ni][r]);
                if (w < NOPE) kb[(size_t)row * DM + h * HD + w] = val;
                else          vb[(size_t)row * DM + h * HD + (w - NOPE)] = val;
            }
        }
}

// ---------------------------------------------------------------------------
// K2: bf16 MFMA flash attention (unchanged from r2).
// ---------------------------------------------------------------------------
__global__ __launch_bounds__(256) void k_attn(
    const bf16* __restrict__ qb, const bf16* __restrict__ kb,
    const bf16* __restrict__ vb, bf16* __restrict__ ab)
{
    __shared__ __align__(16) char qs[64 * 128];
    __shared__ __align__(16) char ks[64 * 128];
    __shared__ __align__(16) char vt[64 * 128];
    __shared__ __align__(16) char ps[64 * 128];

    const int qt = blockIdx.x, h = blockIdx.y, b = blockIdx.z;
    const int tid = threadIdx.x;
    const int lane = tid & 63, wave = tid >> 6;
    const int g = lane >> 4, c = lane & 15;
    const int wq0 = wave * 16;

    #pragma unroll
    for (int pass = 0; pass < 2; ++pass) {
        int row = (tid >> 3) + pass * 32;
        int col8 = (tid & 7) * 8;
        int4 v = *(const int4*)&qb[(size_t)(b * SEQ + qt * 64 + row) * DM + h * HD + col8];
        *(int4*)&qs[row * 128 + ((col8 * 2) ^ ((row & 7) << 4))] = v;
    }

    f32x4 o[4] = {};
    float m_r[4], l_r[4];
    #pragma unroll
    for (int r = 0; r < 4; ++r) { m_r[r] = -1e30f; l_r[r] = 0.f; }
    __syncthreads();

    for (int kt = 0; kt < SEQ / 64; ++kt) {
        const size_t gbase = (size_t)(b * SEQ + kt * 64) * DM + h * HD;
        #pragma unroll
        for (int pass = 0; pass < 2; ++pass) {
            int row = (tid >> 3) + pass * 32;
            int col8 = (tid & 7) * 8;
            int4 kv4 = *(const int4*)&kb[gbase + (size_t)row * DM + col8];
            *(int4*)&ks[row * 128 + ((col8 * 2) ^ ((row & 7) << 4))] = kv4;
        }
        {
            int vd0 = tid & 7;
            #pragma unroll
            for (int pass = 0; pass < 2; ++pass) {
                int key = (tid >> 3) + pass * 32;
                const bf16* vrow = &vb[gbase + (size_t)key * DM];
                #pragma unroll
                for (int j = 0; j < 8; ++j) {
                    int d = vd0 + 8 * j;
                    *(unsigned short*)&vt[d * 128 + ((key * 2) ^ (vd0 << 4))] =
                        *(const unsigned short*)&vrow[d];
                }
            }
        }
        __syncthreads();

        f32x4 sc[4] = {};
        #pragma unroll
        for (int s = 0; s < 2; ++s) {
            int arow = wq0 + c;
            bf16x8 aq = *(const bf16x8*)&qs[arow * 128 + ((64 * s + 16 * g) ^ ((arow & 7) << 4))];
            #pragma unroll
            for (int nt = 0; nt < 4; ++nt) {
                int brow = nt * 16 + c;
                bf16x8 bk = *(const bf16x8*)&ks[brow * 128 + ((64 * s + 16 * g) ^ ((brow & 7) << 4))];
                sc[nt] = __builtin_amdgcn_mfma_f32_16x16x32_bf16(aq, bk, sc[nt], 0, 0, 0);
            }
        }
        #pragma unroll
        for (int nt = 0; nt < 4; ++nt)
            #pragma unroll
            for (int r = 0; r < 4; ++r) sc[nt][r] *= 0.125f;

        float corr[4];
        #pragma unroll
        for (int r = 0; r < 4; ++r) {
            float mt = fmaxf(fmaxf(sc[0][r], sc[1][r]), fmaxf(sc[2][r], sc[3][r]));
            mt = fmaxf(mt, __shfl_xor(mt, 1));
            mt = fmaxf(mt, __shfl_xor(mt, 2));
            mt = fmaxf(mt, __shfl_xor(mt, 4));
            mt = fmaxf(mt, __shfl_xor(mt, 8));
            float mn = fmaxf(m_r[r], mt);
            float cr = __expf(m_r[r] - mn);
            m_r[r] = mn;
            float ls = 0.f;
            #pragma unroll
            for (int nt = 0; nt < 4; ++nt) {
                float p = __expf(sc[nt][r] - mn);
                sc[nt][r] = p;
                ls += p;
            }
            ls += __shfl_xor(ls, 1); ls += __shfl_xor(ls, 2);
            ls += __shfl_xor(ls, 4); ls += __shfl_xor(ls, 8);
            l_r[r] = l_r[r] * cr + ls;
            corr[r] = cr;
        }
        #pragma unroll
        for (int nt = 0; nt < 4; ++nt)
            #pragma unroll
            for (int r = 0; r < 4; ++r) o[nt][r] *= corr[r];

        #pragma unroll
        for (int nti = 0; nti < 4; ++nti) {
            int nt = (nti + g) & 3;
            #pragma unroll
            for (int r = 0; r < 4; ++r) {
                int prow = wq0 + 4 * g + r;
                int pcol = nt * 16 + c;
                *(unsigned short*)&ps[prow * 128 + ((pcol * 2) ^ ((prow & 7) << 4))] =
                    bfbits(sc[nt][r]);
            }
        }

        #pragma unroll
        for (int s = 0; s < 2; ++s) {
            int arow = wq0 + c;
            bf16x8 pa = *(const bf16x8*)&ps[arow * 128 + ((64 * s + 16 * g) ^ ((arow & 7) << 4))];
            #pragma unroll
            for (int ntd = 0; ntd < 4; ++ntd) {
                int brow = ntd * 16 + c;
                bf16x8 bv = *(const bf16x8*)&vt[brow * 128 + ((64 * s + 16 * g) ^ ((brow & 7) << 4))];
                o[ntd] = __builtin_amdgcn_mfma_f32_16x16x32_bf16(pa, bv, o[ntd], 0, 0, 0);
            }
        }
        __syncthreads();
    }

    #pragma unroll
    for (int r = 0; r < 4; ++r) l_r[r] = 1.0f / l_r[r];
    int qrow = b * SEQ + qt * 64 + wq0 + 4 * g;
    #pragma unroll
    for (int nt = 0; nt < 4; ++nt)
        #pragma unroll
        for (int r = 0; r < 4; ++r)
            ab[(size_t)(qrow + r) * DM + h * HD + nt * 16 + c] =
                __float2bfloat16(o[nt][r] * l_r[r]);
}

// ---------------------------------------------------------------------------
// GEMM family (unchanged from r2): BM=128, BN=64, BK=32, 4 waves 2x2.
// ---------------------------------------------------------------------------
__global__ __launch_bounds__(256) void k_mm_plain(
    const bf16* __restrict__ A, const bf16* __restrict__ Bt, bf16* __restrict__ C)
{
    __shared__ __align__(16) char As[128 * 64];
    __shared__ __align__(16) char Bs[64 * 64];
    const int tid = threadIdx.x;
    const int lane = tid & 63, wave = tid >> 6;
    const int g = lane >> 4, c = lane & 15;
    const int wm = wave >> 1, wn = wave & 1;
    const int m0 = blockIdx.y * 128, n0 = blockIdx.x * 64;
    const int sr = tid >> 2, scol = (tid & 3) * 8;

    size_t aoff0 = (size_t)(m0 + sr) * DM + scol;
    size_t aoff1 = aoff0 + (size_t)64 * DM;
    size_t boff  = (size_t)(n0 + sr) * DM + scol;
    int4 a0 = *(const int4*)&A[aoff0];
    int4 a1 = *(const int4*)&A[aoff1];
    int4 b0 = *(const int4*)&Bt[boff];

    f32x4 acc[4][2] = {};
    for (int k0 = 0; k0 < DM; k0 += 32) {
        __syncthreads();
        *(int4*)&As[sr * 64 + (tid & 3) * 16] = a0;
        *(int4*)&As[4096 + sr * 64 + (tid & 3) * 16] = a1;
        *(int4*)&Bs[sr * 64 + (tid & 3) * 16] = b0;
        __syncthreads();
        if (k0 + 32 < DM) {
            a0 = *(const int4*)&A[aoff0 + k0 + 32];
            a1 = *(const int4*)&A[aoff1 + k0 + 32];
            b0 = *(const int4*)&Bt[boff + k0 + 32];
        }
        bf16x8 af[4], bfx[2];
        #pragma unroll
        for (int mi = 0; mi < 4; ++mi)
            af[mi] = *(const bf16x8*)&As[(wm * 64 + mi * 16 + c) * 64 + 16 * g];
        #pragma unroll
        for (int ni = 0; ni < 2; ++ni)
            bfx[ni] = *(const bf16x8*)&Bs[(wn * 32 + ni * 16 + c) * 64 + 16 * g];
        #pragma unroll
        for (int mi = 0; mi < 4; ++mi)
            #pragma unroll
            for (int ni = 0; ni < 2; ++ni)
                acc[mi][ni] = __builtin_amdgcn_mfma_f32_16x16x32_bf16(af[mi], bfx[ni], acc[mi][ni], 0, 0, 0);
    }
    #pragma unroll
    for (int mi = 0; mi < 4; ++mi)
        #pragma unroll
        for (int ni = 0; ni < 2; ++ni)
            #pragma unroll
            for (int r = 0; r < 4; ++r)
                C[(size_t)(m0 + wm * 64 + mi * 16 + 4 * g + r) * DM + n0 + wn * 32 + ni * 16 + c]
                    = __float2bfloat16(acc[mi][ni][r]);
}

template<bool ROUTED>
__global__ __launch_bounds__(256) void k_mm_gu(
    const bf16* __restrict__ X, const bf16* __restrict__ BgT,
    const bf16* __restrict__ BuT, const int* __restrict__ cnt,
    const int* __restrict__ lists, bf16* __restrict__ act)
{
    const int e = blockIdx.z;
    const int ntok = ROUTED ? cnt[e] : T;
    const int m0 = blockIdx.y * 128;
    if (m0 >= ntok) return;
    const int n0 = blockIdx.x * 64;
    __shared__ __align__(16) char As[128 * 64];
    __shared__ __align__(16) char Bg[64 * 64];
    __shared__ __align__(16) char Bu[64 * 64];
    __shared__ int rowid[128];
    const int tid = threadIdx.x;
    if (tid < 128) {
        int idx = m0 + tid;
        rowid[tid] = ROUTED ? lists[e * T + (idx < ntok ? idx : ntok - 1)] : idx;
    }
    __syncthreads();
    const int lane = tid & 63, wave = tid >> 6;
    const int g = lane >> 4, c = lane & 15;
    const int wm = wave >> 1, wn = wave & 1;
    const int sr = tid >> 2, scol = (tid & 3) * 8;
    const int ra = rowid[sr], rb = rowid[64 + sr];
    const bf16* Bge = BgT + (ROUTED ? (size_t)e * HID * DM : 0);
    const bf16* Bue = BuT + (ROUTED ? (size_t)e * HID * DM : 0);
    size_t aoff0 = (size_t)ra * DM + scol;
    size_t aoff1 = (size_t)rb * DM + scol;
    size_t boff  = (size_t)(n0 + sr) * DM + scol;
    int4 a0 = *(const int4*)&X[aoff0];
    int4 a1 = *(const int4*)&X[aoff1];
    int4 g0 = *(const int4*)&Bge[boff];
    int4 u0 = *(const int4*)&Bue[boff];

    f32x4 accg[4][2] = {}, accu[4][2] = {};
    for (int k0 = 0; k0 < DM; k0 += 32) {
        __syncthreads();
        *(int4*)&As[sr * 64 + (tid & 3) * 16] = a0;
        *(int4*)&As[4096 + sr * 64 + (tid & 3) * 16] = a1;
        *(int4*)&Bg[sr * 64 + (tid & 3) * 16] = g0;
        *(int4*)&Bu[sr * 64 + (tid & 3) * 16] = u0;
        __syncthreads();
        if (k0 + 32 < DM) {
            a0 = *(const int4*)&X[aoff0 + k0 + 32];
            a1 = *(const int4*)&X[aoff1 + k0 + 32];
            g0 = *(const int4*)&Bge[boff + k0 + 32];
            u0 = *(const int4*)&Bue[boff + k0 + 32];
        }
        bf16x8 af[4], gf[2], uf[2];
        #pragma unroll
        for (int mi = 0; mi < 4; ++mi)
            af[mi] = *(const bf16x8*)&As[(wm * 64 + mi * 16 + c) * 64 + 16 * g];
        #pragma unroll
        for (int ni = 0; ni < 2; ++ni) {
            gf[ni] = *(const bf16x8*)&Bg[(wn * 32 + ni * 16 + c) * 64 + 16 * g];
            uf[ni] = *(const bf16x8*)&Bu[(wn * 32 + ni * 16 + c) * 64 + 16 * g];
        }
        #pragma unroll
        for (int mi = 0; mi < 4; ++mi)
            #pragma unroll
            for (int ni = 0; ni < 2; ++ni) {
                accg[mi][ni] = __builtin_amdgcn_mfma_f32_16x16x32_bf16(af[mi], gf[ni], accg[mi][ni], 0, 0, 0);
                accu[mi][ni] = __builtin_amdgcn_mfma_f32_16x16x32_bf16(af[mi], uf[ni], accu[mi][ni], 0, 0, 0);
            }
    }
    #pragma unroll
    for (int mi = 0; mi < 4; ++mi)
        #pragma unroll
        for (int ni = 0; ni < 2; ++ni)
            #pragma unroll
            for (int r = 0; r < 4; ++r) {
                int lr = wm * 64 + mi * 16 + 4 * g + r;
                if (ROUTED && m0 + lr >= ntok) continue;
                int token = rowid[lr];
                float gv = accg[mi][ni][r], uv = accu[mi][ni][r];
                act[(size_t)token * HID + n0 + wn * 32 + ni * 16 + c] =
                    __float2bfloat16(gv * sigmoidf_(gv) * uv);
            }
}

template<bool ROUTED>
__global__ __launch_bounds__(256) void k_mm_down(
    const bf16* __restrict__ Xact, const bf16* __restrict__ BdT,
    const int* __restrict__ cnt, const int* __restrict__ lists,
    const float* __restrict__ wtok, float* __restrict__ out)
{
    const int e = blockIdx.z;
    const int ntok = ROUTED ? cnt[e] : T;
    const int m0 = blockIdx.y * 128;
    if (m0 >= ntok) return;
    const int n0 = blockIdx.x * 64;
    __shared__ __align__(16) char As[128 * 64];
    __shared__ __align__(16) char Bs[64 * 64];
    __shared__ int rowid[128];
    const int tid = threadIdx.x;
    if (tid < 128) {
        int idx = m0 + tid;
        rowid[tid] = ROUTED ? lists[e * T + (idx < ntok ? idx : ntok - 1)] : idx;
    }
    __syncthreads();
    const int lane = tid & 63, wave = tid >> 6;
    const int g = lane >> 4, c = lane & 15;
    const int wm = wave >> 1, wn = wave & 1;
    const int sr = tid >> 2, scol = (tid & 3) * 8;
    const int ra = rowid[sr], rb = rowid[64 + sr];
    const bf16* Bde = BdT + (ROUTED ? (size_t)e * HID * DM : 0);
    size_t aoff0 = (size_t)ra * HID + scol;
    size_t aoff1 = (size_t)rb * HID + scol;
    size_t boff  = (size_t)(n0 + sr) * HID + scol;
    int4 a0 = *(const int4*)&Xact[aoff0];
    int4 a1 = *(const int4*)&Xact[aoff1];
    int4 b0 = *(const int4*)&Bde[boff];

    f32x4 acc[4][2] = {};
    for (int k0 = 0; k0 < HID; k0 += 32) {
        __syncthreads();
        *(int4*)&As[sr * 64 + (tid & 3) * 16] = a0;
        *(int4*)&As[4096 + sr * 64 + (tid & 3) * 16] = a1;
        *(int4*)&Bs[sr * 64 + (tid & 3) * 16] = b0;
        __syncthreads();
        if (k0 + 32 < HID) {
            a0 = *(const int4*)&Xact[aoff0 + k0 + 32];
            a1 = *(const int4*)&Xact[aoff1 + k0 + 32];
            b0 = *(const int4*)&Bde[boff + k0 + 32];
        }
        bf16x8 af[4], bfx[2];
        #pragma unroll
        for (int mi = 0; mi < 4; ++mi)
            af[mi] = *(const bf16x8*)&As[(wm * 64 + mi * 16 + c) * 64 + 16 * g];
        #pragma unroll
        for (int ni = 0; ni < 2; ++ni)
            bfx[ni] = *(const bf16x8*)&Bs[(wn * 32 + ni * 16 + c) * 64 + 16 * g];
        #pragma unroll
        for (int mi = 0; mi < 4; ++mi)
            #pragma unroll
            for (int ni = 0; ni < 2; ++ni)
                acc[mi][ni] = __builtin_amdgcn_mfma_f32_16x16x32_bf16(af[mi], bfx[ni], acc[mi][ni], 0, 0, 0);
    }
    #pragma unroll
    for (int mi = 0; mi < 4; ++mi)
        #pragma unroll
        for (int ni = 0; ni < 2; ++ni)
            #pragma unroll
            for (int r = 0; r < 4; ++r) {
                int lr = wm * 64 + mi * 16 + 4 * g + r;
                if (ROUTED && m0 + lr >= ntok) continue;
                int token = rowid[lr];
                int bt = token >> 10, st = token & (SEQ - 1);
                size_t oo = (size_t)st * (BATCH * DM) + bt * DM + n0 + wn * 32 + ni * 16 + c;
                if (ROUTED) out[oo] = acc[mi][ni][r] * wtok[token];
                else        out[oo] += acc[mi][ni][r];
            }
}

// ---------------------------------------------------------------------------
__global__ __launch_bounds__(256) void k_gate(
    const bf16* __restrict__ y, const float* __restrict__ gw,
    int* __restrict__ cnt, int* __restrict__ lists, float* __restrict__ wtok)
{
    int warp = threadIdx.x >> 6, lane = threadIdx.x & 63;
    int t = blockIdx.x * 4 + warp;
    float acc[NEXP] = {};
    for (int d = lane; d < DM; d += 64) {
        float xv = __bfloat162float(y[(size_t)t * DM + d]);
        #pragma unroll
        for (int e = 0; e < NEXP; ++e) acc[e] += xv * gw[e * DM + d];
    }
    #pragma unroll
    for (int off = 32; off; off >>= 1)
        #pragma unroll
        for (int e = 0; e < NEXP; ++e) acc[e] += __shfl_xor(acc[e], off);
    if (lane == 0) {
        float mx = fmaxf(fmaxf(acc[0], acc[1]), fmaxf(acc[2], acc[3]));
        float ex[NEXP], ssum = 0.f;
        #pragma unroll
        for (int e = 0; e < NEXP; ++e) { ex[e] = __expf(acc[e] - mx); ssum += ex[e]; }
        int best = 0; float bv = ex[0];
        #pragma unroll
        for (int e = 1; e < NEXP; ++e) if (ex[e] > bv) { bv = ex[e]; best = e; }
        wtok[t] = bv / ssum;
        int pos = atomicAdd(&cnt[best], 1);
        lists[best * T + pos] = t;
    }
}

// ---------------------------------------------------------------------------
extern "C" void kernel_launch(void* const* d_in, const int* in_sizes, int n_in,
                              void* d_out, int out_size, void* d_ws, size_t ws_size,
                              hipStream_t stream) {
    (void)in_sizes; (void)n_in; (void)out_size; (void)ws_size;
    const float* dec      = (const float*)d_in[0];
    const float* wq_a     = (const float*)d_in[1];
    const float* q_norm_w = (const float*)d_in[2];
    const float* wq_b     = (const float*)d_in[3];
    const float* wkv_a    = (const float*)d_in[4];
    const float* kv_norm_w= (const float*)d_in[5];
    const float* wkv_b    = (const float*)d_in[6];
    const float* wo       = (const float*)d_in[7];
    const float* gate_w   = (const float*)d_in[8];
    const float* exp_gate = (const float*)d_in[9];
    const float* exp_up   = (const float*)d_in[10];
    const float* exp_down = (const float*)d_in[11];
    const float* sh_gate  = (const float*)d_in[12];
    const float* sh_up    = (const float*)d_in[13];
    const float* sh_down  = (const float*)d_in[14];
    float* out = (float*)d_out;

    char* W = (char*)d_ws;
    bf16* qb  = (bf16*)(W);                    // 4MB; reused as y
    bf16* kb  = (bf16*)(W + (4ull  << 20));    // 4MB; reused as act_r
    bf16* vb  = (bf16*)(W + (8ull  << 20));    // 4MB; reused as act_s
    char* SMALL = W + (12ull << 20);           // 4MB region (dead before attn out)
    bf16* ab  = (bf16*)(W + (12ull << 20));    // 4MB (attn output, after SMALL dead)
    bf16* woT = (bf16*)(W + (16ull << 20));
    bf16* sgT = (bf16*)(W + (18ull << 20));
    bf16* suT = (bf16*)(W + (20ull << 20));
    bf16* sdT = (bf16*)(W + (22ull << 20));
    bf16* egT = (bf16*)(W + (24ull << 20));
    bf16* euT = (bf16*)(W + (32ull << 20));
    bf16* edT = (bf16*)(W + (40ull << 20));
    int*   cnt   = (int*)(W + (48ull << 20));
    int*   lists = cnt + 16;
    float* wtok  = (float*)(lists + NEXP * T);
    bf16* yb    = qb;
    bf16* act_r = kb;
    bf16* act_s = vb;

    // small scratch inside SMALL (all dead before k_attn writes ab)
    float* lora  = (float*)(SMALL);                    // 2048*72*4  = 589824
    bf16*  loraT = (bf16*) (SMALL + 589824);           // 80*1024*2  = 163840
    bf16*  wqbT  = (bf16*) (SMALL + 753664);           // 1024*32*2  = 65536
    bf16*  wkvbT = (bf16*) (SMALL + 819200);           // 1536*32*2  = 98304
    bf16*  nrmq  = (bf16*) (SMALL + 917504);           // 2048*32*2  = 131072
    bf16*  nrmkv = (bf16*) (SMALL + 1048576);          // 131072
    float* ctab  = (float*)(SMALL + 1179648);          // 1024*256*4 = 1048576
    float* stab  = (float*)(SMALL + 2228224);          // 1048576 (end 3276800 < 4MB)

    hipMemsetAsync(cnt, 0, 16 * sizeof(int), stream);
    hipMemsetAsync(lora, 0, T * 72 * sizeof(float), stream);

    k_cvt_t<<<dim3(32, 32, 1), 256, 0, stream>>>(wo,       woT, 1024, 1024);
    k_cvt_t<<<dim3(32, 32, 1), 256, 0, stream>>>(sh_gate,  sgT, 1024, 1024);
    k_cvt_t<<<dim3(32, 32, 1), 256, 0, stream>>>(sh_up,    suT, 1024, 1024);
    k_cvt_t<<<dim3(32, 32, 1), 256, 0, stream>>>(sh_down,  sdT, 1024, 1024);
    k_cvt_t<<<dim3(32, 32, 4), 256, 0, stream>>>(exp_gate, egT, 1024, 1024);
    k_cvt_t<<<dim3(32, 32, 4), 256, 0, stream>>>(exp_up,   euT, 1024, 1024);
    k_cvt_t<<<dim3(32, 32, 4), 256, 0, stream>>>(exp_down, edT, 1024, 1024);

    k_prep<<<dim3(320, 1, 3), 256, 0, stream>>>(wq_a, wkv_a, wq_b, wkv_b,
                                                loraT, wqbT, wkvbT);
    k_freqs<<<SEQ, 256, 0, stream>>>(ctab, stab);
    k_p1<<<dim3(4, 16), 256, 0, stream>>>(dec, loraT, lora);
    k_p2<<<T / 256, 256, 0, stream>>>(lora, q_norm_w, kv_norm_w, nrmq, nrmkv);
    k_p2b<<<T, 256, 0, stream>>>(lora, ctab, stab, kb);
    k_p3q<<<dim3(16, 16), 256, 0, stream>>>(nrmq, wqbT, ctab, stab, qb);
    k_p3kv<<<dim3(24, 16), 256, 0, stream>>>(nrmkv, wkvbT, kb, vb);

    k_attn<<<dim3(SEQ / 64, NH, BATCH), 256, 0, stream>>>(qb, kb, vb, ab);
    k_mm_plain<<<dim3(DM / 64, T / 128), 256, 0, stream>>>(ab, woT, yb);
    k_gate<<<T / 4, 256, 0, stream>>>(yb, gate_w, cnt, lists, wtok);
    k_mm_gu<true><<<dim3(HID / 64, T / 128, NEXP), 256, 0, stream>>>(yb, egT, euT, cnt, lists, act_r);
    k_mm_down<true><<<dim3(DM / 64, T / 128, NEXP), 256, 0, stream>>>(act_r, edT, cnt, lists, wtok, out);
    k_mm_gu<false><<<dim3(HID / 64, T / 128, 1), 256, 0, stream>>>(yb, sgT, suT, cnt, lists, act_s);
    k_mm_down<false><<<dim3(DM / 64, T / 128, 1), 256, 0, stream>>>(act_s, sdT, cnt, lists, wtok, out);
}

// Round 4
// 231.292 us; speedup vs baseline: 3.8388x; 1.1083x over previous
//
#include <hip/hip_runtime.h>
#include <hip/hip_bf16.h>
#include <math.h>

#define SEQ 1024
#define BATCH 2
#define T 2048
#define DM 1024
#define NH 16
#define NOPE 32
#define HD 64
#define QL 20
#define KVL 20
#define KVA 52
#define HID 1024
#define NEXP 4
#define LSTR 80   // padded LDS row stride (bytes) for GEMM tiles: 20*row%32 banks -> <=2-way

typedef short bf16x8 __attribute__((ext_vector_type(8)));
typedef float f32x4 __attribute__((ext_vector_type(4)));
typedef __hip_bfloat16 bf16;

static __device__ __forceinline__ float sigmoidf_(float x) {
    return 1.0f / (1.0f + __expf(-x));
}
static __device__ __forceinline__ unsigned short bfbits(float x) {
    bf16 h = __float2bfloat16(x);
    return *reinterpret_cast<unsigned short*>(&h);
}

// ---------------------------------------------------------------------------
// k_setup: one launch for all weight preprocessing.
// z 0..15 : 32x32 transpose+cvt tiles of the 16 [1024][1024] weight slices
// z 16    : cos/sin tables
// z 17..19: lora/wqb/wkvb packing
// ---------------------------------------------------------------------------
__global__ __launch_bounds__(256) void k_setup(
    const float* __restrict__ wo, const float* __restrict__ sg,
    const float* __restrict__ su, const float* __restrict__ sd,
    const float* __restrict__ eg, const float* __restrict__ eu,
    const float* __restrict__ ed,
    bf16* __restrict__ woT, bf16* __restrict__ sgT, bf16* __restrict__ suT,
    bf16* __restrict__ sdT, bf16* __restrict__ egT, bf16* __restrict__ euT,
    bf16* __restrict__ edT,
    const float* __restrict__ wq_a, const float* __restrict__ wkv_a,
    const float* __restrict__ wq_b, const float* __restrict__ wkv_b,
    bf16* __restrict__ loraT, bf16* __restrict__ wqbT, bf16* __restrict__ wkvbT,
    float* __restrict__ ctab, float* __restrict__ stab)
{
    int z = blockIdx.z;
    int tid = threadIdx.x;
    if (z < 16) {
        __shared__ float tile[32][33];
        const float* in; bf16* out;
        if      (z == 0) { in = wo; out = woT; }
        else if (z == 1) { in = sg; out = sgT; }
        else if (z == 2) { in = su; out = suT; }
        else if (z == 3) { in = sd; out = sdT; }
        else if (z < 8)  { size_t o = (size_t)(z - 4)  * DM * HID; in = eg + o; out = egT + o; }
        else if (z < 12) { size_t o = (size_t)(z - 8)  * DM * HID; in = eu + o; out = euT + o; }
        else             { size_t o = (size_t)(z - 12) * HID * DM; in = ed + o; out = edT + o; }
        int c0 = blockIdx.x * 32, r0 = blockIdx.y * 32;
        int tx = tid & 31, ty = tid >> 5;
        #pragma unroll
        for (int ii = 0; ii < 4; ++ii)
            tile[ty + ii * 8][tx] = in[(size_t)(r0 + ty + ii * 8) * 1024 + c0 + tx];
        __syncthreads();
        int c = tid >> 3, rg = (tid & 7) * 4;
        ushort4 o4;
        o4.x = bfbits(tile[rg + 0][c]);
        o4.y = bfbits(tile[rg + 1][c]);
        o4.z = bfbits(tile[rg + 2][c]);
        o4.w = bfbits(tile[rg + 3][c]);
        *(ushort4*)&out[(size_t)(c0 + c) * 1024 + r0 + rg] = o4;
    } else if (z == 16) {
        int s = blockIdx.y * 32 + blockIdx.x;
        int p = tid;
        float freq = exp2f(-(float)p * (13.287712379549449f / 256.0f));
        float ang = (float)s * freq;
        float sn, cs;
        __sincosf(ang, &sn, &cs);
        ctab[s * 256 + p] = cs;
        stab[s * 256 + p] = sn;
    } else {
        int idx = (blockIdx.y * 32 + blockIdx.x) * 256 + tid;
        if (z == 17) {
            if (idx >= 80 * 1024) return;
            int n = idx >> 10, k = idx & 1023;
            float v = (n < 20) ? wq_a[k * QL + n] : (n < 72 ? wkv_a[k * KVA + (n - 20)] : 0.f);
            loraT[idx] = __float2bfloat16(v);
        } else if (z == 18) {
            if (idx >= 1024 * 32) return;
            int n = idx >> 5, k = idx & 31;
            wqbT[idx] = __float2bfloat16(k < 20 ? wq_b[k * DM + n] : 0.f);
        } else {
            if (idx >= 1536 * 32) return;
            int n = idx >> 5, k = idx & 31;
            wkvbT[idx] = __float2bfloat16(k < 20 ? wkv_b[k * (NH * 96) + n] : 0.f);
        }
    }
}

// ---------------------------------------------------------------------------
// k_p1: lora[T][72] = dec @ [wq_a|wkv_a] via MFMA, K-split 4 + atomicAdd.
// ---------------------------------------------------------------------------
__global__ __launch_bounds__(256) void k_p1(
    const float* __restrict__ dec, const bf16* __restrict__ loraT,
    float* __restrict__ lora)
{
    __shared__ __align__(16) char As[128 * LSTR];
    __shared__ __align__(16) char Bs[80 * LSTR];
    const int tid = threadIdx.x;
    const int kz = blockIdx.x;
    const int m0 = blockIdx.y * 128;
    const int lane = tid & 63, wave = tid >> 6;
    const int g = lane >> 4, c = lane & 15;
    f32x4 acc[2][5] = {};
    for (int ks = 0; ks < 8; ++ks) {
        int k0 = kz * 256 + ks * 32;
        __syncthreads();
        #pragma unroll
        for (int pass = 0; pass < 4; ++pass) {
            int row = (tid >> 3) + pass * 32;
            int t = m0 + row;
            int b = t >> 10, s = t & 1023;
            f32x4 v = *(const f32x4*)&dec[(size_t)(s * 2 + b) * DM + k0 + (tid & 7) * 4];
            ushort4 h4;
            h4.x = bfbits(v[0]); h4.y = bfbits(v[1]);
            h4.z = bfbits(v[2]); h4.w = bfbits(v[3]);
            *(ushort4*)&As[row * LSTR + (tid & 7) * 8] = h4;
        }
        if (tid < 160) {
            int row = tid >> 1, hf = tid & 1;
            const bf16* src = &loraT[row * 1024 + k0 + hf * 16];
            *(int4*)&Bs[row * LSTR + hf * 32]      = *(const int4*)&src[0];
            *(int4*)&Bs[row * LSTR + hf * 32 + 16] = *(const int4*)&src[8];
        }
        __syncthreads();
        bf16x8 af[2], bff[5];
        #pragma unroll
        for (int mi = 0; mi < 2; ++mi)
            af[mi] = *(const bf16x8*)&As[(wave * 32 + mi * 16 + c) * LSTR + 16 * g];
        #pragma unroll
        for (int nf = 0; nf < 5; ++nf)
            bff[nf] = *(const bf16x8*)&Bs[(nf * 16 + c) * LSTR + 16 * g];
        #pragma unroll
        for (int mi = 0; mi < 2; ++mi)
            #pragma unroll
            for (int nf = 0; nf < 5; ++nf)
                acc[mi][nf] = __builtin_amdgcn_mfma_f32_16x16x32_bf16(af[mi], bff[nf], acc[mi][nf], 0, 0, 0);
    }
    #pragma unroll
    for (int mi = 0; mi < 2; ++mi)
        #pragma unroll
        for (int nf = 0; nf < 5; ++nf)
            #pragma unroll
            for (int r = 0; r < 4; ++r) {
                int col = nf * 16 + c;
                if (col < 72) {
                    int row = m0 + wave * 32 + mi * 16 + 4 * g + r;
                    atomicAdd(&lora[row * 72 + col], acc[mi][nf][r]);
                }
            }
}

// ---------------------------------------------------------------------------
// k_p2: RMS -> padded bf16 nrmq/nrmkv [T][32]
// ---------------------------------------------------------------------------
__global__ __launch_bounds__(256) void k_p2(
    const float* __restrict__ lora, const float* __restrict__ qnw,
    const float* __restrict__ kvnw, bf16* __restrict__ nrmq, bf16* __restrict__ nrmkv)
{
    int t = blockIdx.x * 256 + threadIdx.x;
    float lq[20], lk[20];
    float ssq = 0.f, ssk = 0.f;
    #pragma unroll
    for (int i = 0; i < 20; ++i) { lq[i] = lora[t * 72 + i];      ssq += lq[i] * lq[i]; }
    #pragma unroll
    for (int i = 0; i < 20; ++i) { lk[i] = lora[t * 72 + 20 + i]; ssk += lk[i] * lk[i]; }
    float fq = rsqrtf(ssq / 20.f + 1e-6f);
    float fk = rsqrtf(ssk / 20.f + 1e-6f);
    #pragma unroll
    for (int i = 0; i < 32; ++i) {
        nrmq[t * 32 + i]  = __float2bfloat16(i < 20 ? lq[i] * fq * qnw[i]  : 0.f);
        nrmkv[t * 32 + i] = __float2bfloat16(i < 20 ? lk[i] * fk * kvnw[i] : 0.f);
    }
}

// ---------------------------------------------------------------------------
// k_p2b: k_pe RoPE broadcast -> kb PE region
// ---------------------------------------------------------------------------
__global__ __launch_bounds__(256) void k_p2b(
    const float* __restrict__ lora, const float* __restrict__ ctab,
    const float* __restrict__ stab, bf16* __restrict__ kb)
{
    int t = blockIdx.x, p = threadIdx.x;
    int r = p & 15, h = p >> 4, s = t & (SEQ - 1);
    float y0 = lora[t * 72 + 40 + 2 * r];
    float y1 = lora[t * 72 + 41 + 2 * r];
    float cs = ctab[s * 256 + p], sn = stab[s * 256 + p];
    ushort2 pk;
    pk.x = bfbits(y0 * cs - y1 * sn);
    pk.y = bfbits(y0 * sn + y1 * cs);
    *(ushort2*)&kb[(size_t)t * DM + h * HD + NOPE + 2 * r] = pk;
}

// ---------------------------------------------------------------------------
// k_p3q: q = nrmq @ wqbT with fused RoPE + fused 1/8 score scale -> qb
// ---------------------------------------------------------------------------
__global__ __launch_bounds__(256) void k_p3q(
    const bf16* __restrict__ nrmq, const bf16* __restrict__ wqbT,
    const float* __restrict__ ctab, const float* __restrict__ stab,
    bf16* __restrict__ qb)
{
    __shared__ __align__(16) char As[128 * LSTR];
    __shared__ __align__(16) char Bs[64 * LSTR];
    const int tid = threadIdx.x;
    const int m0 = blockIdx.y * 128, n0 = blockIdx.x * 64;
    const int lane = tid & 63, wave = tid >> 6;
    const int g = lane >> 4, c = lane & 15;
    const int wm = wave >> 1, wn = wave & 1;
    {
        int row = tid >> 1, hf = tid & 1;
        const bf16* sa = &nrmq[(size_t)(m0 + row) * 32 + hf * 16];
        *(int4*)&As[row * LSTR + hf * 32]      = *(const int4*)&sa[0];
        *(int4*)&As[row * LSTR + hf * 32 + 16] = *(const int4*)&sa[8];
        int brow = tid >> 2;
        *(int4*)&Bs[brow * LSTR + (tid & 3) * 16] = *(const int4*)&wqbT[(size_t)(n0 + brow) * 32 + (tid & 3) * 8];
    }
    __syncthreads();
    f32x4 acc[4][2] = {};
    bf16x8 af[4], bfr[2];
    #pragma unroll
    for (int mi = 0; mi < 4; ++mi)
        af[mi] = *(const bf16x8*)&As[(wm * 64 + mi * 16 + c) * LSTR + 16 * g];
    #pragma unroll
    for (int ni = 0; ni < 2; ++ni)
        bfr[ni] = *(const bf16x8*)&Bs[(wn * 32 + ni * 16 + c) * LSTR + 16 * g];
    #pragma unroll
    for (int mi = 0; mi < 4; ++mi)
        #pragma unroll
        for (int ni = 0; ni < 2; ++ni) {
            acc[mi][ni] = __builtin_amdgcn_mfma_f32_16x16x32_bf16(af[mi], bfr[ni], acc[mi][ni], 0, 0, 0);
            #pragma unroll
            for (int r = 0; r < 4; ++r) acc[mi][ni][r] *= 0.125f;   // fold score scale
        }

    #pragma unroll
    for (int mi = 0; mi < 4; ++mi)
        #pragma unroll
        for (int ni = 0; ni < 2; ++ni) {
            int n = n0 + wn * 32 + ni * 16 + c;
            int w = n & 63;
            if (w < 32) {
                #pragma unroll
                for (int r = 0; r < 4; ++r) {
                    int row = m0 + wm * 64 + mi * 16 + 4 * g + r;
                    qb[(size_t)row * DM + n] = __float2bfloat16(acc[mi][ni][r]);
                }
            } else {
                int h = n >> 6;
                int pidx = h * 16 + ((w - 32) >> 1);
                int odd = w & 1;
                #pragma unroll
                for (int r = 0; r < 4; ++r) {
                    int row = m0 + wm * 64 + mi * 16 + 4 * g + r;
                    int s = row & (SEQ - 1);
                    float own = acc[mi][ni][r];
                    float oth = __shfl_xor(own, 1);
                    float cs = ctab[s * 256 + pidx], sn = stab[s * 256 + pidx];
                    float o = odd ? (oth * sn + own * cs) : (own * cs - oth * sn);
                    qb[(size_t)row * DM + n] = __float2bfloat16(o);
                }
            }
        }
}

// ---------------------------------------------------------------------------
// k_p3kv: kvb = nrmkv @ wkvbT; k_nope -> kb, V -> vt_g ([b][h][d][s], packed)
// ---------------------------------------------------------------------------
__global__ __launch_bounds__(256) void k_p3kv(
    const bf16* __restrict__ nrmkv, const bf16* __restrict__ wkvbT,
    bf16* __restrict__ kb, bf16* __restrict__ vt_g)
{
    __shared__ __align__(16) char As[128 * LSTR];
    __shared__ __align__(16) char Bs[64 * LSTR];
    const int tid = threadIdx.x;
    const int m0 = blockIdx.y * 128, n0 = blockIdx.x * 64;
    const int lane = tid & 63, wave = tid >> 6;
    const int g = lane >> 4, c = lane & 15;
    const int wm = wave >> 1, wn = wave & 1;
    {
        int row = tid >> 1, hf = tid & 1;
        const bf16* sa = &nrmkv[(size_t)(m0 + row) * 32 + hf * 16];
        *(int4*)&As[row * LSTR + hf * 32]      = *(const int4*)&sa[0];
        *(int4*)&As[row * LSTR + hf * 32 + 16] = *(const int4*)&sa[8];
        int brow = tid >> 2;
        *(int4*)&Bs[brow * LSTR + (tid & 3) * 16] = *(const int4*)&wkvbT[(size_t)(n0 + brow) * 32 + (tid & 3) * 8];
    }
    __syncthreads();
    f32x4 acc[4][2] = {};
    bf16x8 af[4], bfr[2];
    #pragma unroll
    for (int mi = 0; mi < 4; ++mi)
        af[mi] = *(const bf16x8*)&As[(wm * 64 + mi * 16 + c) * LSTR + 16 * g];
    #pragma unroll
    for (int ni = 0; ni < 2; ++ni)
        bfr[ni] = *(const bf16x8*)&Bs[(wn * 32 + ni * 16 + c) * LSTR + 16 * g];
    #pragma unroll
    for (int mi = 0; mi < 4; ++mi)
        #pragma unroll
        for (int ni = 0; ni < 2; ++ni)
            acc[mi][ni] = __builtin_amdgcn_mfma_f32_16x16x32_bf16(af[mi], bfr[ni], acc[mi][ni], 0, 0, 0);

    #pragma unroll
    for (int mi = 0; mi < 4; ++mi)
        #pragma unroll
        for (int ni = 0; ni < 2; ++ni) {
            int n = n0 + wn * 32 + ni * 16 + c;
            int h = n / 96, w = n - h * 96;
            int row0 = m0 + wm * 64 + mi * 16 + 4 * g;   // 4-aligned, same batch
            if (w < NOPE) {
                #pragma unroll
                for (int r = 0; r < 4; ++r)
                    kb[(size_t)(row0 + r) * DM + h * HD + w] = __float2bfloat16(acc[mi][ni][r]);
            } else {
                int d = w - NOPE;
                int b = row0 >> 10, s0 = row0 & (SEQ - 1);
                ushort4 v4;
                v4.x = bfbits(acc[mi][ni][0]);
                v4.y = bfbits(acc[mi][ni][1]);
                v4.z = bfbits(acc[mi][ni][2]);
                v4.w = bfbits(acc[mi][ni][3]);
                *(ushort4*)&vt_g[(((size_t)(b * NH + h) * HD + d) << 10) + s0] = v4;
            }
        }
}

// ---------------------------------------------------------------------------
// k_attn: 2 waves, 32 q rows/block. K and V both staged with b128 loads
// (V pre-transposed in global). XOR-swizzled LDS, conflict-free.
// Score scale pre-folded into q.
// ---------------------------------------------------------------------------
__global__ __launch_bounds__(128) void k_attn(
    const bf16* __restrict__ qb, const bf16* __restrict__ kb,
    const bf16* __restrict__ vt_g, bf16* __restrict__ ab)
{
    __shared__ __align__(16) char qs[32 * 128];
    __shared__ __align__(16) char ks[64 * 128];
    __shared__ __align__(16) char vt[64 * 128];
    __shared__ __align__(16) char ps[32 * 128];

    const int qt = blockIdx.x, h = blockIdx.y, b = blockIdx.z;
    const int tid = threadIdx.x;
    const int lane = tid & 63, wave = tid >> 6;
    const int g = lane >> 4, c = lane & 15;
    const int wq0 = wave * 16;

    #pragma unroll
    for (int pass = 0; pass < 2; ++pass) {
        int row = (tid >> 3) + pass * 16;
        int col8 = (tid & 7) * 8;
        int4 v = *(const int4*)&qb[(size_t)(b * SEQ + qt * 32 + row) * DM + h * HD + col8];
        *(int4*)&qs[row * 128 + ((col8 * 2) ^ ((row & 7) << 4))] = v;
    }

    f32x4 o[4] = {};
    float m_r[4], l_r[4];
    #pragma unroll
    for (int r = 0; r < 4; ++r) { m_r[r] = -1e30f; l_r[r] = 0.f; }
    __syncthreads();

    const size_t vbase = ((size_t)(b * NH + h) * HD) << 10;
    for (int kt = 0; kt < SEQ / 64; ++kt) {
        #pragma unroll
        for (int pass = 0; pass < 4; ++pass) {
            int row = (tid >> 3) + pass * 16;
            int col8 = (tid & 7) * 8;
            int sw = ((col8 * 2) ^ ((row & 7) << 4));
            int4 kv4 = *(const int4*)&kb[(size_t)(b * SEQ + kt * 64 + row) * DM + h * HD + col8];
            *(int4*)&ks[row * 128 + sw] = kv4;
            int4 vv4 = *(const int4*)&vt_g[vbase + ((size_t)row << 10) + kt * 64 + col8];
            *(int4*)&vt[row * 128 + sw] = vv4;
        }
        __syncthreads();

        f32x4 sc[4] = {};
        #pragma unroll
        for (int s = 0; s < 2; ++s) {
            int arow = wq0 + c;
            bf16x8 aq = *(const bf16x8*)&qs[arow * 128 + ((64 * s + 16 * g) ^ ((arow & 7) << 4))];
            #pragma unroll
            for (int nt = 0; nt < 4; ++nt) {
                int brow = nt * 16 + c;
                bf16x8 bk = *(const bf16x8*)&ks[brow * 128 + ((64 * s + 16 * g) ^ ((brow & 7) << 4))];
                sc[nt] = __builtin_amdgcn_mfma_f32_16x16x32_bf16(aq, bk, sc[nt], 0, 0, 0);
            }
        }

        float corr[4];
        #pragma unroll
        for (int r = 0; r < 4; ++r) {
            float mt = fmaxf(fmaxf(sc[0][r], sc[1][r]), fmaxf(sc[2][r], sc[3][r]));
            mt = fmaxf(mt, __shfl_xor(mt, 1));
            mt = fmaxf(mt, __shfl_xor(mt, 2));
            mt = fmaxf(mt, __shfl_xor(mt, 4));
            mt = fmaxf(mt, __shfl_xor(mt, 8));
            float mn = fmaxf(m_r[r], mt);
            float cr = __expf(m_r[r] - mn);
            m_r[r] = mn;
            float ls = 0.f;
            #pragma unroll
            for (int nt = 0; nt < 4; ++nt) {
                float p = __expf(sc[nt][r] - mn);
                sc[nt][r] = p;
                ls += p;
            }
            ls += __shfl_xor(ls, 1); ls += __shfl_xor(ls, 2);
            ls += __shfl_xor(ls, 4); ls += __shfl_xor(ls, 8);
            l_r[r] = l_r[r] * cr + ls;
            corr[r] = cr;
        }
        #pragma unroll
        for (int nt = 0; nt < 4; ++nt)
            #pragma unroll
            for (int r = 0; r < 4; ++r) o[nt][r] *= corr[r];

        #pragma unroll
        for (int nti = 0; nti < 4; ++nti) {
            int nt = (nti + g) & 3;
            #pragma unroll
            for (int r = 0; r < 4; ++r) {
                int prow = wq0 + 4 * g + r;
                int pcol = nt * 16 + c;
                *(unsigned short*)&ps[prow * 128 + ((pcol * 2) ^ ((prow & 7) << 4))] =
                    bfbits(sc[nt][r]);
            }
        }

        #pragma unroll
        for (int s = 0; s < 2; ++s) {
            int arow = wq0 + c;
            bf16x8 pa = *(const bf16x8*)&ps[arow * 128 + ((64 * s + 16 * g) ^ ((arow & 7) << 4))];
            #pragma unroll
            for (int ntd = 0; ntd < 4; ++ntd) {
                int brow = ntd * 16 + c;
                bf16x8 bv = *(const bf16x8*)&vt[brow * 128 + ((64 * s + 16 * g) ^ ((brow & 7) << 4))];
                o[ntd] = __builtin_amdgcn_mfma_f32_16x16x32_bf16(pa, bv, o[ntd], 0, 0, 0);
            }
        }
        __syncthreads();
    }

    #pragma unroll
    for (int r = 0; r < 4; ++r) l_r[r] = 1.0f / l_r[r];
    int qrow = b * SEQ + qt * 32 + wq0 + 4 * g;
    #pragma unroll
    for (int nt = 0; nt < 4; ++nt)
        #pragma unroll
        for (int r = 0; r < 4; ++r)
            ab[(size_t)(qrow + r) * DM + h * HD + nt * 16 + c] =
                __float2bfloat16(o[nt][r] * l_r[r]);
}

// ---------------------------------------------------------------------------
// GEMM family: BM=64, BN=64, BK=32, 4 waves (2x2), wave tile 32x32.
// LDS rows padded to 80B (conflict-free). Grid 512 -> 2 blocks/CU.
// ---------------------------------------------------------------------------
__global__ __launch_bounds__(256) void k_mm_plain(
    const bf16* __restrict__ A, const bf16* __restrict__ Bt, bf16* __restrict__ C)
{
    __shared__ __align__(16) char As[64 * LSTR];
    __shared__ __align__(16) char Bs[64 * LSTR];
    const int tid = threadIdx.x;
    const int lane = tid & 63, wave = tid >> 6;
    const int g = lane >> 4, c = lane & 15;
    const int wm = wave >> 1, wn = wave & 1;
    const int m0 = blockIdx.y * 64, n0 = blockIdx.x * 64;
    const int sr = tid >> 2, sb = (tid & 3) * 16, scol = (tid & 3) * 8;

    size_t aoff = (size_t)(m0 + sr) * DM + scol;
    size_t boff = (size_t)(n0 + sr) * DM + scol;
    int4 a0 = *(const int4*)&A[aoff];
    int4 b0 = *(const int4*)&Bt[boff];

    f32x4 acc[2][2] = {};
    for (int k0 = 0; k0 < DM; k0 += 32) {
        __syncthreads();
        *(int4*)&As[sr * LSTR + sb] = a0;
        *(int4*)&Bs[sr * LSTR + sb] = b0;
        __syncthreads();
        if (k0 + 32 < DM) {
            a0 = *(const int4*)&A[aoff + k0 + 32];
            b0 = *(const int4*)&Bt[boff + k0 + 32];
        }
        bf16x8 af[2], bfx[2];
        #pragma unroll
        for (int mi = 0; mi < 2; ++mi)
            af[mi] = *(const bf16x8*)&As[(wm * 32 + mi * 16 + c) * LSTR + 16 * g];
        #pragma unroll
        for (int ni = 0; ni < 2; ++ni)
            bfx[ni] = *(const bf16x8*)&Bs[(wn * 32 + ni * 16 + c) * LSTR + 16 * g];
        #pragma unroll
        for (int mi = 0; mi < 2; ++mi)
            #pragma unroll
            for (int ni = 0; ni < 2; ++ni)
                acc[mi][ni] = __builtin_amdgcn_mfma_f32_16x16x32_bf16(af[mi], bfx[ni], acc[mi][ni], 0, 0, 0);
    }
    #pragma unroll
    for (int mi = 0; mi < 2; ++mi)
        #pragma unroll
        for (int ni = 0; ni < 2; ++ni)
            #pragma unroll
            for (int r = 0; r < 4; ++r)
                C[(size_t)(m0 + wm * 32 + mi * 16 + 4 * g + r) * DM + n0 + wn * 32 + ni * 16 + c]
                    = __float2bfloat16(acc[mi][ni][r]);
}

template<bool ROUTED>
__global__ __launch_bounds__(256) void k_mm_gu(
    const bf16* __restrict__ X, const bf16* __restrict__ BgT,
    const bf16* __restrict__ BuT, const int* __restrict__ cnt,
    const int* __restrict__ lists, bf16* __restrict__ act)
{
    const int e = blockIdx.z;
    const int ntok = ROUTED ? cnt[e] : T;
    const int m0 = blockIdx.y * 64;
    if (m0 >= ntok) return;
    const int n0 = blockIdx.x * 64;
    __shared__ __align__(16) char As[64 * LSTR];
    __shared__ __align__(16) char Bg[64 * LSTR];
    __shared__ __align__(16) char Bu[64 * LSTR];
    __shared__ int rowid[64];
    const int tid = threadIdx.x;
    if (tid < 64) {
        int idx = m0 + tid;
        rowid[tid] = ROUTED ? lists[e * T + (idx < ntok ? idx : ntok - 1)] : idx;
    }
    __syncthreads();
    const int lane = tid & 63, wave = tid >> 6;
    const int g = lane >> 4, c = lane & 15;
    const int wm = wave >> 1, wn = wave & 1;
    const int sr = tid >> 2, sb = (tid & 3) * 16, scol = (tid & 3) * 8;
    const int ra = rowid[sr];
    const bf16* Bge = BgT + (ROUTED ? (size_t)e * HID * DM : 0);
    const bf16* Bue = BuT + (ROUTED ? (size_t)e * HID * DM : 0);
    size_t aoff = (size_t)ra * DM + scol;
    size_t boff = (size_t)(n0 + sr) * DM + scol;
    int4 a0 = *(const int4*)&X[aoff];
    int4 g0 = *(const int4*)&Bge[boff];
    int4 u0 = *(const int4*)&Bue[boff];

    f32x4 accg[2][2] = {}, accu[2][2] = {};
    for (int k0 = 0; k0 < DM; k0 += 32) {
        __syncthreads();
        *(int4*)&As[sr * LSTR + sb] = a0;
        *(int4*)&Bg[sr * LSTR + sb] = g0;
        *(int4*)&Bu[sr * LSTR + sb] = u0;
        __syncthreads();
        if (k0 + 32 < DM) {
            a0 = *(const int4*)&X[aoff + k0 + 32];
            g0 = *(const int4*)&Bge[boff + k0 + 32];
            u0 = *(const int4*)&Bue[boff + k0 + 32];
        }
        bf16x8 af[2], gf[2], uf[2];
        #pragma unroll
        for (int mi = 0; mi < 2; ++mi)
            af[mi] = *(const bf16x8*)&As[(wm * 32 + mi * 16 + c) * LSTR + 16 * g];
        #pragma unroll
        for (int ni = 0; ni < 2; ++ni) {
            gf[ni] = *(const bf16x8*)&Bg[(wn * 32 + ni * 16 + c) * LSTR + 16 * g];
            uf[ni] = *(const bf16x8*)&Bu[(wn * 32 + ni * 16 + c) * LSTR + 16 * g];
        }
        #pragma unroll
        for (int mi = 0; mi < 2; ++mi)
            #pragma unroll
            for (int ni = 0; ni < 2; ++ni) {
                accg[mi][ni] = __builtin_amdgcn_mfma_f32_16x16x32_bf16(af[mi], gf[ni], accg[mi][ni], 0, 0, 0);
                accu[mi][ni] = __builtin_amdgcn_mfma_f32_16x16x32_bf16(af[mi], uf[ni], accu[mi][ni], 0, 0, 0);
            }
    }
    #pragma unroll
    for (int mi = 0; mi < 2; ++mi)
        #pragma unroll
        for (int ni = 0; ni < 2; ++ni)
            #pragma unroll
            for (int r = 0; r < 4; ++r) {
                int lr = wm * 32 + mi * 16 + 4 * g + r;
                if (ROUTED && m0 + lr >= ntok) continue;
                int token = rowid[lr];
                float gv = accg[mi][ni][r], uv = accu[mi][ni][r];
                act[(size_t)token * HID + n0 + wn * 32 + ni * 16 + c] =
                    __float2bfloat16(gv * sigmoidf_(gv) * uv);
            }
}

template<bool ROUTED>
__global__ __launch_bounds__(256) void k_mm_down(
    const bf16* __restrict__ Xact, const bf16* __restrict__ BdT,
    const int* __restrict__ cnt, const int* __restrict__ lists,
    const float* __restrict__ wtok, float* __restrict__ out)
{
    const int e = blockIdx.z;
    const int ntok = ROUTED ? cnt[e] : T;
    const int m0 = blockIdx.y * 64;
    if (m0 >= ntok) return;
    const int n0 = blockIdx.x * 64;
    __shared__ __align__(16) char As[64 * LSTR];
    __shared__ __align__(16) char Bs[64 * LSTR];
    __shared__ int rowid[64];
    const int tid = threadIdx.x;
    if (tid < 64) {
        int idx = m0 + tid;
        rowid[tid] = ROUTED ? lists[e * T + (idx < ntok ? idx : ntok - 1)] : idx;
    }
    __syncthreads();
    const int lane = tid & 63, wave = tid >> 6;
    const int g = lane >> 4, c = lane & 15;
    const int wm = wave >> 1, wn = wave & 1;
    const int sr = tid >> 2, sb = (tid & 3) * 16, scol = (tid & 3) * 8;
    const int ra = rowid[sr];
    const bf16* Bde = BdT + (ROUTED ? (size_t)e * HID * DM : 0);
    size_t aoff = (size_t)ra * HID + scol;
    size_t boff = (size_t)(n0 + sr) * HID + scol;
    int4 a0 = *(const int4*)&Xact[aoff];
    int4 b0 = *(const int4*)&Bde[boff];

    f32x4 acc[2][2] = {};
    for (int k0 = 0; k0 < HID; k0 += 32) {
        __syncthreads();
        *(int4*)&As[sr * LSTR + sb] = a0;
        *(int4*)&Bs[sr * LSTR + sb] = b0;
        __syncthreads();
        if (k0 + 32 < HID) {
            a0 = *(const int4*)&Xact[aoff + k0 + 32];
            b0 = *(const int4*)&Bde[boff + k0 + 32];
        }
        bf16x8 af[2], bfx[2];
        #pragma unroll
        for (int mi = 0; mi < 2; ++mi)
            af[mi] = *(const bf16x8*)&As[(wm * 32 + mi * 16 + c) * LSTR + 16 * g];
        #pragma unroll
        for (int ni = 0; ni < 2; ++ni)
            bfx[ni] = *(const bf16x8*)&Bs[(wn * 32 + ni * 16 + c) * LSTR + 16 * g];
        #pragma unroll
        for (int mi = 0; mi < 2; ++mi)
            #pragma unroll
            for (int ni = 0; ni < 2; ++ni)
                acc[mi][ni] = __builtin_amdgcn_mfma_f32_16x16x32_bf16(af[mi], bfx[ni], acc[mi][ni], 0, 0, 0);
    }
    #pragma unroll
    for (int mi = 0; mi < 2; ++mi)
        #pragma unroll
        for (int ni = 0; ni < 2; ++ni)
            #pragma unroll
            for (int r = 0; r < 4; ++r) {
                int lr = wm * 32 + mi * 16 + 4 * g + r;
                if (ROUTED && m0 + lr >= ntok) continue;
                int token = rowid[lr];
                int bt = token >> 10, st = token & (SEQ - 1);
                size_t oo = (size_t)st * (BATCH * DM) + bt * DM + n0 + wn * 32 + ni * 16 + c;
                if (ROUTED) out[oo] = acc[mi][ni][r] * wtok[token];
                else        out[oo] += acc[mi][ni][r];
            }
}

// ---------------------------------------------------------------------------
__global__ __launch_bounds__(256) void k_gate(
    const bf16* __restrict__ y, const float* __restrict__ gw,
    int* __restrict__ cnt, int* __restrict__ lists, float* __restrict__ wtok)
{
    int warp = threadIdx.x >> 6, lane = threadIdx.x & 63;
    int t = blockIdx.x * 4 + warp;
    float acc[NEXP] = {};
    for (int d = lane; d < DM; d += 64) {
        float xv = __bfloat162float(y[(size_t)t * DM + d]);
        #pragma unroll
        for (int e = 0; e < NEXP; ++e) acc[e] += xv * gw[e * DM + d];
    }
    #pragma unroll
    for (int off = 32; off; off >>= 1)
        #pragma unroll
        for (int e = 0; e < NEXP; ++e) acc[e] += __shfl_xor(acc[e], off);
    if (lane == 0) {
        float mx = fmaxf(fmaxf(acc[0], acc[1]), fmaxf(acc[2], acc[3]));
        float ex[NEXP], ssum = 0.f;
        #pragma unroll
        for (int e = 0; e < NEXP; ++e) { ex[e] = __expf(acc[e] - mx); ssum += ex[e]; }
        int best = 0; float bv = ex[0];
        #pragma unroll
        for (int e = 1; e < NEXP; ++e) if (ex[e] > bv) { bv = ex[e]; best = e; }
        wtok[t] = bv / ssum;
        int pos = atomicAdd(&cnt[best], 1);
        lists[best * T + pos] = t;
    }
}

// ---------------------------------------------------------------------------
extern "C" void kernel_launch(void* const* d_in, const int* in_sizes, int n_in,
                              void* d_out, int out_size, void* d_ws, size_t ws_size,
                              hipStream_t stream) {
    (void)in_sizes; (void)n_in; (void)out_size; (void)ws_size;
    const float* dec      = (const float*)d_in[0];
    const float* wq_a     = (const float*)d_in[1];
    const float* q_norm_w = (const float*)d_in[2];
    const float* wq_b     = (const float*)d_in[3];
    const float* wkv_a    = (const float*)d_in[4];
    const float* kv_norm_w= (const float*)d_in[5];
    const float* wkv_b    = (const float*)d_in[6];
    const float* wo       = (const float*)d_in[7];
    const float* gate_w   = (const float*)d_in[8];
    const float* exp_gate = (const float*)d_in[9];
    const float* exp_up   = (const float*)d_in[10];
    const float* exp_down = (const float*)d_in[11];
    const float* sh_gate  = (const float*)d_in[12];
    const float* sh_up    = (const float*)d_in[13];
    const float* sh_down  = (const float*)d_in[14];
    float* out = (float*)d_out;

    char* W = (char*)d_ws;
    bf16* qb   = (bf16*)(W);                    // 4MB; reused as y
    bf16* kb   = (bf16*)(W + (4ull  << 20));    // 4MB; reused as act_r
    bf16* vt_g = (bf16*)(W + (8ull  << 20));    // 4MB [b][h][d][s]; reused as act_s
    char* SMALL = W + (12ull << 20);            // scratch, dead before attn writes ab
    bf16* ab   = (bf16*)(W + (12ull << 20));    // 4MB
    bf16* woT = (bf16*)(W + (16ull << 20));
    bf16* sgT = (bf16*)(W + (18ull << 20));
    bf16* suT = (bf16*)(W + (20ull << 20));
    bf16* sdT = (bf16*)(W + (22ull << 20));
    bf16* egT = (bf16*)(W + (24ull << 20));
    bf16* euT = (bf16*)(W + (32ull << 20));
    bf16* edT = (bf16*)(W + (40ull << 20));
    int*   cnt   = (int*)(W + (48ull << 20));
    int*   lists = cnt + 16;
    float* wtok  = (float*)(lists + NEXP * T);
    bf16* yb    = qb;
    bf16* act_r = kb;
    bf16* act_s = vt_g;

    float* lora  = (float*)(SMALL);
    bf16*  loraT = (bf16*) (SMALL + 589824);
    bf16*  wqbT  = (bf16*) (SMALL + 753664);
    bf16*  wkvbT = (bf16*) (SMALL + 819200);
    bf16*  nrmq  = (bf16*) (SMALL + 917504);
    bf16*  nrmkv = (bf16*) (SMALL + 1048576);
    float* ctab  = (float*)(SMALL + 1179648);
    float* stab  = (float*)(SMALL + 2228224);

    hipMemsetAsync(cnt, 0, 16 * sizeof(int), stream);
    hipMemsetAsync(lora, 0, T * 72 * sizeof(float), stream);

    k_setup<<<dim3(32, 32, 20), 256, 0, stream>>>(
        wo, sh_gate, sh_up, sh_down, exp_gate, exp_up, exp_down,
        woT, sgT, suT, sdT, egT, euT, edT,
        wq_a, wkv_a, wq_b, wkv_b, loraT, wqbT, wkvbT, ctab, stab);

    k_p1<<<dim3(4, 16), 256, 0, stream>>>(dec, loraT, lora);
    k_p2<<<T / 256, 256, 0, stream>>>(lora, q_norm_w, kv_norm_w, nrmq, nrmkv);
    k_p2b<<<T, 256, 0, stream>>>(lora, ctab, stab, kb);
    k_p3q<<<dim3(16, 16), 256, 0, stream>>>(nrmq, wqbT, ctab, stab, qb);
    k_p3kv<<<dim3(24, 16), 256, 0, stream>>>(nrmkv, wkvbT, kb, vt_g);

    k_attn<<<dim3(SEQ / 32, NH, BATCH), 128, 0, stream>>>(qb, kb, vt_g, ab);
    k_mm_plain<<<dim3(DM / 64, T / 64), 256, 0, stream>>>(ab, woT, yb);
    k_gate<<<T / 4, 256, 0, stream>>>(yb, gate_w, cnt, lists, wtok);
    k_mm_gu<true><<<dim3(HID / 64, T / 64, NEXP), 256, 0, stream>>>(yb, egT, euT, cnt, lists, act_r);
    k_mm_down<true><<<dim3(DM / 64, T / 64, NEXP), 256, 0, stream>>>(act_r, edT, cnt, lists, wtok, out);
    k_mm_gu<false><<<dim3(HID / 64, T / 64, 1), 256, 0, stream>>>(yb, sgT, suT, cnt, lists, act_s);
    k_mm_down<false><<<dim3(DM / 64, T / 64, 1), 256, 0, stream>>>(act_s, sdT, cnt, lists, wtok, out);
}

// Round 5
// 222.760 us; speedup vs baseline: 3.9858x; 1.0383x over previous
//
#include <hip/hip_runtime.h>
#include <hip/hip_bf16.h>
#include <math.h>

#define SEQ 1024
#define BATCH 2
#define T 2048
#define DM 1024
#define NH 16
#define NOPE 32
#define HD 64
#define QL 20
#define KVL 20
#define KVA 52
#define HID 1024
#define NEXP 4
#define LSTR 80   // padded LDS row stride (bytes) for GEMM tiles

typedef short bf16x8 __attribute__((ext_vector_type(8)));
typedef float f32x4 __attribute__((ext_vector_type(4)));
typedef float f32x16 __attribute__((ext_vector_type(16)));
typedef __hip_bfloat16 bf16;

static __device__ __forceinline__ float sigmoidf_(float x) {
    return 1.0f / (1.0f + __expf(-x));
}
static __device__ __forceinline__ unsigned short bfbits(float x) {
    bf16 h = __float2bfloat16(x);
    return *reinterpret_cast<unsigned short*>(&h);
}
static __device__ __forceinline__ unsigned cvt_pk_bf16(float lo, float hi) {
    unsigned r;
    asm("v_cvt_pk_bf16_f32 %0, %1, %2" : "=v"(r) : "v"(lo), "v"(hi));
    return r;
}

// ---------------------------------------------------------------------------
// k_setup: all weight preprocessing in one launch (unchanged from r3).
// ---------------------------------------------------------------------------
__global__ __launch_bounds__(256) void k_setup(
    const float* __restrict__ wo, const float* __restrict__ sg,
    const float* __restrict__ su, const float* __restrict__ sd,
    const float* __restrict__ eg, const float* __restrict__ eu,
    const float* __restrict__ ed,
    bf16* __restrict__ woT, bf16* __restrict__ sgT, bf16* __restrict__ suT,
    bf16* __restrict__ sdT, bf16* __restrict__ egT, bf16* __restrict__ euT,
    bf16* __restrict__ edT,
    const float* __restrict__ wq_a, const float* __restrict__ wkv_a,
    const float* __restrict__ wq_b, const float* __restrict__ wkv_b,
    bf16* __restrict__ loraT, bf16* __restrict__ wqbT, bf16* __restrict__ wkvbT,
    float* __restrict__ ctab, float* __restrict__ stab)
{
    int z = blockIdx.z;
    int tid = threadIdx.x;
    if (z < 16) {
        __shared__ float tile[32][33];
        const float* in; bf16* out;
        if      (z == 0) { in = wo; out = woT; }
        else if (z == 1) { in = sg; out = sgT; }
        else if (z == 2) { in = su; out = suT; }
        else if (z == 3) { in = sd; out = sdT; }
        else if (z < 8)  { size_t o = (size_t)(z - 4)  * DM * HID; in = eg + o; out = egT + o; }
        else if (z < 12) { size_t o = (size_t)(z - 8)  * DM * HID; in = eu + o; out = euT + o; }
        else             { size_t o = (size_t)(z - 12) * HID * DM; in = ed + o; out = edT + o; }
        int c0 = blockIdx.x * 32, r0 = blockIdx.y * 32;
        int tx = tid & 31, ty = tid >> 5;
        #pragma unroll
        for (int ii = 0; ii < 4; ++ii)
            tile[ty + ii * 8][tx] = in[(size_t)(r0 + ty + ii * 8) * 1024 + c0 + tx];
        __syncthreads();
        int c = tid >> 3, rg = (tid & 7) * 4;
        ushort4 o4;
        o4.x = bfbits(tile[rg + 0][c]);
        o4.y = bfbits(tile[rg + 1][c]);
        o4.z = bfbits(tile[rg + 2][c]);
        o4.w = bfbits(tile[rg + 3][c]);
        *(ushort4*)&out[(size_t)(c0 + c) * 1024 + r0 + rg] = o4;
    } else if (z == 16) {
        int s = blockIdx.y * 32 + blockIdx.x;
        int p = tid;
        float freq = exp2f(-(float)p * (13.287712379549449f / 256.0f));
        float ang = (float)s * freq;
        float sn, cs;
        __sincosf(ang, &sn, &cs);
        ctab[s * 256 + p] = cs;
        stab[s * 256 + p] = sn;
    } else {
        int idx = (blockIdx.y * 32 + blockIdx.x) * 256 + tid;
        if (z == 17) {
            if (idx >= 80 * 1024) return;
            int n = idx >> 10, k = idx & 1023;
            float v = (n < 20) ? wq_a[k * QL + n] : (n < 72 ? wkv_a[k * KVA + (n - 20)] : 0.f);
            loraT[idx] = __float2bfloat16(v);
        } else if (z == 18) {
            if (idx >= 1024 * 32) return;
            int n = idx >> 5, k = idx & 31;
            wqbT[idx] = __float2bfloat16(k < 20 ? wq_b[k * DM + n] : 0.f);
        } else {
            if (idx >= 1536 * 32) return;
            int n = idx >> 5, k = idx & 31;
            wkvbT[idx] = __float2bfloat16(k < 20 ? wkv_b[k * (NH * 96) + n] : 0.f);
        }
    }
}

// ---------------------------------------------------------------------------
// k_p1: lora[T][72] = dec @ [wq_a|wkv_a] via MFMA, K-split 4 + atomicAdd.
// ---------------------------------------------------------------------------
__global__ __launch_bounds__(256) void k_p1(
    const float* __restrict__ dec, const bf16* __restrict__ loraT,
    float* __restrict__ lora)
{
    __shared__ __align__(16) char As[128 * LSTR];
    __shared__ __align__(16) char Bs[80 * LSTR];
    const int tid = threadIdx.x;
    const int kz = blockIdx.x;
    const int m0 = blockIdx.y * 128;
    const int lane = tid & 63, wave = tid >> 6;
    const int g = lane >> 4, c = lane & 15;
    f32x4 acc[2][5] = {};
    for (int ks = 0; ks < 8; ++ks) {
        int k0 = kz * 256 + ks * 32;
        __syncthreads();
        #pragma unroll
        for (int pass = 0; pass < 4; ++pass) {
            int row = (tid >> 3) + pass * 32;
            int t = m0 + row;
            int b = t >> 10, s = t & 1023;
            f32x4 v = *(const f32x4*)&dec[(size_t)(s * 2 + b) * DM + k0 + (tid & 7) * 4];
            ushort4 h4;
            h4.x = bfbits(v[0]); h4.y = bfbits(v[1]);
            h4.z = bfbits(v[2]); h4.w = bfbits(v[3]);
            *(ushort4*)&As[row * LSTR + (tid & 7) * 8] = h4;
        }
        if (tid < 160) {
            int row = tid >> 1, hf = tid & 1;
            const bf16* src = &loraT[row * 1024 + k0 + hf * 16];
            *(int4*)&Bs[row * LSTR + hf * 32]      = *(const int4*)&src[0];
            *(int4*)&Bs[row * LSTR + hf * 32 + 16] = *(const int4*)&src[8];
        }
        __syncthreads();
        bf16x8 af[2], bff[5];
        #pragma unroll
        for (int mi = 0; mi < 2; ++mi)
            af[mi] = *(const bf16x8*)&As[(wave * 32 + mi * 16 + c) * LSTR + 16 * g];
        #pragma unroll
        for (int nf = 0; nf < 5; ++nf)
            bff[nf] = *(const bf16x8*)&Bs[(nf * 16 + c) * LSTR + 16 * g];
        #pragma unroll
        for (int mi = 0; mi < 2; ++mi)
            #pragma unroll
            for (int nf = 0; nf < 5; ++nf)
                acc[mi][nf] = __builtin_amdgcn_mfma_f32_16x16x32_bf16(af[mi], bff[nf], acc[mi][nf], 0, 0, 0);
    }
    #pragma unroll
    for (int mi = 0; mi < 2; ++mi)
        #pragma unroll
        for (int nf = 0; nf < 5; ++nf)
            #pragma unroll
            for (int r = 0; r < 4; ++r) {
                int col = nf * 16 + c;
                if (col < 72) {
                    int row = m0 + wave * 32 + mi * 16 + 4 * g + r;
                    atomicAdd(&lora[row * 72 + col], acc[mi][nf][r]);
                }
            }
}

// ---------------------------------------------------------------------------
// k_p2: RMS -> padded bf16 nrmq/nrmkv [T][32]
// ---------------------------------------------------------------------------
__global__ __launch_bounds__(256) void k_p2(
    const float* __restrict__ lora, const float* __restrict__ qnw,
    const float* __restrict__ kvnw, bf16* __restrict__ nrmq, bf16* __restrict__ nrmkv)
{
    int t = blockIdx.x * 256 + threadIdx.x;
    float lq[20], lk[20];
    float ssq = 0.f, ssk = 0.f;
    #pragma unroll
    for (int i = 0; i < 20; ++i) { lq[i] = lora[t * 72 + i];      ssq += lq[i] * lq[i]; }
    #pragma unroll
    for (int i = 0; i < 20; ++i) { lk[i] = lora[t * 72 + 20 + i]; ssk += lk[i] * lk[i]; }
    float fq = rsqrtf(ssq / 20.f + 1e-6f);
    float fk = rsqrtf(ssk / 20.f + 1e-6f);
    #pragma unroll
    for (int i = 0; i < 32; ++i) {
        nrmq[t * 32 + i]  = __float2bfloat16(i < 20 ? lq[i] * fq * qnw[i]  : 0.f);
        nrmkv[t * 32 + i] = __float2bfloat16(i < 20 ? lk[i] * fk * kvnw[i] : 0.f);
    }
}

// ---------------------------------------------------------------------------
// k_p2b: k_pe RoPE broadcast -> kb PE region
// ---------------------------------------------------------------------------
__global__ __launch_bounds__(256) void k_p2b(
    const float* __restrict__ lora, const float* __restrict__ ctab,
    const float* __restrict__ stab, bf16* __restrict__ kb)
{
    int t = blockIdx.x, p = threadIdx.x;
    int r = p & 15, h = p >> 4, s = t & (SEQ - 1);
    float y0 = lora[t * 72 + 40 + 2 * r];
    float y1 = lora[t * 72 + 41 + 2 * r];
    float cs = ctab[s * 256 + p], sn = stab[s * 256 + p];
    ushort2 pk;
    pk.x = bfbits(y0 * cs - y1 * sn);
    pk.y = bfbits(y0 * sn + y1 * cs);
    *(ushort2*)&kb[(size_t)t * DM + h * HD + NOPE + 2 * r] = pk;
}

// ---------------------------------------------------------------------------
// k_p3q: q = nrmq @ wqbT, fused RoPE + fused score scale (1/8 * log2e) -> qb
// ---------------------------------------------------------------------------
__global__ __launch_bounds__(256) void k_p3q(
    const bf16* __restrict__ nrmq, const bf16* __restrict__ wqbT,
    const float* __restrict__ ctab, const float* __restrict__ stab,
    bf16* __restrict__ qb)
{
    __shared__ __align__(16) char As[128 * LSTR];
    __shared__ __align__(16) char Bs[64 * LSTR];
    const int tid = threadIdx.x;
    const int m0 = blockIdx.y * 128, n0 = blockIdx.x * 64;
    const int lane = tid & 63, wave = tid >> 6;
    const int g = lane >> 4, c = lane & 15;
    const int wm = wave >> 1, wn = wave & 1;
    {
        int row = tid >> 1, hf = tid & 1;
        const bf16* sa = &nrmq[(size_t)(m0 + row) * 32 + hf * 16];
        *(int4*)&As[row * LSTR + hf * 32]      = *(const int4*)&sa[0];
        *(int4*)&As[row * LSTR + hf * 32 + 16] = *(const int4*)&sa[8];
        int brow = tid >> 2;
        *(int4*)&Bs[brow * LSTR + (tid & 3) * 16] = *(const int4*)&wqbT[(size_t)(n0 + brow) * 32 + (tid & 3) * 8];
    }
    __syncthreads();
    f32x4 acc[4][2] = {};
    bf16x8 af[4], bfr[2];
    #pragma unroll
    for (int mi = 0; mi < 4; ++mi)
        af[mi] = *(const bf16x8*)&As[(wm * 64 + mi * 16 + c) * LSTR + 16 * g];
    #pragma unroll
    for (int ni = 0; ni < 2; ++ni)
        bfr[ni] = *(const bf16x8*)&Bs[(wn * 32 + ni * 16 + c) * LSTR + 16 * g];
    #pragma unroll
    for (int mi = 0; mi < 4; ++mi)
        #pragma unroll
        for (int ni = 0; ni < 2; ++ni) {
            acc[mi][ni] = __builtin_amdgcn_mfma_f32_16x16x32_bf16(af[mi], bfr[ni], acc[mi][ni], 0, 0, 0);
            #pragma unroll
            for (int r = 0; r < 4; ++r) acc[mi][ni][r] *= 0.18033688f;  // 0.125*log2(e)
        }

    #pragma unroll
    for (int mi = 0; mi < 4; ++mi)
        #pragma unroll
        for (int ni = 0; ni < 2; ++ni) {
            int n = n0 + wn * 32 + ni * 16 + c;
            int w = n & 63;
            if (w < 32) {
                #pragma unroll
                for (int r = 0; r < 4; ++r) {
                    int row = m0 + wm * 64 + mi * 16 + 4 * g + r;
                    qb[(size_t)row * DM + n] = __float2bfloat16(acc[mi][ni][r]);
                }
            } else {
                int h = n >> 6;
                int pidx = h * 16 + ((w - 32) >> 1);
                int odd = w & 1;
                #pragma unroll
                for (int r = 0; r < 4; ++r) {
                    int row = m0 + wm * 64 + mi * 16 + 4 * g + r;
                    int s = row & (SEQ - 1);
                    float own = acc[mi][ni][r];
                    float oth = __shfl_xor(own, 1);
                    float cs = ctab[s * 256 + pidx], sn = stab[s * 256 + pidx];
                    float o = odd ? (oth * sn + own * cs) : (own * cs - oth * sn);
                    qb[(size_t)row * DM + n] = __float2bfloat16(o);
                }
            }
        }
}

// ---------------------------------------------------------------------------
// k_p3kv: kvb = nrmkv @ wkvbT; k_nope -> kb, V -> vt_g ([b][h][d][s])
// ---------------------------------------------------------------------------
__global__ __launch_bounds__(256) void k_p3kv(
    const bf16* __restrict__ nrmkv, const bf16* __restrict__ wkvbT,
    bf16* __restrict__ kb, bf16* __restrict__ vt_g)
{
    __shared__ __align__(16) char As[128 * LSTR];
    __shared__ __align__(16) char Bs[64 * LSTR];
    const int tid = threadIdx.x;
    const int m0 = blockIdx.y * 128, n0 = blockIdx.x * 64;
    const int lane = tid & 63, wave = tid >> 6;
    const int g = lane >> 4, c = lane & 15;
    const int wm = wave >> 1, wn = wave & 1;
    {
        int row = tid >> 1, hf = tid & 1;
        const bf16* sa = &nrmkv[(size_t)(m0 + row) * 32 + hf * 16];
        *(int4*)&As[row * LSTR + hf * 32]      = *(const int4*)&sa[0];
        *(int4*)&As[row * LSTR + hf * 32 + 16] = *(const int4*)&sa[8];
        int brow = tid >> 2;
        *(int4*)&Bs[brow * LSTR + (tid & 3) * 16] = *(const int4*)&wkvbT[(size_t)(n0 + brow) * 32 + (tid & 3) * 8];
    }
    __syncthreads();
    f32x4 acc[4][2] = {};
    bf16x8 af[4], bfr[2];
    #pragma unroll
    for (int mi = 0; mi < 4; ++mi)
        af[mi] = *(const bf16x8*)&As[(wm * 64 + mi * 16 + c) * LSTR + 16 * g];
    #pragma unroll
    for (int ni = 0; ni < 2; ++ni)
        bfr[ni] = *(const bf16x8*)&Bs[(wn * 32 + ni * 16 + c) * LSTR + 16 * g];
    #pragma unroll
    for (int mi = 0; mi < 4; ++mi)
        #pragma unroll
        for (int ni = 0; ni < 2; ++ni)
            acc[mi][ni] = __builtin_amdgcn_mfma_f32_16x16x32_bf16(af[mi], bfr[ni], acc[mi][ni], 0, 0, 0);

    #pragma unroll
    for (int mi = 0; mi < 4; ++mi)
        #pragma unroll
        for (int ni = 0; ni < 2; ++ni) {
            int n = n0 + wn * 32 + ni * 16 + c;
            int h = n / 96, w = n - h * 96;
            int row0 = m0 + wm * 64 + mi * 16 + 4 * g;
            if (w < NOPE) {
                #pragma unroll
                for (int r = 0; r < 4; ++r)
                    kb[(size_t)(row0 + r) * DM + h * HD + w] = __float2bfloat16(acc[mi][ni][r]);
            } else {
                int d = w - NOPE;
                int b = row0 >> 10, s0 = row0 & (SEQ - 1);
                ushort4 v4;
                v4.x = bfbits(acc[mi][ni][0]);
                v4.y = bfbits(acc[mi][ni][1]);
                v4.z = bfbits(acc[mi][ni][2]);
                v4.w = bfbits(acc[mi][ni][3]);
                *(ushort4*)&vt_g[(((size_t)(b * NH + h) * HD + d) << 10) + s0] = v4;
            }
        }
}

// ---------------------------------------------------------------------------
// k_attn: swapped-QK^T 32x32 MFMA flash attention, in-register softmax.
// 2 waves/block, each wave owns 32 q-rows. Scores arrive as sc[key][q]
// (col=q=lane&31) -> row-reduce is 31 local fmax + 1 shfl_xor(32).
// P stays in registers (cvt_pk_bf16 + 8 shfl to build PV B-frags).
// exp2-space (log2e folded into q scale); defer-max THR=8.
// ---------------------------------------------------------------------------
__global__ __launch_bounds__(128) void k_attn(
    const bf16* __restrict__ qb, const bf16* __restrict__ kb,
    const bf16* __restrict__ vt_g, bf16* __restrict__ ab)
{
    __shared__ __align__(16) char ks[64 * 128];   // K tile [key][d], swizzled
    __shared__ __align__(16) char vt[64 * 128];   // V^T tile [d][key], swizzled

    const int qt = blockIdx.x, h = blockIdx.y, b = blockIdx.z;
    const int tid = threadIdx.x;
    const int lane = tid & 63, wave = tid >> 6;
    const int l31 = lane & 31, hi = lane >> 5;
    const int q0 = qt * 64 + wave * 32;

    // Q fragments in registers: step st covers d = 16*st + 8*hi + 0..7
    bf16x8 qf[4];
    {
        const bf16* qrow = &qb[(size_t)(b * SEQ + q0 + l31) * DM + h * HD + 8 * hi];
        #pragma unroll
        for (int st = 0; st < 4; ++st)
            qf[st] = *(const bf16x8*)&qrow[16 * st];
    }

    f32x16 o0 = {}, o1 = {};           // O^T accum: d 0..31 / 32..63, col q=l31
    float m_run = -3.0e38f, l_run = 0.f;
    const size_t vbase = ((size_t)(b * NH + h) * HD) << 10;

    for (int kt = 0; kt < SEQ / 64; ++kt) {
        __syncthreads();
        #pragma unroll
        for (int ps = 0; ps < 4; ++ps) {
            int row = (tid >> 3) + ps * 16;
            int col8 = (tid & 7) * 8;
            int sw = (col8 * 2) ^ ((row & 7) << 4);
            int4 kv4 = *(const int4*)&kb[(size_t)(b * SEQ + kt * 64 + row) * DM + h * HD + col8];
            *(int4*)&ks[row * 128 + sw] = kv4;
            int4 vv4 = *(const int4*)&vt_g[vbase + ((size_t)row << 10) + kt * 64 + col8];
            *(int4*)&vt[row * 128 + sw] = vv4;
        }
        __syncthreads();

        // QK^T (swapped): sc[key'][q'], key' = (r&3)+8*(r>>2)+4*hi, q' = l31
        f32x16 sc0 = {}, sc1 = {};
        #pragma unroll
        for (int st = 0; st < 4; ++st) {
            int colb = 32 * st + 16 * hi;
            int r0 = l31;
            bf16x8 kf0 = *(const bf16x8*)&ks[r0 * 128 + (colb ^ ((r0 & 7) << 4))];
            sc0 = __builtin_amdgcn_mfma_f32_32x32x16_bf16(kf0, qf[st], sc0, 0, 0, 0);
            int r1 = 32 + l31;
            bf16x8 kf1 = *(const bf16x8*)&ks[r1 * 128 + (colb ^ ((r1 & 7) << 4))];
            sc1 = __builtin_amdgcn_mfma_f32_32x32x16_bf16(kf1, qf[st], sc1, 0, 0, 0);
        }

        // column max (32 local + partner half)
        float mt = fmaxf(sc0[0], sc1[0]);
        #pragma unroll
        for (int i = 1; i < 16; ++i) mt = fmaxf(mt, fmaxf(sc0[i], sc1[i]));
        mt = fmaxf(mt, __shfl_xor(mt, 32));

        // defer-max: skip rescale when growth <= 8 (log2 space)
        if (!__all(mt <= m_run + 8.0f)) {
            float m_new = fmaxf(m_run, mt);
            float corr = exp2f(m_run - m_new);
            m_run = m_new;
            l_run *= corr;
            #pragma unroll
            for (int i = 0; i < 16; ++i) { o0[i] *= corr; o1[i] *= corr; }
        }
        float ls = 0.f;
        #pragma unroll
        for (int i = 0; i < 16; ++i) {
            sc0[i] = exp2f(sc0[i] - m_run);
            sc1[i] = exp2f(sc1[i] - m_run);
            ls += sc0[i] + sc1[i];
        }
        ls += __shfl_xor(ls, 32);
        l_run += ls;

        // P -> packed bf16 pairs (keys pk[i] = 8*(i>>1) + 4*hi + 2*(i&1) + {0,1})
        unsigned pk0[8], pk1[8];
        #pragma unroll
        for (int i = 0; i < 8; ++i) {
            pk0[i] = cvt_pk_bf16(sc0[2 * i], sc0[2 * i + 1]);
            pk1[i] = cvt_pk_bf16(sc1[2 * i], sc1[2 * i + 1]);
        }

        // PV: O^T[d][q] += V^T[d][key] * P^T[key][q]
#define PV_SUB(PK, KK)                                                          \
        {                                                                       \
            _Pragma("unroll")                                                   \
            for (int s = 0; s < 2; ++s) {                                       \
                unsigned sx = hi ? PK[4*s]   : PK[4*s+2];                       \
                unsigned rx = __shfl_xor(sx, 32);                               \
                unsigned sy = hi ? PK[4*s+1] : PK[4*s+3];                       \
                unsigned ry = __shfl_xor(sy, 32);                               \
                int4 bi;                                                        \
                bi.x = hi ? (int)rx : (int)PK[4*s];                             \
                bi.y = hi ? (int)ry : (int)PK[4*s+1];                           \
                bi.z = hi ? (int)PK[4*s+2] : (int)rx;                           \
                bi.w = hi ? (int)PK[4*s+3] : (int)ry;                           \
                bf16x8 bfr = *(bf16x8*)&bi;                                     \
                int cb = (KK) * 64 + 32 * s + 16 * hi;                          \
                {                                                               \
                    int vr = l31;                                               \
                    bf16x8 vf = *(const bf16x8*)&vt[vr * 128 + (cb ^ ((vr & 7) << 4))]; \
                    o0 = __builtin_amdgcn_mfma_f32_32x32x16_bf16(vf, bfr, o0, 0, 0, 0); \
                }                                                               \
                {                                                               \
                    int vr = 32 + l31;                                          \
                    bf16x8 vf = *(const bf16x8*)&vt[vr * 128 + (cb ^ ((vr & 7) << 4))]; \
                    o1 = __builtin_amdgcn_mfma_f32_32x32x16_bf16(vf, bfr, o1, 0, 0, 0); \
                }                                                               \
            }                                                                   \
        }
        PV_SUB(pk0, 0)
        PV_SUB(pk1, 1)
#undef PV_SUB
    }

    // epilogue: normalize, transpose O^T -> O via LDS, coalesced store
    float inv = 1.0f / l_run;
    #pragma unroll
    for (int i = 0; i < 16; ++i) { o0[i] *= inv; o1[i] *= inv; }

    __syncthreads();   // all MFMA reads of ks/vt done
    char* tb = (wave == 0) ? ks : vt;   // 32 rows x 140B each (4480 <= 8192)
    #pragma unroll
    for (int i = 0; i < 8; ++i) {
        int dbase = 2 * (i & 1) + 8 * (i >> 1) + 4 * hi;
        *(unsigned*)&tb[l31 * 140 + (dbase) * 2]      = cvt_pk_bf16(o0[2 * i], o0[2 * i + 1]);
        *(unsigned*)&tb[l31 * 140 + (32 + dbase) * 2] = cvt_pk_bf16(o1[2 * i], o1[2 * i + 1]);
    }
    __builtin_amdgcn_s_waitcnt(0);  // lgkmcnt(0): wave-local ds ordering
    #pragma unroll
    for (int p = 0; p < 8; ++p) {
        int idx = p * 64 + lane;
        int q = idx >> 4, c8 = idx & 15;
        int2 rv;
        rv.x = *(const int*)&tb[q * 140 + c8 * 8];
        rv.y = *(const int*)&tb[q * 140 + c8 * 8 + 4];
        *(int2*)&ab[(size_t)(b * SEQ + q0 + q) * DM + h * HD + c8 * 4] = rv;
    }
}

// ---------------------------------------------------------------------------
// GEMM family: BM=128, BN=64, BK=32, 4 waves (2x2), wave tile 64x32.
// LDS rows padded to 80B.
// ---------------------------------------------------------------------------
__global__ __launch_bounds__(256) void k_mm_plain(
    const bf16* __restrict__ A, const bf16* __restrict__ Bt, bf16* __restrict__ C)
{
    __shared__ __align__(16) char As[128 * LSTR];
    __shared__ __align__(16) char Bs[64 * LSTR];
    const int tid = threadIdx.x;
    const int lane = tid & 63, wave = tid >> 6;
    const int g = lane >> 4, c = lane & 15;
    const int wm = wave >> 1, wn = wave & 1;
    const int m0 = blockIdx.y * 128, n0 = blockIdx.x * 64;
    const int sr = tid >> 2, sb = (tid & 3) * 16, scol = (tid & 3) * 8;

    size_t aoff0 = (size_t)(m0 + sr) * DM + scol;
    size_t aoff1 = aoff0 + (size_t)64 * DM;
    size_t boff  = (size_t)(n0 + sr) * DM + scol;
    int4 a0 = *(const int4*)&A[aoff0];
    int4 a1 = *(const int4*)&A[aoff1];
    int4 b0 = *(const int4*)&Bt[boff];

    f32x4 acc[4][2] = {};
    for (int k0 = 0; k0 < DM; k0 += 32) {
        __syncthreads();
        *(int4*)&As[sr * LSTR + sb] = a0;
        *(int4*)&As[(64 + sr) * LSTR + sb] = a1;
        *(int4*)&Bs[sr * LSTR + sb] = b0;
        __syncthreads();
        if (k0 + 32 < DM) {
            a0 = *(const int4*)&A[aoff0 + k0 + 32];
            a1 = *(const int4*)&A[aoff1 + k0 + 32];
            b0 = *(const int4*)&Bt[boff + k0 + 32];
        }
        bf16x8 af[4], bfx[2];
        #pragma unroll
        for (int mi = 0; mi < 4; ++mi)
            af[mi] = *(const bf16x8*)&As[(wm * 64 + mi * 16 + c) * LSTR + 16 * g];
        #pragma unroll
        for (int ni = 0; ni < 2; ++ni)
            bfx[ni] = *(const bf16x8*)&Bs[(wn * 32 + ni * 16 + c) * LSTR + 16 * g];
        #pragma unroll
        for (int mi = 0; mi < 4; ++mi)
            #pragma unroll
            for (int ni = 0; ni < 2; ++ni)
                acc[mi][ni] = __builtin_amdgcn_mfma_f32_16x16x32_bf16(af[mi], bfx[ni], acc[mi][ni], 0, 0, 0);
    }
    #pragma unroll
    for (int mi = 0; mi < 4; ++mi)
        #pragma unroll
        for (int ni = 0; ni < 2; ++ni)
            #pragma unroll
            for (int r = 0; r < 4; ++r)
                C[(size_t)(m0 + wm * 64 + mi * 16 + 4 * g + r) * DM + n0 + wn * 32 + ni * 16 + c]
                    = __float2bfloat16(acc[mi][ni][r]);
}

template<bool ROUTED>
__global__ __launch_bounds__(256) void k_mm_gu(
    const bf16* __restrict__ X, const bf16* __restrict__ BgT,
    const bf16* __restrict__ BuT, const int* __restrict__ cnt,
    const int* __restrict__ lists, bf16* __restrict__ act)
{
    const int e = blockIdx.z;
    const int ntok = ROUTED ? cnt[e] : T;
    const int m0 = blockIdx.y * 128;
    if (m0 >= ntok) return;
    const int n0 = blockIdx.x * 64;
    __shared__ __align__(16) char As[128 * LSTR];
    __shared__ __align__(16) char Bg[64 * LSTR];
    __shared__ __align__(16) char Bu[64 * LSTR];
    __shared__ int rowid[128];
    const int tid = threadIdx.x;
    if (tid < 128) {
        int idx = m0 + tid;
        rowid[tid] = ROUTED ? lists[e * T + (idx < ntok ? idx : ntok - 1)] : idx;
    }
    __syncthreads();
    const int lane = tid & 63, wave = tid >> 6;
    const int g = lane >> 4, c = lane & 15;
    const int wm = wave >> 1, wn = wave & 1;
    const int sr = tid >> 2, sb = (tid & 3) * 16, scol = (tid & 3) * 8;
    const int ra = rowid[sr], rb = rowid[64 + sr];
    const bf16* Bge = BgT + (ROUTED ? (size_t)e * HID * DM : 0);
    const bf16* Bue = BuT + (ROUTED ? (size_t)e * HID * DM : 0);
    size_t aoff0 = (size_t)ra * DM + scol;
    size_t aoff1 = (size_t)rb * DM + scol;
    size_t boff  = (size_t)(n0 + sr) * DM + scol;
    int4 a0 = *(const int4*)&X[aoff0];
    int4 a1 = *(const int4*)&X[aoff1];
    int4 g0 = *(const int4*)&Bge[boff];
    int4 u0 = *(const int4*)&Bue[boff];

    f32x4 accg[4][2] = {}, accu[4][2] = {};
    for (int k0 = 0; k0 < DM; k0 += 32) {
        __syncthreads();
        *(int4*)&As[sr * LSTR + sb] = a0;
        *(int4*)&As[(64 + sr) * LSTR + sb] = a1;
        *(int4*)&Bg[sr * LSTR + sb] = g0;
        *(int4*)&Bu[sr * LSTR + sb] = u0;
        __syncthreads();
        if (k0 + 32 < DM) {
            a0 = *(const int4*)&X[aoff0 + k0 + 32];
            a1 = *(const int4*)&X[aoff1 + k0 + 32];
            g0 = *(const int4*)&Bge[boff + k0 + 32];
            u0 = *(const int4*)&Bue[boff + k0 + 32];
        }
        bf16x8 af[4], gf[2], uf[2];
        #pragma unroll
        for (int mi = 0; mi < 4; ++mi)
            af[mi] = *(const bf16x8*)&As[(wm * 64 + mi * 16 + c) * LSTR + 16 * g];
        #pragma unroll
        for (int ni = 0; ni < 2; ++ni) {
            gf[ni] = *(const bf16x8*)&Bg[(wn * 32 + ni * 16 + c) * LSTR + 16 * g];
            uf[ni] = *(const bf16x8*)&Bu[(wn * 32 + ni * 16 + c) * LSTR + 16 * g];
        }
        #pragma unroll
        for (int mi = 0; mi < 4; ++mi)
            #pragma unroll
            for (int ni = 0; ni < 2; ++ni) {
                accg[mi][ni] = __builtin_amdgcn_mfma_f32_16x16x32_bf16(af[mi], gf[ni], accg[mi][ni], 0, 0, 0);
                accu[mi][ni] = __builtin_amdgcn_mfma_f32_16x16x32_bf16(af[mi], uf[ni], accu[mi][ni], 0, 0, 0);
            }
    }
    #pragma unroll
    for (int mi = 0; mi < 4; ++mi)
        #pragma unroll
        for (int ni = 0; ni < 2; ++ni)
            #pragma unroll
            for (int r = 0; r < 4; ++r) {
                int lr = wm * 64 + mi * 16 + 4 * g + r;
                if (ROUTED && m0 + lr >= ntok) continue;
                int token = rowid[lr];
                float gv = accg[mi][ni][r], uv = accu[mi][ni][r];
                act[(size_t)token * HID + n0 + wn * 32 + ni * 16 + c] =
                    __float2bfloat16(gv * sigmoidf_(gv) * uv);
            }
}

template<bool ROUTED>
__global__ __launch_bounds__(256) void k_mm_down(
    const bf16* __restrict__ Xact, const bf16* __restrict__ BdT,
    const int* __restrict__ cnt, const int* __restrict__ lists,
    const float* __restrict__ wtok, float* __restrict__ out)
{
    const int e = blockIdx.z;
    const int ntok = ROUTED ? cnt[e] : T;
    const int m0 = blockIdx.y * 128;
    if (m0 >= ntok) return;
    const int n0 = blockIdx.x * 64;
    __shared__ __align__(16) char As[128 * LSTR];
    __shared__ __align__(16) char Bs[64 * LSTR];
    __shared__ int rowid[128];
    const int tid = threadIdx.x;
    if (tid < 128) {
        int idx = m0 + tid;
        rowid[tid] = ROUTED ? lists[e * T + (idx < ntok ? idx : ntok - 1)] : idx;
    }
    __syncthreads();
    const int lane = tid & 63, wave = tid >> 6;
    const int g = lane >> 4, c = lane & 15;
    const int wm = wave >> 1, wn = wave & 1;
    const int sr = tid >> 2, sb = (tid & 3) * 16, scol = (tid & 3) * 8;
    const int ra = rowid[sr], rb = rowid[64 + sr];
    const bf16* Bde = BdT + (ROUTED ? (size_t)e * HID * DM : 0);
    size_t aoff0 = (size_t)ra * HID + scol;
    size_t aoff1 = (size_t)rb * HID + scol;
    size_t boff  = (size_t)(n0 + sr) * HID + scol;
    int4 a0 = *(const int4*)&Xact[aoff0];
    int4 a1 = *(const int4*)&Xact[aoff1];
    int4 b0 = *(const int4*)&Bde[boff];

    f32x4 acc[4][2] = {};
    for (int k0 = 0; k0 < HID; k0 += 32) {
        __syncthreads();
        *(int4*)&As[sr * LSTR + sb] = a0;
        *(int4*)&As[(64 + sr) * LSTR + sb] = a1;
        *(int4*)&Bs[sr * LSTR + sb] = b0;
        __syncthreads();
        if (k0 + 32 < HID) {
            a0 = *(const int4*)&Xact[aoff0 + k0 + 32];
            a1 = *(const int4*)&Xact[aoff1 + k0 + 32];
            b0 = *(const int4*)&Bde[boff + k0 + 32];
        }
        bf16x8 af[4], bfx[2];
        #pragma unroll
        for (int mi = 0; mi < 4; ++mi)
            af[mi] = *(const bf16x8*)&As[(wm * 64 + mi * 16 + c) * LSTR + 16 * g];
        #pragma unroll
        for (int ni = 0; ni < 2; ++ni)
            bfx[ni] = *(const bf16x8*)&Bs[(wn * 32 + ni * 16 + c) * LSTR + 16 * g];
        #pragma unroll
        for (int mi = 0; mi < 4; ++mi)
            #pragma unroll
            for (int ni = 0; ni < 2; ++ni)
                acc[mi][ni] = __builtin_amdgcn_mfma_f32_16x16x32_bf16(af[mi], bfx[ni], acc[mi][ni], 0, 0, 0);
    }
    #pragma unroll
    for (int mi = 0; mi < 4; ++mi)
        #pragma unroll
        for (int ni = 0; ni < 2; ++ni)
            #pragma unroll
            for (int r = 0; r < 4; ++r) {
                int lr = wm * 64 + mi * 16 + 4 * g + r;
                if (ROUTED && m0 + lr >= ntok) continue;
                int token = rowid[lr];
                int bt = token >> 10, st = token & (SEQ - 1);
                size_t oo = (size_t)st * (BATCH * DM) + bt * DM + n0 + wn * 32 + ni * 16 + c;
                if (ROUTED) out[oo] = acc[mi][ni][r] * wtok[token];
                else        out[oo] += acc[mi][ni][r];
            }
}

// ---------------------------------------------------------------------------
__global__ __launch_bounds__(256) void k_gate(
    const bf16* __restrict__ y, const float* __restrict__ gw,
    int* __restrict__ cnt, int* __restrict__ lists, float* __restrict__ wtok)
{
    int warp = threadIdx.x >> 6, lane = threadIdx.x & 63;
    int t = blockIdx.x * 4 + warp;
    float acc[NEXP] = {};
    for (int d = lane; d < DM; d += 64) {
        float xv = __bfloat162float(y[(size_t)t * DM + d]);
        #pragma unroll
        for (int e = 0; e < NEXP; ++e) acc[e] += xv * gw[e * DM + d];
    }
    #pragma unroll
    for (int off = 32; off; off >>= 1)
        #pragma unroll
        for (int e = 0; e < NEXP; ++e) acc[e] += __shfl_xor(acc[e], off);
    if (lane == 0) {
        float mx = fmaxf(fmaxf(acc[0], acc[1]), fmaxf(acc[2], acc[3]));
        float ex[NEXP], ssum = 0.f;
        #pragma unroll
        for (int e = 0; e < NEXP; ++e) { ex[e] = __expf(acc[e] - mx); ssum += ex[e]; }
        int best = 0; float bv = ex[0];
        #pragma unroll
        for (int e = 1; e < NEXP; ++e) if (ex[e] > bv) { bv = ex[e]; best = e; }
        wtok[t] = bv / ssum;
        int pos = atomicAdd(&cnt[best], 1);
        lists[best * T + pos] = t;
    }
}

// ---------------------------------------------------------------------------
extern "C" void kernel_launch(void* const* d_in, const int* in_sizes, int n_in,
                              void* d_out, int out_size, void* d_ws, size_t ws_size,
                              hipStream_t stream) {
    (void)in_sizes; (void)n_in; (void)out_size; (void)ws_size;
    const float* dec      = (const float*)d_in[0];
    const float* wq_a     = (const float*)d_in[1];
    const float* q_norm_w = (const float*)d_in[2];
    const float* wq_b     = (const float*)d_in[3];
    const float* wkv_a    = (const float*)d_in[4];
    const float* kv_norm_w= (const float*)d_in[5];
    const float* wkv_b    = (const float*)d_in[6];
    const float* wo       = (const float*)d_in[7];
    const float* gate_w   = (const float*)d_in[8];
    const float* exp_gate = (const float*)d_in[9];
    const float* exp_up   = (const float*)d_in[10];
    const float* exp_down = (const float*)d_in[11];
    const float* sh_gate  = (const float*)d_in[12];
    const float* sh_up    = (const float*)d_in[13];
    const float* sh_down  = (const float*)d_in[14];
    float* out = (float*)d_out;

    char* W = (char*)d_ws;
    bf16* qb   = (bf16*)(W);                    // 4MB; reused as y
    bf16* kb   = (bf16*)(W + (4ull  << 20));    // 4MB; reused as act_r
    bf16* vt_g = (bf16*)(W + (8ull  << 20));    // 4MB [b][h][d][s]; reused as act_s
    char* SMALL = W + (12ull << 20);            // scratch, dead before attn writes ab
    bf16* ab   = (bf16*)(W + (12ull << 20));    // 4MB
    bf16* woT = (bf16*)(W + (16ull << 20));
    bf16* sgT = (bf16*)(W + (18ull << 20));
    bf16* suT = (bf16*)(W + (20ull << 20));
    bf16* sdT = (bf16*)(W + (22ull << 20));
    bf16* egT = (bf16*)(W + (24ull << 20));
    bf16* euT = (bf16*)(W + (32ull << 20));
    bf16* edT = (bf16*)(W + (40ull << 20));
    int*   cnt   = (int*)(W + (48ull << 20));
    int*   lists = cnt + 16;
    float* wtok  = (float*)(lists + NEXP * T);
    bf16* yb    = qb;
    bf16* act_r = kb;
    bf16* act_s = vt_g;

    float* lora  = (float*)(SMALL);
    bf16*  loraT = (bf16*) (SMALL + 589824);
    bf16*  wqbT  = (bf16*) (SMALL + 753664);
    bf16*  wkvbT = (bf16*) (SMALL + 819200);
    bf16*  nrmq  = (bf16*) (SMALL + 917504);
    bf16*  nrmkv = (bf16*) (SMALL + 1048576);
    float* ctab  = (float*)(SMALL + 1179648);
    float* stab  = (float*)(SMALL + 2228224);

    hipMemsetAsync(cnt, 0, 16 * sizeof(int), stream);
    hipMemsetAsync(lora, 0, T * 72 * sizeof(float), stream);

    k_setup<<<dim3(32, 32, 20), 256, 0, stream>>>(
        wo, sh_gate, sh_up, sh_down, exp_gate, exp_up, exp_down,
        woT, sgT, suT, sdT, egT, euT, edT,
        wq_a, wkv_a, wq_b, wkv_b, loraT, wqbT, wkvbT, ctab, stab);

    k_p1<<<dim3(4, 16), 256, 0, stream>>>(dec, loraT, lora);
    k_p2<<<T / 256, 256, 0, stream>>>(lora, q_norm_w, kv_norm_w, nrmq, nrmkv);
    k_p2b<<<T, 256, 0, stream>>>(lora, ctab, stab, kb);
    k_p3q<<<dim3(16, 16), 256, 0, stream>>>(nrmq, wqbT, ctab, stab, qb);
    k_p3kv<<<dim3(24, 16), 256, 0, stream>>>(nrmkv, wkvbT, kb, vt_g);

    k_attn<<<dim3(SEQ / 64, NH, BATCH), 128, 0, stream>>>(qb, kb, vt_g, ab);
    k_mm_plain<<<dim3(DM / 64, T / 128), 256, 0, stream>>>(ab, woT, yb);
    k_gate<<<T / 4, 256, 0, stream>>>(yb, gate_w, cnt, lists, wtok);
    k_mm_gu<true><<<dim3(HID / 64, T / 128, NEXP), 256, 0, stream>>>(yb, egT, euT, cnt, lists, act_r);
    k_mm_down<true><<<dim3(DM / 64, T / 128, NEXP), 256, 0, stream>>>(act_r, edT, cnt, lists, wtok, out);
    k_mm_gu<false><<<dim3(HID / 64, T / 128, 1), 256, 0, stream>>>(yb, sgT, suT, cnt, lists, act_s);
    k_mm_down<false><<<dim3(DM / 64, T / 128, 1), 256, 0, stream>>>(act_s, sdT, cnt, lists, wtok, out);
}

// Round 6
// 203.991 us; speedup vs baseline: 4.3525x; 1.0920x over previous
//
#include <hip/hip_runtime.h>
#include <hip/hip_bf16.h>
#include <math.h>

#define SEQ 1024
#define BATCH 2
#define T 2048
#define DM 1024
#define NH 16
#define NOPE 32
#define HD 64
#define QL 20
#define KVL 20
#define KVA 52
#define HID 1024
#define NEXP 4
#define LSTR 80   // padded LDS row stride (bytes) for GEMM tiles

typedef short bf16x8 __attribute__((ext_vector_type(8)));
typedef float f32x4 __attribute__((ext_vector_type(4)));
typedef float f32x16 __attribute__((ext_vector_type(16)));
typedef __hip_bfloat16 bf16;

static __device__ __forceinline__ float sigmoidf_(float x) {
    return 1.0f / (1.0f + __expf(-x));
}
static __device__ __forceinline__ unsigned short bfbits(float x) {
    bf16 h = __float2bfloat16(x);
    return *reinterpret_cast<unsigned short*>(&h);
}
static __device__ __forceinline__ unsigned cvt_pk_bf16(float lo, float hi) {
    unsigned r;
    asm("v_cvt_pk_bf16_f32 %0, %1, %2" : "=v"(r) : "v"(lo), "v"(hi));
    return r;
}

// ---------------------------------------------------------------------------
// k_setup: all weight preprocessing in one launch.
// ---------------------------------------------------------------------------
__global__ __launch_bounds__(256) void k_setup(
    const float* __restrict__ wo, const float* __restrict__ sg,
    const float* __restrict__ su, const float* __restrict__ sd,
    const float* __restrict__ eg, const float* __restrict__ eu,
    const float* __restrict__ ed,
    bf16* __restrict__ woT, bf16* __restrict__ sgT, bf16* __restrict__ suT,
    bf16* __restrict__ sdT, bf16* __restrict__ egT, bf16* __restrict__ euT,
    bf16* __restrict__ edT,
    const float* __restrict__ wq_a, const float* __restrict__ wkv_a,
    const float* __restrict__ wq_b, const float* __restrict__ wkv_b,
    bf16* __restrict__ loraT, bf16* __restrict__ wqbT, bf16* __restrict__ wkvbT,
    float* __restrict__ ctab, float* __restrict__ stab)
{
    int z = blockIdx.z;
    int tid = threadIdx.x;
    if (z < 16) {
        __shared__ float tile[32][33];
        const float* in; bf16* out;
        if      (z == 0) { in = wo; out = woT; }
        else if (z == 1) { in = sg; out = sgT; }
        else if (z == 2) { in = su; out = suT; }
        else if (z == 3) { in = sd; out = sdT; }
        else if (z < 8)  { size_t o = (size_t)(z - 4)  * DM * HID; in = eg + o; out = egT + o; }
        else if (z < 12) { size_t o = (size_t)(z - 8)  * DM * HID; in = eu + o; out = euT + o; }
        else             { size_t o = (size_t)(z - 12) * HID * DM; in = ed + o; out = edT + o; }
        int c0 = blockIdx.x * 32, r0 = blockIdx.y * 32;
        int tx = tid & 31, ty = tid >> 5;
        #pragma unroll
        for (int ii = 0; ii < 4; ++ii)
            tile[ty + ii * 8][tx] = in[(size_t)(r0 + ty + ii * 8) * 1024 + c0 + tx];
        __syncthreads();
        int c = tid >> 3, rg = (tid & 7) * 4;
        ushort4 o4;
        o4.x = bfbits(tile[rg + 0][c]);
        o4.y = bfbits(tile[rg + 1][c]);
        o4.z = bfbits(tile[rg + 2][c]);
        o4.w = bfbits(tile[rg + 3][c]);
        *(ushort4*)&out[(size_t)(c0 + c) * 1024 + r0 + rg] = o4;
    } else if (z == 16) {
        int s = blockIdx.y * 32 + blockIdx.x;
        int p = tid;
        float freq = exp2f(-(float)p * (13.287712379549449f / 256.0f));
        float ang = (float)s * freq;
        float sn, cs;
        __sincosf(ang, &sn, &cs);
        ctab[s * 256 + p] = cs;
        stab[s * 256 + p] = sn;
    } else {
        int idx = (blockIdx.y * 32 + blockIdx.x) * 256 + tid;
        if (z == 17) {
            if (idx >= 80 * 1024) return;
            int n = idx >> 10, k = idx & 1023;
            float v = (n < 20) ? wq_a[k * QL + n] : (n < 72 ? wkv_a[k * KVA + (n - 20)] : 0.f);
            loraT[idx] = __float2bfloat16(v);
        } else if (z == 18) {
            if (idx >= 1024 * 32) return;
            int n = idx >> 5, k = idx & 31;
            wqbT[idx] = __float2bfloat16(k < 20 ? wq_b[k * DM + n] : 0.f);
        } else {
            if (idx >= 1536 * 32) return;
            int n = idx >> 5, k = idx & 31;
            wkvbT[idx] = __float2bfloat16(k < 20 ? wkv_b[k * (NH * 96) + n] : 0.f);
        }
    }
}

// ---------------------------------------------------------------------------
// k_p1: lora[T][72] = dec @ [wq_a|wkv_a] via MFMA, K-split 4 + atomicAdd.
// ---------------------------------------------------------------------------
__global__ __launch_bounds__(256) void k_p1(
    const float* __restrict__ dec, const bf16* __restrict__ loraT,
    float* __restrict__ lora)
{
    __shared__ __align__(16) char As[128 * LSTR];
    __shared__ __align__(16) char Bs[80 * LSTR];
    const int tid = threadIdx.x;
    const int kz = blockIdx.x;
    const int m0 = blockIdx.y * 128;
    const int lane = tid & 63, wave = tid >> 6;
    const int g = lane >> 4, c = lane & 15;
    f32x4 acc[2][5] = {};
    for (int ks = 0; ks < 8; ++ks) {
        int k0 = kz * 256 + ks * 32;
        __syncthreads();
        #pragma unroll
        for (int pass = 0; pass < 4; ++pass) {
            int row = (tid >> 3) + pass * 32;
            int t = m0 + row;
            int b = t >> 10, s = t & 1023;
            f32x4 v = *(const f32x4*)&dec[(size_t)(s * 2 + b) * DM + k0 + (tid & 7) * 4];
            ushort4 h4;
            h4.x = bfbits(v[0]); h4.y = bfbits(v[1]);
            h4.z = bfbits(v[2]); h4.w = bfbits(v[3]);
            *(ushort4*)&As[row * LSTR + (tid & 7) * 8] = h4;
        }
        if (tid < 160) {
            int row = tid >> 1, hf = tid & 1;
            const bf16* src = &loraT[row * 1024 + k0 + hf * 16];
            *(int4*)&Bs[row * LSTR + hf * 32]      = *(const int4*)&src[0];
            *(int4*)&Bs[row * LSTR + hf * 32 + 16] = *(const int4*)&src[8];
        }
        __syncthreads();
        bf16x8 af[2], bff[5];
        #pragma unroll
        for (int mi = 0; mi < 2; ++mi)
            af[mi] = *(const bf16x8*)&As[(wave * 32 + mi * 16 + c) * LSTR + 16 * g];
        #pragma unroll
        for (int nf = 0; nf < 5; ++nf)
            bff[nf] = *(const bf16x8*)&Bs[(nf * 16 + c) * LSTR + 16 * g];
        #pragma unroll
        for (int mi = 0; mi < 2; ++mi)
            #pragma unroll
            for (int nf = 0; nf < 5; ++nf)
                acc[mi][nf] = __builtin_amdgcn_mfma_f32_16x16x32_bf16(af[mi], bff[nf], acc[mi][nf], 0, 0, 0);
    }
    #pragma unroll
    for (int mi = 0; mi < 2; ++mi)
        #pragma unroll
        for (int nf = 0; nf < 5; ++nf)
            #pragma unroll
            for (int r = 0; r < 4; ++r) {
                int col = nf * 16 + c;
                if (col < 72) {
                    int row = m0 + wave * 32 + mi * 16 + 4 * g + r;
                    atomicAdd(&lora[row * 72 + col], acc[mi][nf][r]);
                }
            }
}

// ---------------------------------------------------------------------------
// k_p2: RMS -> padded bf16 nrmq/nrmkv [T][32]
// ---------------------------------------------------------------------------
__global__ __launch_bounds__(256) void k_p2(
    const float* __restrict__ lora, const float* __restrict__ qnw,
    const float* __restrict__ kvnw, bf16* __restrict__ nrmq, bf16* __restrict__ nrmkv)
{
    int t = blockIdx.x * 256 + threadIdx.x;
    float lq[20], lk[20];
    float ssq = 0.f, ssk = 0.f;
    #pragma unroll
    for (int i = 0; i < 20; ++i) { lq[i] = lora[t * 72 + i];      ssq += lq[i] * lq[i]; }
    #pragma unroll
    for (int i = 0; i < 20; ++i) { lk[i] = lora[t * 72 + 20 + i]; ssk += lk[i] * lk[i]; }
    float fq = rsqrtf(ssq / 20.f + 1e-6f);
    float fk = rsqrtf(ssk / 20.f + 1e-6f);
    #pragma unroll
    for (int i = 0; i < 32; ++i) {
        nrmq[t * 32 + i]  = __float2bfloat16(i < 20 ? lq[i] * fq * qnw[i]  : 0.f);
        nrmkv[t * 32 + i] = __float2bfloat16(i < 20 ? lk[i] * fk * kvnw[i] : 0.f);
    }
}

// ---------------------------------------------------------------------------
// k_p2b: k_pe RoPE broadcast -> kb PE region
// ---------------------------------------------------------------------------
__global__ __launch_bounds__(256) void k_p2b(
    const float* __restrict__ lora, const float* __restrict__ ctab,
    const float* __restrict__ stab, bf16* __restrict__ kb)
{
    int t = blockIdx.x, p = threadIdx.x;
    int r = p & 15, h = p >> 4, s = t & (SEQ - 1);
    float y0 = lora[t * 72 + 40 + 2 * r];
    float y1 = lora[t * 72 + 41 + 2 * r];
    float cs = ctab[s * 256 + p], sn = stab[s * 256 + p];
    ushort2 pk;
    pk.x = bfbits(y0 * cs - y1 * sn);
    pk.y = bfbits(y0 * sn + y1 * cs);
    *(ushort2*)&kb[(size_t)t * DM + h * HD + NOPE + 2 * r] = pk;
}

// ---------------------------------------------------------------------------
// k_p3q: q = nrmq @ wqbT, fused RoPE + fused score scale (1/8 * log2e) -> qb
// ---------------------------------------------------------------------------
__global__ __launch_bounds__(256) void k_p3q(
    const bf16* __restrict__ nrmq, const bf16* __restrict__ wqbT,
    const float* __restrict__ ctab, const float* __restrict__ stab,
    bf16* __restrict__ qb)
{
    __shared__ __align__(16) char As[128 * LSTR];
    __shared__ __align__(16) char Bs[64 * LSTR];
    const int tid = threadIdx.x;
    const int m0 = blockIdx.y * 128, n0 = blockIdx.x * 64;
    const int lane = tid & 63, wave = tid >> 6;
    const int g = lane >> 4, c = lane & 15;
    const int wm = wave >> 1, wn = wave & 1;
    {
        int row = tid >> 1, hf = tid & 1;
        const bf16* sa = &nrmq[(size_t)(m0 + row) * 32 + hf * 16];
        *(int4*)&As[row * LSTR + hf * 32]      = *(const int4*)&sa[0];
        *(int4*)&As[row * LSTR + hf * 32 + 16] = *(const int4*)&sa[8];
        int brow = tid >> 2;
        *(int4*)&Bs[brow * LSTR + (tid & 3) * 16] = *(const int4*)&wqbT[(size_t)(n0 + brow) * 32 + (tid & 3) * 8];
    }
    __syncthreads();
    f32x4 acc[4][2] = {};
    bf16x8 af[4], bfr[2];
    #pragma unroll
    for (int mi = 0; mi < 4; ++mi)
        af[mi] = *(const bf16x8*)&As[(wm * 64 + mi * 16 + c) * LSTR + 16 * g];
    #pragma unroll
    for (int ni = 0; ni < 2; ++ni)
        bfr[ni] = *(const bf16x8*)&Bs[(wn * 32 + ni * 16 + c) * LSTR + 16 * g];
    #pragma unroll
    for (int mi = 0; mi < 4; ++mi)
        #pragma unroll
        for (int ni = 0; ni < 2; ++ni) {
            acc[mi][ni] = __builtin_amdgcn_mfma_f32_16x16x32_bf16(af[mi], bfr[ni], acc[mi][ni], 0, 0, 0);
            #pragma unroll
            for (int r = 0; r < 4; ++r) acc[mi][ni][r] *= 0.18033688f;  // 0.125*log2(e)
        }

    #pragma unroll
    for (int mi = 0; mi < 4; ++mi)
        #pragma unroll
        for (int ni = 0; ni < 2; ++ni) {
            int n = n0 + wn * 32 + ni * 16 + c;
            int w = n & 63;
            if (w < 32) {
                #pragma unroll
                for (int r = 0; r < 4; ++r) {
                    int row = m0 + wm * 64 + mi * 16 + 4 * g + r;
                    qb[(size_t)row * DM + n] = __float2bfloat16(acc[mi][ni][r]);
                }
            } else {
                int h = n >> 6;
                int pidx = h * 16 + ((w - 32) >> 1);
                int odd = w & 1;
                #pragma unroll
                for (int r = 0; r < 4; ++r) {
                    int row = m0 + wm * 64 + mi * 16 + 4 * g + r;
                    int s = row & (SEQ - 1);
                    float own = acc[mi][ni][r];
                    float oth = __shfl_xor(own, 1);
                    float cs = ctab[s * 256 + pidx], sn = stab[s * 256 + pidx];
                    float o = odd ? (oth * sn + own * cs) : (own * cs - oth * sn);
                    qb[(size_t)row * DM + n] = __float2bfloat16(o);
                }
            }
        }
}

// ---------------------------------------------------------------------------
// k_p3kv: kvb = nrmkv @ wkvbT; k_nope -> kb, V -> vt_g ([b][h][d][s])
// ---------------------------------------------------------------------------
__global__ __launch_bounds__(256) void k_p3kv(
    const bf16* __restrict__ nrmkv, const bf16* __restrict__ wkvbT,
    bf16* __restrict__ kb, bf16* __restrict__ vt_g)
{
    __shared__ __align__(16) char As[128 * LSTR];
    __shared__ __align__(16) char Bs[64 * LSTR];
    const int tid = threadIdx.x;
    const int m0 = blockIdx.y * 128, n0 = blockIdx.x * 64;
    const int lane = tid & 63, wave = tid >> 6;
    const int g = lane >> 4, c = lane & 15;
    const int wm = wave >> 1, wn = wave & 1;
    {
        int row = tid >> 1, hf = tid & 1;
        const bf16* sa = &nrmkv[(size_t)(m0 + row) * 32 + hf * 16];
        *(int4*)&As[row * LSTR + hf * 32]      = *(const int4*)&sa[0];
        *(int4*)&As[row * LSTR + hf * 32 + 16] = *(const int4*)&sa[8];
        int brow = tid >> 2;
        *(int4*)&Bs[brow * LSTR + (tid & 3) * 16] = *(const int4*)&wkvbT[(size_t)(n0 + brow) * 32 + (tid & 3) * 8];
    }
    __syncthreads();
    f32x4 acc[4][2] = {};
    bf16x8 af[4], bfr[2];
    #pragma unroll
    for (int mi = 0; mi < 4; ++mi)
        af[mi] = *(const bf16x8*)&As[(wm * 64 + mi * 16 + c) * LSTR + 16 * g];
    #pragma unroll
    for (int ni = 0; ni < 2; ++ni)
        bfr[ni] = *(const bf16x8*)&Bs[(wn * 32 + ni * 16 + c) * LSTR + 16 * g];
    #pragma unroll
    for (int mi = 0; mi < 4; ++mi)
        #pragma unroll
        for (int ni = 0; ni < 2; ++ni)
            acc[mi][ni] = __builtin_amdgcn_mfma_f32_16x16x32_bf16(af[mi], bfr[ni], acc[mi][ni], 0, 0, 0);

    #pragma unroll
    for (int mi = 0; mi < 4; ++mi)
        #pragma unroll
        for (int ni = 0; ni < 2; ++ni) {
            int n = n0 + wn * 32 + ni * 16 + c;
            int h = n / 96, w = n - h * 96;
            int row0 = m0 + wm * 64 + mi * 16 + 4 * g;
            if (w < NOPE) {
                #pragma unroll
                for (int r = 0; r < 4; ++r)
                    kb[(size_t)(row0 + r) * DM + h * HD + w] = __float2bfloat16(acc[mi][ni][r]);
            } else {
                int d = w - NOPE;
                int b = row0 >> 10, s0 = row0 & (SEQ - 1);
                ushort4 v4;
                v4.x = bfbits(acc[mi][ni][0]);
                v4.y = bfbits(acc[mi][ni][1]);
                v4.z = bfbits(acc[mi][ni][2]);
                v4.w = bfbits(acc[mi][ni][3]);
                *(ushort4*)&vt_g[(((size_t)(b * NH + h) * HD + d) << 10) + s0] = v4;
            }
        }
}

// ---------------------------------------------------------------------------
// k_attn: in-block K-split flash attention. 4 waves: (sp, wq).
// sp half processes keys [sp*512, sp*512+512) for q-rows [q0, q0+32).
// sp=1 deposits (O,m,l) into LDS; sp=0 merges and writes.
// Swapped-QK^T 32x32 MFMA, in-register softmax (exp2-space, defer-max).
// ---------------------------------------------------------------------------
__global__ __launch_bounds__(256) void k_attn(
    const bf16* __restrict__ qb, const bf16* __restrict__ kb,
    const bf16* __restrict__ vt_g, bf16* __restrict__ ab)
{
    __shared__ __align__(16) char stage[2][16384];  // per-sp: K 8KB | V^T 8KB
    __shared__ float pol[2][32][65];                // [wq][q][d] partial O
    __shared__ float mll[2][32][2];                 // [wq][q][m,l]

    const int qt = blockIdx.x, h = blockIdx.y, b = blockIdx.z;
    const int tid = threadIdx.x;
    const int lane = tid & 63, wave = tid >> 6;
    const int l31 = lane & 31, hi = lane >> 5;
    const int sp = wave >> 1, wq = wave & 1;
    const int q0 = qt * 64 + wq * 32;
    char* ks = stage[sp];
    char* vt = stage[sp] + 8192;
    const int ptid = tid & 127;   // index within sp-pair (2 waves)

    // Q fragments in registers: step st covers d = 16*st + 8*hi + 0..7
    bf16x8 qf[4];
    {
        const bf16* qrow = &qb[(size_t)(b * SEQ + q0 + l31) * DM + h * HD + 8 * hi];
        #pragma unroll
        for (int st = 0; st < 4; ++st)
            qf[st] = *(const bf16x8*)&qrow[16 * st];
    }

    f32x16 o0 = {}, o1 = {};           // O^T accum: d 0..31 / 32..63, col q=l31
    float m_run = -3.0e38f, l_run = 0.f;
    const size_t vbase = ((size_t)(b * NH + h) * HD) << 10;

    for (int ktl = 0; ktl < 8; ++ktl) {
        const int kt = sp * 8 + ktl;
        __syncthreads();
        #pragma unroll
        for (int ps = 0; ps < 4; ++ps) {
            int row = (ptid >> 3) + ps * 16;
            int col8 = (ptid & 7) * 8;
            int sw = (col8 * 2) ^ ((row & 7) << 4);
            int4 kv4 = *(const int4*)&kb[(size_t)(b * SEQ + kt * 64 + row) * DM + h * HD + col8];
            *(int4*)&ks[row * 128 + sw] = kv4;
            int4 vv4 = *(const int4*)&vt_g[vbase + ((size_t)row << 10) + kt * 64 + col8];
            *(int4*)&vt[row * 128 + sw] = vv4;
        }
        __syncthreads();

        // QK^T (swapped): sc[key'][q'], key' = (r&3)+8*(r>>2)+4*hi, q' = l31
        f32x16 sc0 = {}, sc1 = {};
        #pragma unroll
        for (int st = 0; st < 4; ++st) {
            int colb = 32 * st + 16 * hi;
            int r0 = l31;
            bf16x8 kf0 = *(const bf16x8*)&ks[r0 * 128 + (colb ^ ((r0 & 7) << 4))];
            sc0 = __builtin_amdgcn_mfma_f32_32x32x16_bf16(kf0, qf[st], sc0, 0, 0, 0);
            int r1 = 32 + l31;
            bf16x8 kf1 = *(const bf16x8*)&ks[r1 * 128 + (colb ^ ((r1 & 7) << 4))];
            sc1 = __builtin_amdgcn_mfma_f32_32x32x16_bf16(kf1, qf[st], sc1, 0, 0, 0);
        }

        // column max (32 local + partner half)
        float mt = fmaxf(sc0[0], sc1[0]);
        #pragma unroll
        for (int i = 1; i < 16; ++i) mt = fmaxf(mt, fmaxf(sc0[i], sc1[i]));
        mt = fmaxf(mt, __shfl_xor(mt, 32));

        // defer-max: skip rescale when growth <= 8 (log2 space)
        if (!__all(mt <= m_run + 8.0f)) {
            float m_new = fmaxf(m_run, mt);
            float corr = exp2f(m_run - m_new);
            m_run = m_new;
            l_run *= corr;
            #pragma unroll
            for (int i = 0; i < 16; ++i) { o0[i] *= corr; o1[i] *= corr; }
        }
        float ls = 0.f;
        #pragma unroll
        for (int i = 0; i < 16; ++i) {
            sc0[i] = exp2f(sc0[i] - m_run);
            sc1[i] = exp2f(sc1[i] - m_run);
            ls += sc0[i] + sc1[i];
        }
        ls += __shfl_xor(ls, 32);
        l_run += ls;

        // P -> packed bf16 pairs
        unsigned pk0[8], pk1[8];
        #pragma unroll
        for (int i = 0; i < 8; ++i) {
            pk0[i] = cvt_pk_bf16(sc0[2 * i], sc0[2 * i + 1]);
            pk1[i] = cvt_pk_bf16(sc1[2 * i], sc1[2 * i + 1]);
        }

        // PV: O^T[d][q] += V^T[d][key] * P^T[key][q]
#define PV_SUB(PK, KK)                                                          \
        {                                                                       \
            _Pragma("unroll")                                                   \
            for (int s = 0; s < 2; ++s) {                                       \
                unsigned sx = hi ? PK[4*s]   : PK[4*s+2];                       \
                unsigned rx = __shfl_xor(sx, 32);                               \
                unsigned sy = hi ? PK[4*s+1] : PK[4*s+3];                       \
                unsigned ry = __shfl_xor(sy, 32);                               \
                int4 bi;                                                        \
                bi.x = hi ? (int)rx : (int)PK[4*s];                             \
                bi.y = hi ? (int)ry : (int)PK[4*s+1];                           \
                bi.z = hi ? (int)PK[4*s+2] : (int)rx;                           \
                bi.w = hi ? (int)PK[4*s+3] : (int)ry;                           \
                bf16x8 bfr = *(bf16x8*)&bi;                                     \
                int cb = (KK) * 64 + 32 * s + 16 * hi;                          \
                {                                                               \
                    int vr = l31;                                               \
                    bf16x8 vf = *(const bf16x8*)&vt[vr * 128 + (cb ^ ((vr & 7) << 4))]; \
                    o0 = __builtin_amdgcn_mfma_f32_32x32x16_bf16(vf, bfr, o0, 0, 0, 0); \
                }                                                               \
                {                                                               \
                    int vr = 32 + l31;                                          \
                    bf16x8 vf = *(const bf16x8*)&vt[vr * 128 + (cb ^ ((vr & 7) << 4))]; \
                    o1 = __builtin_amdgcn_mfma_f32_32x32x16_bf16(vf, bfr, o1, 0, 0, 0); \
                }                                                               \
            }                                                                   \
        }
        PV_SUB(pk0, 0)
        PV_SUB(pk1, 1)
#undef PV_SUB
    }

    // deposit sp=1 partials into LDS
    if (sp == 1) {
        #pragma unroll
        for (int i = 0; i < 16; ++i) {
            int d = (i & 3) + 8 * (i >> 2) + 4 * hi;
            pol[wq][l31][d]      = o0[i];
            pol[wq][l31][32 + d] = o1[i];
        }
        if (hi == 0) { mll[wq][l31][0] = m_run; mll[wq][l31][1] = l_run; }
    }
    __syncthreads();
    if (sp == 1) return;

    // merge
    float m_b = mll[wq][l31][0], l_b = mll[wq][l31][1];
    float M = fmaxf(m_run, m_b);
    float wa = exp2f(m_run - M), wb = exp2f(m_b - M);
    float inv = 1.0f / (l_run * wa + l_b * wb);
    #pragma unroll
    for (int i = 0; i < 16; ++i) {
        int d = (i & 3) + 8 * (i >> 2) + 4 * hi;
        o0[i] = (o0[i] * wa + pol[wq][l31][d]      * wb) * inv;
        o1[i] = (o1[i] * wa + pol[wq][l31][32 + d] * wb) * inv;
    }

    // transpose O^T -> O via wave-private LDS, coalesced store
    char* tb = stage[wq];   // first 4480B of each 16KB half
    #pragma unroll
    for (int i = 0; i < 8; ++i) {
        int dbase = 2 * (i & 1) + 8 * (i >> 1) + 4 * hi;
        *(unsigned*)&tb[l31 * 140 + (dbase) * 2]      = cvt_pk_bf16(o0[2 * i], o0[2 * i + 1]);
        *(unsigned*)&tb[l31 * 140 + (32 + dbase) * 2] = cvt_pk_bf16(o1[2 * i], o1[2 * i + 1]);
    }
    __builtin_amdgcn_s_waitcnt(0);  // lgkmcnt(0): wave-local ds ordering
    #pragma unroll
    for (int p = 0; p < 8; ++p) {
        int idx = p * 64 + lane;
        int q = idx >> 4, c8 = idx & 15;
        int2 rv;
        rv.x = *(const int*)&tb[q * 140 + c8 * 8];
        rv.y = *(const int*)&tb[q * 140 + c8 * 8 + 4];
        *(int2*)&ab[(size_t)(b * SEQ + q0 + q) * DM + h * HD + c8 * 4] = rv;
    }
}

// ---------------------------------------------------------------------------
// GEMM family: BM=128, BN=64, BK=32, 8 waves (4x2), wave tile 32x32.
// 512 threads; LDS rows padded to 80B.
// ---------------------------------------------------------------------------
__global__ __launch_bounds__(512) void k_mm_plain(
    const bf16* __restrict__ A, const bf16* __restrict__ Bt, bf16* __restrict__ C)
{
    __shared__ __align__(16) char As[128 * LSTR];
    __shared__ __align__(16) char Bs[64 * LSTR];
    const int tid = threadIdx.x;
    const int lane = tid & 63, wave = tid >> 6;
    const int g = lane >> 4, c = lane & 15;
    const int wm = wave >> 1, wn = wave & 1;
    const int m0 = blockIdx.y * 128, n0 = blockIdx.x * 64;
    const int sr = tid >> 2, sb = (tid & 3) * 16, scol = (tid & 3) * 8;
    const int srb = (tid & 255) >> 2;

    size_t aoff = (size_t)(m0 + sr) * DM + scol;
    size_t boff = (size_t)(n0 + srb) * DM + scol;
    int4 a0 = *(const int4*)&A[aoff];
    int4 b0;
    if (tid < 256) b0 = *(const int4*)&Bt[boff];

    f32x4 acc[2][2] = {};
    for (int k0 = 0; k0 < DM; k0 += 32) {
        __syncthreads();
        *(int4*)&As[sr * LSTR + sb] = a0;
        if (tid < 256) *(int4*)&Bs[srb * LSTR + sb] = b0;
        __syncthreads();
        if (k0 + 32 < DM) {
            a0 = *(const int4*)&A[aoff + k0 + 32];
            if (tid < 256) b0 = *(const int4*)&Bt[boff + k0 + 32];
        }
        bf16x8 af[2], bfx[2];
        #pragma unroll
        for (int mi = 0; mi < 2; ++mi)
            af[mi] = *(const bf16x8*)&As[(wm * 32 + mi * 16 + c) * LSTR + 16 * g];
        #pragma unroll
        for (int ni = 0; ni < 2; ++ni)
            bfx[ni] = *(const bf16x8*)&Bs[(wn * 32 + ni * 16 + c) * LSTR + 16 * g];
        #pragma unroll
        for (int mi = 0; mi < 2; ++mi)
            #pragma unroll
            for (int ni = 0; ni < 2; ++ni)
                acc[mi][ni] = __builtin_amdgcn_mfma_f32_16x16x32_bf16(af[mi], bfx[ni], acc[mi][ni], 0, 0, 0);
    }
    #pragma unroll
    for (int mi = 0; mi < 2; ++mi)
        #pragma unroll
        for (int ni = 0; ni < 2; ++ni)
            #pragma unroll
            for (int r = 0; r < 4; ++r)
                C[(size_t)(m0 + wm * 32 + mi * 16 + 4 * g + r) * DM + n0 + wn * 32 + ni * 16 + c]
                    = __float2bfloat16(acc[mi][ni][r]);
}

template<bool ROUTED>
__global__ __launch_bounds__(512) void k_mm_gu(
    const bf16* __restrict__ X, const bf16* __restrict__ BgT,
    const bf16* __restrict__ BuT, const int* __restrict__ cnt,
    const int* __restrict__ lists, bf16* __restrict__ act)
{
    const int e = blockIdx.z;
    const int ntok = ROUTED ? cnt[e] : T;
    const int m0 = blockIdx.y * 128;
    if (m0 >= ntok) return;
    const int n0 = blockIdx.x * 64;
    __shared__ __align__(16) char As[128 * LSTR];
    __shared__ __align__(16) char Bg[64 * LSTR];
    __shared__ __align__(16) char Bu[64 * LSTR];
    __shared__ int rowid[128];
    const int tid = threadIdx.x;
    if (tid < 128) {
        int idx = m0 + tid;
        rowid[tid] = ROUTED ? lists[e * T + (idx < ntok ? idx : ntok - 1)] : idx;
    }
    __syncthreads();
    const int lane = tid & 63, wave = tid >> 6;
    const int g = lane >> 4, c = lane & 15;
    const int wm = wave >> 1, wn = wave & 1;
    const int sr = tid >> 2, sb = (tid & 3) * 16, scol = (tid & 3) * 8;
    const int srb = (tid & 255) >> 2;
    const int ra = rowid[sr];
    const bf16* Bge = BgT + (ROUTED ? (size_t)e * HID * DM : 0);
    const bf16* Bue = BuT + (ROUTED ? (size_t)e * HID * DM : 0);
    const bf16* Bmine = (tid < 256) ? Bge : Bue;
    size_t aoff = (size_t)ra * DM + scol;
    size_t boff = (size_t)(n0 + srb) * DM + scol;
    int4 a0 = *(const int4*)&X[aoff];
    int4 b0 = *(const int4*)&Bmine[boff];
    char* Bdst = (tid < 256) ? Bg : Bu;

    f32x4 accg[2][2] = {}, accu[2][2] = {};
    for (int k0 = 0; k0 < DM; k0 += 32) {
        __syncthreads();
        *(int4*)&As[sr * LSTR + sb] = a0;
        *(int4*)&Bdst[srb * LSTR + sb] = b0;
        __syncthreads();
        if (k0 + 32 < DM) {
            a0 = *(const int4*)&X[aoff + k0 + 32];
            b0 = *(const int4*)&Bmine[boff + k0 + 32];
        }
        bf16x8 af[2], gf[2], uf[2];
        #pragma unroll
        for (int mi = 0; mi < 2; ++mi)
            af[mi] = *(const bf16x8*)&As[(wm * 32 + mi * 16 + c) * LSTR + 16 * g];
        #pragma unroll
        for (int ni = 0; ni < 2; ++ni) {
            gf[ni] = *(const bf16x8*)&Bg[(wn * 32 + ni * 16 + c) * LSTR + 16 * g];
            uf[ni] = *(const bf16x8*)&Bu[(wn * 32 + ni * 16 + c) * LSTR + 16 * g];
        }
        #pragma unroll
        for (int mi = 0; mi < 2; ++mi)
            #pragma unroll
            for (int ni = 0; ni < 2; ++ni) {
                accg[mi][ni] = __builtin_amdgcn_mfma_f32_16x16x32_bf16(af[mi], gf[ni], accg[mi][ni], 0, 0, 0);
                accu[mi][ni] = __builtin_amdgcn_mfma_f32_16x16x32_bf16(af[mi], uf[ni], accu[mi][ni], 0, 0, 0);
            }
    }
    #pragma unroll
    for (int mi = 0; mi < 2; ++mi)
        #pragma unroll
        for (int ni = 0; ni < 2; ++ni)
            #pragma unroll
            for (int r = 0; r < 4; ++r) {
                int lr = wm * 32 + mi * 16 + 4 * g + r;
                if (ROUTED && m0 + lr >= ntok) continue;
                int token = rowid[lr];
                float gv = accg[mi][ni][r], uv = accu[mi][ni][r];
                act[(size_t)token * HID + n0 + wn * 32 + ni * 16 + c] =
                    __float2bfloat16(gv * sigmoidf_(gv) * uv);
            }
}

template<bool ROUTED>
__global__ __launch_bounds__(512) void k_mm_down(
    const bf16* __restrict__ Xact, const bf16* __restrict__ BdT,
    const int* __restrict__ cnt, const int* __restrict__ lists,
    const float* __restrict__ wtok, float* __restrict__ out)
{
    const int e = blockIdx.z;
    const int ntok = ROUTED ? cnt[e] : T;
    const int m0 = blockIdx.y * 128;
    if (m0 >= ntok) return;
    const int n0 = blockIdx.x * 64;
    __shared__ __align__(16) char As[128 * LSTR];
    __shared__ __align__(16) char Bs[64 * LSTR];
    __shared__ int rowid[128];
    const int tid = threadIdx.x;
    if (tid < 128) {
        int idx = m0 + tid;
        rowid[tid] = ROUTED ? lists[e * T + (idx < ntok ? idx : ntok - 1)] : idx;
    }
    __syncthreads();
    const int lane = tid & 63, wave = tid >> 6;
    const int g = lane >> 4, c = lane & 15;
    const int wm = wave >> 1, wn = wave & 1;
    const int sr = tid >> 2, sb = (tid & 3) * 16, scol = (tid & 3) * 8;
    const int srb = (tid & 255) >> 2;
    const int ra = rowid[sr];
    const bf16* Bde = BdT + (ROUTED ? (size_t)e * HID * DM : 0);
    size_t aoff = (size_t)ra * HID + scol;
    size_t boff = (size_t)(n0 + srb) * HID + scol;
    int4 a0 = *(const int4*)&Xact[aoff];
    int4 b0;
    if (tid < 256) b0 = *(const int4*)&Bde[boff];

    f32x4 acc[2][2] = {};
    for (int k0 = 0; k0 < HID; k0 += 32) {
        __syncthreads();
        *(int4*)&As[sr * LSTR + sb] = a0;
        if (tid < 256) *(int4*)&Bs[srb * LSTR + sb] = b0;
        __syncthreads();
        if (k0 + 32 < HID) {
            a0 = *(const int4*)&Xact[aoff + k0 + 32];
            if (tid < 256) b0 = *(const int4*)&Bde[boff + k0 + 32];
        }
        bf16x8 af[2], bfx[2];
        #pragma unroll
        for (int mi = 0; mi < 2; ++mi)
            af[mi] = *(const bf16x8*)&As[(wm * 32 + mi * 16 + c) * LSTR + 16 * g];
        #pragma unroll
        for (int ni = 0; ni < 2; ++ni)
            bfx[ni] = *(const bf16x8*)&Bs[(wn * 32 + ni * 16 + c) * LSTR + 16 * g];
        #pragma unroll
        for (int mi = 0; mi < 2; ++mi)
            #pragma unroll
            for (int ni = 0; ni < 2; ++ni)
                acc[mi][ni] = __builtin_amdgcn_mfma_f32_16x16x32_bf16(af[mi], bfx[ni], acc[mi][ni], 0, 0, 0);
    }
    #pragma unroll
    for (int mi = 0; mi < 2; ++mi)
        #pragma unroll
        for (int ni = 0; ni < 2; ++ni)
            #pragma unroll
            for (int r = 0; r < 4; ++r) {
                int lr = wm * 32 + mi * 16 + 4 * g + r;
                if (ROUTED && m0 + lr >= ntok) continue;
                int token = rowid[lr];
                int bt = token >> 10, st = token & (SEQ - 1);
                size_t oo = (size_t)st * (BATCH * DM) + bt * DM + n0 + wn * 32 + ni * 16 + c;
                if (ROUTED) out[oo] = acc[mi][ni][r] * wtok[token];
                else        out[oo] += acc[mi][ni][r];
            }
}

// ---------------------------------------------------------------------------
__global__ __launch_bounds__(256) void k_gate(
    const bf16* __restrict__ y, const float* __restrict__ gw,
    int* __restrict__ cnt, int* __restrict__ lists, float* __restrict__ wtok)
{
    int warp = threadIdx.x >> 6, lane = threadIdx.x & 63;
    int t = blockIdx.x * 4 + warp;
    float acc[NEXP] = {};
    for (int d = lane; d < DM; d += 64) {
        float xv = __bfloat162float(y[(size_t)t * DM + d]);
        #pragma unroll
        for (int e = 0; e < NEXP; ++e) acc[e] += xv * gw[e * DM + d];
    }
    #pragma unroll
    for (int off = 32; off; off >>= 1)
        #pragma unroll
        for (int e = 0; e < NEXP; ++e) acc[e] += __shfl_xor(acc[e], off);
    if (lane == 0) {
        float mx = fmaxf(fmaxf(acc[0], acc[1]), fmaxf(acc[2], acc[3]));
        float ex[NEXP], ssum = 0.f;
        #pragma unroll
        for (int e = 0; e < NEXP; ++e) { ex[e] = __expf(acc[e] - mx); ssum += ex[e]; }
        int best = 0; float bv = ex[0];
        #pragma unroll
        for (int e = 1; e < NEXP; ++e) if (ex[e] > bv) { bv = ex[e]; best = e; }
        wtok[t] = bv / ssum;
        int pos = atomicAdd(&cnt[best], 1);
        lists[best * T + pos] = t;
    }
}

// ---------------------------------------------------------------------------
extern "C" void kernel_launch(void* const* d_in, const int* in_sizes, int n_in,
                              void* d_out, int out_size, void* d_ws, size_t ws_size,
                              hipStream_t stream) {
    (void)in_sizes; (void)n_in; (void)out_size; (void)ws_size;
    const float* dec      = (const float*)d_in[0];
    const float* wq_a     = (const float*)d_in[1];
    const float* q_norm_w = (const float*)d_in[2];
    const float* wq_b     = (const float*)d_in[3];
    const float* wkv_a    = (const float*)d_in[4];
    const float* kv_norm_w= (const float*)d_in[5];
    const float* wkv_b    = (const float*)d_in[6];
    const float* wo       = (const float*)d_in[7];
    const float* gate_w   = (const float*)d_in[8];
    const float* exp_gate = (const float*)d_in[9];
    const float* exp_up   = (const float*)d_in[10];
    const float* exp_down = (const float*)d_in[11];
    const float* sh_gate  = (const float*)d_in[12];
    const float* sh_up    = (const float*)d_in[13];
    const float* sh_down  = (const float*)d_in[14];
    float* out = (float*)d_out;

    char* W = (char*)d_ws;
    bf16* qb   = (bf16*)(W);                    // 4MB; reused as y
    bf16* kb   = (bf16*)(W + (4ull  << 20));    // 4MB; reused as act_r
    bf16* vt_g = (bf16*)(W + (8ull  << 20));    // 4MB [b][h][d][s]; reused as act_s
    char* SMALL = W + (12ull << 20);            // scratch, dead before attn writes ab
    bf16* ab   = (bf16*)(W + (12ull << 20));    // 4MB
    bf16* woT = (bf16*)(W + (16ull << 20));
    bf16* sgT = (bf16*)(W + (18ull << 20));
    bf16* suT = (bf16*)(W + (20ull << 20));
    bf16* sdT = (bf16*)(W + (22ull << 20));
    bf16* egT = (bf16*)(W + (24ull << 20));
    bf16* euT = (bf16*)(W + (32ull << 20));
    bf16* edT = (bf16*)(W + (40ull << 20));
    int*   cnt   = (int*)(W + (48ull << 20));
    int*   lists = cnt + 16;
    float* wtok  = (float*)(lists + NEXP * T);
    bf16* yb    = qb;
    bf16* act_r = kb;
    bf16* act_s = vt_g;

    float* lora  = (float*)(SMALL);
    bf16*  loraT = (bf16*) (SMALL + 589824);
    bf16*  wqbT  = (bf16*) (SMALL + 753664);
    bf16*  wkvbT = (bf16*) (SMALL + 819200);
    bf16*  nrmq  = (bf16*) (SMALL + 917504);
    bf16*  nrmkv = (bf16*) (SMALL + 1048576);
    float* ctab  = (float*)(SMALL + 1179648);
    float* stab  = (float*)(SMALL + 2228224);

    hipMemsetAsync(cnt, 0, 16 * sizeof(int), stream);
    hipMemsetAsync(lora, 0, T * 72 * sizeof(float), stream);

    k_setup<<<dim3(32, 32, 20), 256, 0, stream>>>(
        wo, sh_gate, sh_up, sh_down, exp_gate, exp_up, exp_down,
        woT, sgT, suT, sdT, egT, euT, edT,
        wq_a, wkv_a, wq_b, wkv_b, loraT, wqbT, wkvbT, ctab, stab);

    k_p1<<<dim3(4, 16), 256, 0, stream>>>(dec, loraT, lora);
    k_p2<<<T / 256, 256, 0, stream>>>(lora, q_norm_w, kv_norm_w, nrmq, nrmkv);
    k_p2b<<<T, 256, 0, stream>>>(lora, ctab, stab, kb);
    k_p3q<<<dim3(16, 16), 256, 0, stream>>>(nrmq, wqbT, ctab, stab, qb);
    k_p3kv<<<dim3(24, 16), 256, 0, stream>>>(nrmkv, wkvbT, kb, vt_g);

    k_attn<<<dim3(SEQ / 64, NH, BATCH), 256, 0, stream>>>(qb, kb, vt_g, ab);
    k_mm_plain<<<dim3(DM / 64, T / 128), 512, 0, stream>>>(ab, woT, yb);
    k_gate<<<T / 4, 256, 0, stream>>>(yb, gate_w, cnt, lists, wtok);
    k_mm_gu<true><<<dim3(HID / 64, T / 128, NEXP), 512, 0, stream>>>(yb, egT, euT, cnt, lists, act_r);
    k_mm_down<true><<<dim3(DM / 64, T / 128, NEXP), 512, 0, stream>>>(act_r, edT, cnt, lists, wtok, out);
    k_mm_gu<false><<<dim3(HID / 64, T / 128, 1), 512, 0, stream>>>(yb, sgT, suT, cnt, lists, act_s);
    k_mm_down<false><<<dim3(DM / 64, T / 128, 1), 512, 0, stream>>>(act_s, sdT, cnt, lists, wtok, out);
}